// Round 1
// baseline (7562.273 us; speedup 1.0000x reference)
//
#include <hip/hip_runtime.h>
#include <hip/hip_bf16.h>
#include <math.h>

// ---------------------------------------------------------------------------
// Problem constants (from reference setup_inputs)
// ---------------------------------------------------------------------------
#define HD 2048      // hidden size h
#define NQH 16       // num q heads
#define NKVH 4       // num kv heads
#define HEADD 128    // head dim
#define QKVN 3072    // qkv output cols = 16*128 + 2*4*128
#define NEXP 16      // experts
#define EI 512       // expert intermediate I
#define SSI 1024     // shared intermediate SI
#define TOPK 4

// ---------------------------------------------------------------------------
// Fused add + RMSNorm.  resid_out = a (+ b);  x_out = rmsnorm(resid)*w
// one block per row, 256 threads, h = 2048 -> 2 float4 per thread
// ---------------------------------------------------------------------------
__global__ __launch_bounds__(256) void add_rmsnorm_kernel(
    const float* __restrict__ a, const float* __restrict__ b,
    const float* __restrict__ w, float* __restrict__ resid_out,
    float* __restrict__ x_out)
{
    int t = blockIdx.x;
    int tid = threadIdx.x;
    const float4* a4 = (const float4*)(a + (size_t)t * HD);
    const float4* b4 = b ? (const float4*)(b + (size_t)t * HD) : nullptr;
    float4* r4 = resid_out ? (float4*)(resid_out + (size_t)t * HD) : nullptr;
    float4* x4 = (float4*)(x_out + (size_t)t * HD);
    const float4* w4 = (const float4*)w;

    float4 v[2];
    float ss = 0.f;
#pragma unroll
    for (int l = 0; l < 2; ++l) {
        int idx = tid + l * 256;
        float4 va = a4[idx];
        if (b4) {
            float4 vb = b4[idx];
            va.x += vb.x; va.y += vb.y; va.z += vb.z; va.w += vb.w;
        }
        if (r4) r4[idx] = va;
        v[l] = va;
        ss += va.x * va.x + va.y * va.y + va.z * va.z + va.w * va.w;
    }
    // block reduction (4 waves)
    for (int off = 32; off > 0; off >>= 1) ss += __shfl_down(ss, off);
    __shared__ float red[4];
    int lane = tid & 63, wv = tid >> 6;
    if (lane == 0) red[wv] = ss;
    __syncthreads();
    if (tid == 0) {
        float s = red[0] + red[1] + red[2] + red[3];
        red[0] = rsqrtf(s / (float)HD + 1e-6f);
    }
    __syncthreads();
    float inv = red[0];
#pragma unroll
    for (int l = 0; l < 2; ++l) {
        int idx = tid + l * 256;
        float4 va = v[l], vw = w4[idx];
        float4 o;
        o.x = va.x * inv * vw.x;
        o.y = va.y * inv * vw.y;
        o.z = va.z * inv * vw.z;
        o.w = va.w * inv * vw.w;
        x4[idx] = o;
    }
}

// ---------------------------------------------------------------------------
// Generic tiled fp32 GEMM:  C[M,N] (+)= A[M,K] @ (B + bz*strideB)[K,N]
// optional addend (C = acc + addend), accumulate (C += acc), batch via z.
// tile 128x64, BK=16, 256 threads, 8x4 per thread.
// ---------------------------------------------------------------------------
#define TBM 128
#define TBN 64
#define TBK 16

__global__ __launch_bounds__(256) void gemm_f32(
    const float* __restrict__ A, const float* __restrict__ B,
    float* __restrict__ C, int M, int N, int K,
    long long strideB, long long strideC,
    const float* __restrict__ addend, int accumulate)
{
    __shared__ float As[TBK][TBM + 4];
    __shared__ float Bs[TBK][TBN];

    int bx = blockIdx.x, by = blockIdx.y, bz = blockIdx.z;
    const float* Bp = B + (size_t)bz * strideB;
    float* Cp = C + (size_t)bz * strideC;

    int tid = threadIdx.x;
    int tx = tid & 15, ty = tid >> 4;
    int row0 = by * TBM, col0 = bx * TBN;

    float acc[8][4] = {};

    for (int k0 = 0; k0 < K; k0 += TBK) {
        // A tile: 128x16 = 2048 elems -> 8 per thread
#pragma unroll
        for (int l = 0; l < 8; ++l) {
            int idx = tid + l * 256;
            int ar = idx >> 4, ak = idx & 15;
            int gr = row0 + ar;
            As[ak][ar] = (gr < M) ? A[(size_t)gr * K + k0 + ak] : 0.f;
        }
        // B tile: 16x64 = 1024 elems -> 4 per thread
#pragma unroll
        for (int l = 0; l < 4; ++l) {
            int idx = tid + l * 256;
            int bk = idx >> 6, bn = idx & 63;
            int gc = col0 + bn;
            Bs[bk][bn] = (gc < N) ? Bp[(size_t)(k0 + bk) * N + gc] : 0.f;
        }
        __syncthreads();
#pragma unroll
        for (int kk = 0; kk < TBK; ++kk) {
            const float4* ap = (const float4*)&As[kk][ty * 8];
            float4 a0 = ap[0], a1 = ap[1];
            const float4* bp = (const float4*)&Bs[kk][tx * 4];
            float4 b0 = bp[0];
            float av[8] = {a0.x, a0.y, a0.z, a0.w, a1.x, a1.y, a1.z, a1.w};
            float bv[4] = {b0.x, b0.y, b0.z, b0.w};
#pragma unroll
            for (int i = 0; i < 8; ++i)
#pragma unroll
                for (int j = 0; j < 4; ++j)
                    acc[i][j] = fmaf(av[i], bv[j], acc[i][j]);
        }
        __syncthreads();
    }

#pragma unroll
    for (int i = 0; i < 8; ++i) {
        int r = row0 + ty * 8 + i;
        if (r >= M) continue;
#pragma unroll
        for (int j = 0; j < 4; ++j) {
            int c = col0 + tx * 4 + j;
            if (c >= N) continue;
            float v = acc[i][j];
            size_t o = (size_t)r * N + c;
            if (accumulate) Cp[o] += v;
            else Cp[o] = addend ? v + addend[o] : v;
        }
    }
}

// ---------------------------------------------------------------------------
// NeoX RoPE in-place on qkv buffer.  grid (20, T), block 64.
// heads 0..15 = q, 16..19 = k.  thread i handles pair (i, i+64).
// ---------------------------------------------------------------------------
__global__ void rope_kernel(float* __restrict__ qkv,
                            const int* __restrict__ pos_ids)
{
    int head = blockIdx.x;
    int t = blockIdx.y;
    int i = threadIdx.x;  // 0..63
    float* base = qkv + (size_t)t * QKVN +
                  (head < NQH ? head * HEADD : NQH * HEADD + (head - NQH) * HEADD);
    float pos = (float)pos_ids[t];
    float inv_freq = powf(10000.0f, -(2.0f * (float)i) / (float)HEADD);
    float ang = pos * inv_freq;
    float c = cosf(ang);
    float s = sinf(ang);
    float x1 = base[i];
    float x2 = base[i + 64];
    base[i] = x1 * c - x2 * s;
    base[i + 64] = x2 * c + x1 * s;
}

// ---------------------------------------------------------------------------
// Causal GQA attention.  grid (16 heads, T rows), 256 threads.
// scores in LDS, block softmax, V accumulate.  ctx[t][h*128+d]
// ---------------------------------------------------------------------------
__global__ __launch_bounds__(256) void attn_kernel(
    const float* __restrict__ qkv, float* __restrict__ ctx, int T)
{
    int h = blockIdx.x;
    int t = blockIdx.y;
    int kvh = h >> 2;
    int tid = threadIdx.x;

    __shared__ float sc[1024];
    __shared__ float qs[HEADD];
    __shared__ float red[256];

    const float* qrow = qkv + (size_t)t * QKVN + h * HEADD;
    if (tid < HEADD) qs[tid] = qrow[tid];
    __syncthreads();

    const float scale = 0.08838834764831845f;  // 1/sqrt(128)

    // scores s = 0..t
    for (int s = tid; s <= t; s += 256) {
        const float4* k4 = (const float4*)(qkv + (size_t)s * QKVN + NQH * HEADD + kvh * HEADD);
        const float4* q4 = (const float4*)qs;
        float d = 0.f;
#pragma unroll
        for (int i = 0; i < HEADD / 4; ++i) {
            float4 kq = k4[i], qq = q4[i];
            d += qq.x * kq.x + qq.y * kq.y + qq.z * kq.z + qq.w * kq.w;
        }
        sc[s] = d * scale;
    }
    __syncthreads();

    // max
    float m = -1e30f;
    for (int s = tid; s <= t; s += 256) m = fmaxf(m, sc[s]);
    red[tid] = m;
    __syncthreads();
    for (int off = 128; off > 0; off >>= 1) {
        if (tid < off) red[tid] = fmaxf(red[tid], red[tid + off]);
        __syncthreads();
    }
    m = red[0];
    __syncthreads();

    // exp + sum
    float sum = 0.f;
    for (int s = tid; s <= t; s += 256) {
        float p = __expf(sc[s] - m);
        sc[s] = p;
        sum += p;
    }
    red[tid] = sum;
    __syncthreads();
    for (int off = 128; off > 0; off >>= 1) {
        if (tid < off) red[tid] += red[tid + off];
        __syncthreads();
    }
    float inv = 1.f / red[0];
    __syncthreads();

    // ctx
    int d = tid & 127;
    int halfsel = tid >> 7;
    float acc = 0.f;
    const float* vbase = qkv + NQH * HEADD + NKVH * HEADD + kvh * HEADD + d;
    for (int s = halfsel; s <= t; s += 2)
        acc += sc[s] * vbase[(size_t)s * QKVN];
    __syncthreads();
    red[tid] = acc;
    __syncthreads();
    if (tid < HEADD)
        ctx[(size_t)t * (NQH * HEADD) + h * HEADD + d] = (red[tid] + red[tid + 128]) * inv;
}

// ---------------------------------------------------------------------------
// Router: logits (T,16) -> comb (T,16): softmax, top-4, renormalize, scatter
// ---------------------------------------------------------------------------
__global__ void router_kernel(const float* __restrict__ logits,
                              float* __restrict__ comb, int T)
{
    int t = blockIdx.x * blockDim.x + threadIdx.x;
    if (t >= T) return;
    float l[NEXP];
#pragma unroll
    for (int e = 0; e < NEXP; ++e) l[e] = logits[t * NEXP + e];

    int sel[TOPK];
    float selv[TOPK];
    bool used[NEXP] = {};
#pragma unroll
    for (int r = 0; r < TOPK; ++r) {
        int best = -1;
        float bv = -1e30f;
        for (int e = 0; e < NEXP; ++e) {
            if (!used[e] && l[e] > bv) { bv = l[e]; best = e; }
        }
        used[best] = true;
        sel[r] = best;
        selv[r] = bv;
    }
    float mx = selv[0];
    float wsum = 0.f, wv[TOPK];
#pragma unroll
    for (int r = 0; r < TOPK; ++r) { wv[r] = __expf(selv[r] - mx); wsum += wv[r]; }
    float out16[NEXP] = {};
#pragma unroll
    for (int r = 0; r < TOPK; ++r) out16[sel[r]] = wv[r] / wsum;
#pragma unroll
    for (int e = 0; e < NEXP; ++e) comb[t * NEXP + e] = out16[e];
}

// ---------------------------------------------------------------------------
// SwiGLU (shared expert): out[t][i] = silu(gu[t][i]) * gu[t][I+i]
// ---------------------------------------------------------------------------
__global__ void silu_mul_kernel(const float* __restrict__ gu,
                                float* __restrict__ out, int T, int I)
{
    size_t n = (size_t)T * I;
    for (size_t idx = (size_t)blockIdx.x * blockDim.x + threadIdx.x; idx < n;
         idx += (size_t)gridDim.x * blockDim.x) {
        size_t t = idx / I;
        int i = (int)(idx % I);
        float g = gu[t * 2 * I + i];
        float u = gu[t * 2 * I + I + i];
        out[idx] = (g / (1.f + __expf(-g))) * u;
    }
}

// ---------------------------------------------------------------------------
// Expert SwiGLU with comb weighting.
// gu: (G, T, 2*EI) for experts e0..e0+G-1 -> act: (T, NEXP*EI), scaled by comb
// ---------------------------------------------------------------------------
__global__ void silu_mul_moe_kernel(const float* __restrict__ gu,
                                    const float* __restrict__ comb, int e0, int G,
                                    float* __restrict__ act, int T)
{
    size_t n = (size_t)G * T * EI;
    for (size_t idx = (size_t)blockIdx.x * blockDim.x + threadIdx.x; idx < n;
         idx += (size_t)gridDim.x * blockDim.x) {
        int i = (int)(idx % EI);
        size_t tg = idx / EI;
        int t = (int)(tg % T);
        int g = (int)(tg / T);
        int e = e0 + g;
        size_t base = ((size_t)g * T + t) * (2 * EI);
        float gv = gu[base + i];
        float uv = gu[base + EI + i];
        float s = (gv / (1.f + __expf(-gv))) * uv * comb[t * NEXP + e];
        act[(size_t)t * (NEXP * EI) + e * EI + i] = s;
    }
}

// ---------------------------------------------------------------------------
extern "C" void kernel_launch(void* const* d_in, const int* in_sizes, int n_in,
                              void* d_out, int out_size, void* d_ws, size_t ws_size,
                              hipStream_t stream)
{
    const float* hidden   = (const float*)d_in[0];
    const float* residual = (const float*)d_in[1];
    const float* rms1_w   = (const float*)d_in[2];
    const float* rms2_w   = (const float*)d_in[3];
    const float* w_qkv    = (const float*)d_in[4];
    const float* w_dense  = (const float*)d_in[5];
    const float* gate_w   = (const float*)d_in[6];
    const float* w13      = (const float*)d_in[7];
    const float* w2       = (const float*)d_in[8];
    const float* sw13     = (const float*)d_in[9];
    const float* sw2      = (const float*)d_in[10];
    const int*   pos_ids  = (const int*)d_in[11];

    const int T = in_sizes[0] / HD;  // 1024

    float* out0 = (float*)d_out;                      // moe + shared
    float* out1 = (float*)d_out + (size_t)T * HD;     // resid2

    // workspace layout (floats)
    float* Abuf = (float*)d_ws;                        // T*HD   (resid -> x2)
    float* Bbuf = Abuf + (size_t)T * HD;               // T*HD   (x -> ctx -> sact)
    float* Cbuf = Bbuf + (size_t)T * HD;               // T*QKVN (qkv -> gu -> expert gu grp)
    float* L1   = Cbuf + (size_t)T * QKVN;             // T*NEXP logits
    float* L2   = L1 + (size_t)T * NEXP;               // T*NEXP comb
    float* Dbuf = L2 + (size_t)T * NEXP;               // 4*T*1024 expert gu group
    float* Ebuf = Dbuf + (size_t)4 * T * 1024;         // T*8192 weighted act

    dim3 blk(256);

    // 1. resid = hidden + residual ; x = rmsnorm(resid)*rms1_w
    add_rmsnorm_kernel<<<dim3(T), blk, 0, stream>>>(hidden, residual, rms1_w, Abuf, Bbuf);

    // 2. qkv = x @ w_qkv   (T,3072)
    gemm_f32<<<dim3(QKVN / TBN, (T + TBM - 1) / TBM), blk, 0, stream>>>(
        Bbuf, w_qkv, Cbuf, T, QKVN, HD, 0, 0, nullptr, 0);

    // 3. RoPE on q and k (in place)
    rope_kernel<<<dim3(NQH + NKVH, T), dim3(64), 0, stream>>>(Cbuf, pos_ids);

    // 4. attention -> ctx (reuse Bbuf)
    attn_kernel<<<dim3(NQH, T), blk, 0, stream>>>(Cbuf, Bbuf, T);

    // 5. resid2 = ctx @ w_dense + resid   -> out1
    gemm_f32<<<dim3(HD / TBN, (T + TBM - 1) / TBM), blk, 0, stream>>>(
        Bbuf, w_dense, out1, T, HD, HD, 0, 0, Abuf, 0);

    // 6. x2 = rmsnorm(resid2)*rms2_w  -> Abuf
    add_rmsnorm_kernel<<<dim3(T), blk, 0, stream>>>(out1, nullptr, rms2_w, nullptr, Abuf);

    // 7. router logits = x2 @ gate_w  (T,16)
    gemm_f32<<<dim3(1, (T + TBM - 1) / TBM), blk, 0, stream>>>(
        Abuf, gate_w, L1, T, NEXP, HD, 0, 0, nullptr, 0);

    // 8. comb (T,16)
    router_kernel<<<dim3((T + 255) / 256), blk, 0, stream>>>(L1, L2, T);

    // 9. shared gu = x2 @ sw13  (T,2048) -> Cbuf
    gemm_f32<<<dim3(2 * SSI / TBN, (T + TBM - 1) / TBM), blk, 0, stream>>>(
        Abuf, sw13, Cbuf, T, 2 * SSI, HD, 0, 0, nullptr, 0);

    // 10. shared act -> Bbuf (T,1024)
    silu_mul_kernel<<<dim3(2048), blk, 0, stream>>>(Cbuf, Bbuf, T, SSI);

    // 11. out0 = shared_act @ sw2  (T,2048)
    gemm_f32<<<dim3(HD / TBN, (T + TBM - 1) / TBM), blk, 0, stream>>>(
        Bbuf, sw2, out0, T, HD, SSI, 0, 0, nullptr, 0);

    // 12. experts, 4 at a time: gu = x2 @ w13[e] ; act = silu-mul * comb
    for (int g = 0; g < 4; ++g) {
        int e0 = g * 4;
        gemm_f32<<<dim3(1024 / TBN, (T + TBM - 1) / TBM, 4), blk, 0, stream>>>(
            Abuf, w13 + (size_t)e0 * HD * 1024, Dbuf, T, 1024, HD,
            (long long)HD * 1024, (long long)T * 1024, nullptr, 0);
        silu_mul_moe_kernel<<<dim3(2048), blk, 0, stream>>>(Dbuf, L2, e0, 4, Ebuf, T);
    }

    // 13. out0 += ACT @ w2.reshape(8192, 2048)
    gemm_f32<<<dim3(HD / TBN, (T + TBM - 1) / TBM), blk, 0, stream>>>(
        Ebuf, w2, out0, T, HD, NEXP * EI, 0, 0, nullptr, 1);
}

// Round 2
// 5442.076 us; speedup vs baseline: 1.3896x; 1.3896x over previous
//
#include <hip/hip_runtime.h>
#include <hip/hip_bf16.h>
#include <math.h>

// ---------------------------------------------------------------------------
// Problem constants (from reference setup_inputs)
// ---------------------------------------------------------------------------
#define HD 2048      // hidden size h
#define NQH 16       // num q heads
#define NKVH 4       // num kv heads
#define HEADD 128    // head dim
#define QKVN 3072    // qkv output cols = 16*128 + 2*4*128
#define NEXP 16      // experts
#define EI 512       // expert intermediate I
#define SSI 1024     // shared intermediate SI
#define TOPK 4

// ---------------------------------------------------------------------------
// Fused add + RMSNorm.  resid_out = a (+ b);  x_out = rmsnorm(resid)*w
// ---------------------------------------------------------------------------
__global__ __launch_bounds__(256) void add_rmsnorm_kernel(
    const float* __restrict__ a, const float* __restrict__ b,
    const float* __restrict__ w, float* __restrict__ resid_out,
    float* __restrict__ x_out)
{
    int t = blockIdx.x;
    int tid = threadIdx.x;
    const float4* a4 = (const float4*)(a + (size_t)t * HD);
    const float4* b4 = b ? (const float4*)(b + (size_t)t * HD) : nullptr;
    float4* r4 = resid_out ? (float4*)(resid_out + (size_t)t * HD) : nullptr;
    float4* x4 = (float4*)(x_out + (size_t)t * HD);
    const float4* w4 = (const float4*)w;

    float4 v[2];
    float ss = 0.f;
#pragma unroll
    for (int l = 0; l < 2; ++l) {
        int idx = tid + l * 256;
        float4 va = a4[idx];
        if (b4) {
            float4 vb = b4[idx];
            va.x += vb.x; va.y += vb.y; va.z += vb.z; va.w += vb.w;
        }
        if (r4) r4[idx] = va;
        v[l] = va;
        ss += va.x * va.x + va.y * va.y + va.z * va.z + va.w * va.w;
    }
    for (int off = 32; off > 0; off >>= 1) ss += __shfl_down(ss, off);
    __shared__ float red[4];
    int lane = tid & 63, wv = tid >> 6;
    if (lane == 0) red[wv] = ss;
    __syncthreads();
    if (tid == 0) {
        float s = red[0] + red[1] + red[2] + red[3];
        red[0] = rsqrtf(s / (float)HD + 1e-6f);
    }
    __syncthreads();
    float inv = red[0];
#pragma unroll
    for (int l = 0; l < 2; ++l) {
        int idx = tid + l * 256;
        float4 va = v[l], vw = w4[idx];
        float4 o;
        o.x = va.x * inv * vw.x;
        o.y = va.y * inv * vw.y;
        o.z = va.z * inv * vw.z;
        o.w = va.w * inv * vw.w;
        x4[idx] = o;
    }
}

// ---------------------------------------------------------------------------
// Generic tiled fp32 GEMM:  C[M,N] (+)= A[M,K] @ (B + bz*strideB)[K,N]
// ---------------------------------------------------------------------------
#define TBM 128
#define TBN 64
#define TBK 16

__global__ __launch_bounds__(256) void gemm_f32(
    const float* __restrict__ A, const float* __restrict__ B,
    float* __restrict__ C, int M, int N, int K,
    long long strideB, long long strideC,
    const float* __restrict__ addend, int accumulate)
{
    __shared__ float As[TBK][TBM + 4];
    __shared__ float Bs[TBK][TBN];

    int bx = blockIdx.x, by = blockIdx.y, bz = blockIdx.z;
    const float* Bp = B + (size_t)bz * strideB;
    float* Cp = C + (size_t)bz * strideC;

    int tid = threadIdx.x;
    int tx = tid & 15, ty = tid >> 4;
    int row0 = by * TBM, col0 = bx * TBN;

    float acc[8][4] = {};

    for (int k0 = 0; k0 < K; k0 += TBK) {
#pragma unroll
        for (int l = 0; l < 8; ++l) {
            int idx = tid + l * 256;
            int ar = idx >> 4, ak = idx & 15;
            int gr = row0 + ar;
            As[ak][ar] = (gr < M) ? A[(size_t)gr * K + k0 + ak] : 0.f;
        }
#pragma unroll
        for (int l = 0; l < 4; ++l) {
            int idx = tid + l * 256;
            int bk = idx >> 6, bn = idx & 63;
            int gc = col0 + bn;
            Bs[bk][bn] = (gc < N) ? Bp[(size_t)(k0 + bk) * N + gc] : 0.f;
        }
        __syncthreads();
#pragma unroll
        for (int kk = 0; kk < TBK; ++kk) {
            const float4* ap = (const float4*)&As[kk][ty * 8];
            float4 a0 = ap[0], a1 = ap[1];
            const float4* bp = (const float4*)&Bs[kk][tx * 4];
            float4 b0 = bp[0];
            float av[8] = {a0.x, a0.y, a0.z, a0.w, a1.x, a1.y, a1.z, a1.w};
            float bv[4] = {b0.x, b0.y, b0.z, b0.w};
#pragma unroll
            for (int i = 0; i < 8; ++i)
#pragma unroll
                for (int j = 0; j < 4; ++j)
                    acc[i][j] = fmaf(av[i], bv[j], acc[i][j]);
        }
        __syncthreads();
    }

#pragma unroll
    for (int i = 0; i < 8; ++i) {
        int r = row0 + ty * 8 + i;
        if (r >= M) continue;
#pragma unroll
        for (int j = 0; j < 4; ++j) {
            int c = col0 + tx * 4 + j;
            if (c >= N) continue;
            float v = acc[i][j];
            size_t o = (size_t)r * N + c;
            if (accumulate) Cp[o] += v;
            else Cp[o] = addend ? v + addend[o] : v;
        }
    }
}

// ---------------------------------------------------------------------------
// NeoX RoPE in-place on qkv buffer.  grid (20, T), block 64.
// ---------------------------------------------------------------------------
__global__ void rope_kernel(float* __restrict__ qkv,
                            const int* __restrict__ pos_ids)
{
    int head = blockIdx.x;
    int t = blockIdx.y;
    int i = threadIdx.x;  // 0..63
    float* base = qkv + (size_t)t * QKVN +
                  (head < NQH ? head * HEADD : NQH * HEADD + (head - NQH) * HEADD);
    float pos = (float)pos_ids[t];
    float inv_freq = powf(10000.0f, -(2.0f * (float)i) / (float)HEADD);
    float ang = pos * inv_freq;
    float c = cosf(ang);
    float s = sinf(ang);
    float x1 = base[i];
    float x2 = base[i + 64];
    base[i] = x1 * c - x2 * s;
    base[i + 64] = x2 * c + x1 * s;
}

// ---------------------------------------------------------------------------
// Flash attention (fp32 VALU).  grid (NQH, T/64), 256 threads.
// Per block: 64 query rows of one head.  K/V tiles of 64 staged in LDS with
// XOR-swizzled float4 layout (conflict-free), online softmax, PV accumulate.
// ---------------------------------------------------------------------------
#define QT 64
#define KT 64

__global__ __launch_bounds__(256) void flash_attn_kernel(
    const float* __restrict__ qkv, float* __restrict__ ctx)
{
    __shared__ float Qs[QT * HEADD];     // swizzled f4 rows [64][32 f4]
    __shared__ float Ks[KT * HEADD];
    __shared__ float Vs[KT * HEADD];
    __shared__ float Ps[QT * 68];        // padded [64][68] f32
    __shared__ float aL[QT];
    __shared__ float lL[QT];

    const int h   = blockIdx.x;
    const int qt  = blockIdx.y;
    const int q0  = qt * QT;
    const int kvh = h >> 2;
    const int tid = threadIdx.x;

    const int tx  = tid & 15, ty  = tid >> 4;  // S-phase 16x16 (4x4 frags)
    const int tx5 = tid & 31, ty3 = tid >> 5;  // PV-phase 32x8 (8x4 frags)

    // ---- stage Q once (rows q0..q0+63), swizzled ----
#pragma unroll
    for (int l = 0; l < 8; ++l) {
        int idx = tid + l * 256;
        int r = idx >> 5, cc = idx & 31;
        float4 v = ((const float4*)(qkv + (size_t)(q0 + r) * QKVN + h * HEADD))[cc];
        ((float4*)Qs)[r * 32 + (cc ^ ((r >> 2) & 7))] = v;
    }

    float m_i[4], l_i[4];
#pragma unroll
    for (int i = 0; i < 4; ++i) { m_i[i] = -1e30f; l_i[i] = 0.f; }
    float oacc[8][4] = {};

    const float scale = 0.08838834764831843f;  // 1/sqrt(128)
    __syncthreads();

    for (int kt = 0; kt <= qt; ++kt) {
        const int s0 = kt * KT;

        // ---- stage K and V tiles (swizzled) ----
#pragma unroll
        for (int l = 0; l < 8; ++l) {
            int idx = tid + l * 256;
            int r = idx >> 5, cc = idx & 31;
            int sw = r * 32 + (cc ^ ((r >> 2) & 7));
            const float* krow = qkv + (size_t)(s0 + r) * QKVN + NQH * HEADD + kvh * HEADD;
            ((float4*)Ks)[sw] = ((const float4*)krow)[cc];
            ((float4*)Vs)[sw] = ((const float4*)(krow + NKVH * HEADD))[cc];
        }
        __syncthreads();

        // ---- S = Q K^T : 4x4 fragment per thread ----
        float sacc[4][4] = {};
        const int qsw = ty & 7;   // (r>>2)&7 for r = 4ty+i
        const int ksw = tx & 7;   // (r>>2)&7 for r = 4tx+j
#pragma unroll 8
        for (int k4 = 0; k4 < 32; ++k4) {
            float4 qv[4], kv[4];
#pragma unroll
            for (int i = 0; i < 4; ++i)
                qv[i] = ((const float4*)Qs)[(4 * ty + i) * 32 + (k4 ^ qsw)];
#pragma unroll
            for (int j = 0; j < 4; ++j)
                kv[j] = ((const float4*)Ks)[(4 * tx + j) * 32 + (k4 ^ ksw)];
#pragma unroll
            for (int i = 0; i < 4; ++i)
#pragma unroll
                for (int j = 0; j < 4; ++j)
                    sacc[i][j] += qv[i].x * kv[j].x + qv[i].y * kv[j].y +
                                  qv[i].z * kv[j].z + qv[i].w * kv[j].w;
        }

        // ---- online softmax (rows 4ty+i, 16-lane tx groups) ----
        const bool diag = (kt == qt);
#pragma unroll
        for (int i = 0; i < 4; ++i) {
            float rm = -1e30f;
#pragma unroll
            for (int j = 0; j < 4; ++j) {
                float s = sacc[i][j] * scale;
                if (diag && (4 * tx + j) > (4 * ty + i)) s = -1e30f;
                sacc[i][j] = s;
                rm = fmaxf(rm, s);
            }
            rm = fmaxf(rm, __shfl_xor(rm, 1));
            rm = fmaxf(rm, __shfl_xor(rm, 2));
            rm = fmaxf(rm, __shfl_xor(rm, 4));
            rm = fmaxf(rm, __shfl_xor(rm, 8));
            float mnew  = fmaxf(m_i[i], rm);
            float alpha = __expf(m_i[i] - mnew);
            float rs = 0.f;
            float4 p4;
            p4.x = __expf(sacc[i][0] - mnew);
            p4.y = __expf(sacc[i][1] - mnew);
            p4.z = __expf(sacc[i][2] - mnew);
            p4.w = __expf(sacc[i][3] - mnew);
            rs = p4.x + p4.y + p4.z + p4.w;
            rs += __shfl_xor(rs, 1);
            rs += __shfl_xor(rs, 2);
            rs += __shfl_xor(rs, 4);
            rs += __shfl_xor(rs, 8);
            l_i[i] = l_i[i] * alpha + rs;
            m_i[i] = mnew;
            ((float4*)Ps)[(4 * ty + i) * 17 + tx] = p4;
            if (tx == 0) aL[4 * ty + i] = alpha;
        }
        __syncthreads();

        // ---- O rescale + PV (rows 8*ty3+i, cols 4*tx5+c) ----
#pragma unroll
        for (int i = 0; i < 8; ++i) {
            float a = aL[ty3 * 8 + i];
#pragma unroll
            for (int c = 0; c < 4; ++c) oacc[i][c] *= a;
        }
#pragma unroll 2
        for (int s4 = 0; s4 < 16; ++s4) {
            float4 p4[8];
#pragma unroll
            for (int i = 0; i < 8; ++i)
                p4[i] = ((const float4*)Ps)[(ty3 * 8 + i) * 17 + s4];
#pragma unroll
            for (int q = 0; q < 4; ++q) {
                int s = 4 * s4 + q;
                float4 v4 = ((const float4*)Vs)[s * 32 + (tx5 ^ ((s >> 2) & 7))];
#pragma unroll
                for (int i = 0; i < 8; ++i) {
                    float p = (q == 0) ? p4[i].x : (q == 1) ? p4[i].y
                            : (q == 2) ? p4[i].z : p4[i].w;
                    oacc[i][0] = fmaf(p, v4.x, oacc[i][0]);
                    oacc[i][1] = fmaf(p, v4.y, oacc[i][1]);
                    oacc[i][2] = fmaf(p, v4.z, oacc[i][2]);
                    oacc[i][3] = fmaf(p, v4.w, oacc[i][3]);
                }
            }
        }
        __syncthreads();
    }

    // ---- finalize: O /= l ----
    if (tx == 0) {
#pragma unroll
        for (int i = 0; i < 4; ++i) lL[4 * ty + i] = 1.f / l_i[i];
    }
    __syncthreads();
#pragma unroll
    for (int i = 0; i < 8; ++i) {
        int r = ty3 * 8 + i;
        float inv = lL[r];
        float4 o = make_float4(oacc[i][0] * inv, oacc[i][1] * inv,
                               oacc[i][2] * inv, oacc[i][3] * inv);
        ((float4*)(ctx + (size_t)(q0 + r) * (NQH * HEADD) + h * HEADD))[tx5] = o;
    }
}

// ---------------------------------------------------------------------------
// Router: logits (T,16) -> comb (T,16)
// ---------------------------------------------------------------------------
__global__ void router_kernel(const float* __restrict__ logits,
                              float* __restrict__ comb, int T)
{
    int t = blockIdx.x * blockDim.x + threadIdx.x;
    if (t >= T) return;
    float l[NEXP];
#pragma unroll
    for (int e = 0; e < NEXP; ++e) l[e] = logits[t * NEXP + e];

    int sel[TOPK];
    float selv[TOPK];
    bool used[NEXP] = {};
#pragma unroll
    for (int r = 0; r < TOPK; ++r) {
        int best = -1;
        float bv = -1e30f;
        for (int e = 0; e < NEXP; ++e) {
            if (!used[e] && l[e] > bv) { bv = l[e]; best = e; }
        }
        used[best] = true;
        sel[r] = best;
        selv[r] = bv;
    }
    float mx = selv[0];
    float wsum = 0.f, wv[TOPK];
#pragma unroll
    for (int r = 0; r < TOPK; ++r) { wv[r] = __expf(selv[r] - mx); wsum += wv[r]; }
    float out16[NEXP] = {};
#pragma unroll
    for (int r = 0; r < TOPK; ++r) out16[sel[r]] = wv[r] / wsum;
#pragma unroll
    for (int e = 0; e < NEXP; ++e) comb[t * NEXP + e] = out16[e];
}

// ---------------------------------------------------------------------------
// SwiGLU (shared expert)
// ---------------------------------------------------------------------------
__global__ void silu_mul_kernel(const float* __restrict__ gu,
                                float* __restrict__ out, int T, int I)
{
    size_t n = (size_t)T * I;
    for (size_t idx = (size_t)blockIdx.x * blockDim.x + threadIdx.x; idx < n;
         idx += (size_t)gridDim.x * blockDim.x) {
        size_t t = idx / I;
        int i = (int)(idx % I);
        float g = gu[t * 2 * I + i];
        float u = gu[t * 2 * I + I + i];
        out[idx] = (g / (1.f + __expf(-g))) * u;
    }
}

// ---------------------------------------------------------------------------
// Expert SwiGLU with comb weighting.
// ---------------------------------------------------------------------------
__global__ void silu_mul_moe_kernel(const float* __restrict__ gu,
                                    const float* __restrict__ comb, int e0, int G,
                                    float* __restrict__ act, int T)
{
    size_t n = (size_t)G * T * EI;
    for (size_t idx = (size_t)blockIdx.x * blockDim.x + threadIdx.x; idx < n;
         idx += (size_t)gridDim.x * blockDim.x) {
        int i = (int)(idx % EI);
        size_t tg = idx / EI;
        int t = (int)(tg % T);
        int g = (int)(tg / T);
        int e = e0 + g;
        size_t base = ((size_t)g * T + t) * (2 * EI);
        float gv = gu[base + i];
        float uv = gu[base + EI + i];
        float s = (gv / (1.f + __expf(-gv))) * uv * comb[t * NEXP + e];
        act[(size_t)t * (NEXP * EI) + e * EI + i] = s;
    }
}

// ---------------------------------------------------------------------------
extern "C" void kernel_launch(void* const* d_in, const int* in_sizes, int n_in,
                              void* d_out, int out_size, void* d_ws, size_t ws_size,
                              hipStream_t stream)
{
    const float* hidden   = (const float*)d_in[0];
    const float* residual = (const float*)d_in[1];
    const float* rms1_w   = (const float*)d_in[2];
    const float* rms2_w   = (const float*)d_in[3];
    const float* w_qkv    = (const float*)d_in[4];
    const float* w_dense  = (const float*)d_in[5];
    const float* gate_w   = (const float*)d_in[6];
    const float* w13      = (const float*)d_in[7];
    const float* w2       = (const float*)d_in[8];
    const float* sw13     = (const float*)d_in[9];
    const float* sw2      = (const float*)d_in[10];
    const int*   pos_ids  = (const int*)d_in[11];

    const int T = in_sizes[0] / HD;  // 1024

    float* out0 = (float*)d_out;                      // moe + shared
    float* out1 = (float*)d_out + (size_t)T * HD;     // resid2

    // workspace layout (floats)
    float* Abuf = (float*)d_ws;                        // T*HD   (resid -> x2)
    float* Bbuf = Abuf + (size_t)T * HD;               // T*HD   (x -> ctx -> sact)
    float* Cbuf = Bbuf + (size_t)T * HD;               // T*QKVN (qkv -> gu)
    float* L1   = Cbuf + (size_t)T * QKVN;             // T*NEXP logits
    float* L2   = L1 + (size_t)T * NEXP;               // T*NEXP comb
    float* Dbuf = L2 + (size_t)T * NEXP;               // 4*T*1024 expert gu group
    float* Ebuf = Dbuf + (size_t)4 * T * 1024;         // T*8192 weighted act

    dim3 blk(256);

    // 1. resid = hidden + residual ; x = rmsnorm(resid)*rms1_w
    add_rmsnorm_kernel<<<dim3(T), blk, 0, stream>>>(hidden, residual, rms1_w, Abuf, Bbuf);

    // 2. qkv = x @ w_qkv   (T,3072)
    gemm_f32<<<dim3(QKVN / TBN, (T + TBM - 1) / TBM), blk, 0, stream>>>(
        Bbuf, w_qkv, Cbuf, T, QKVN, HD, 0, 0, nullptr, 0);

    // 3. RoPE on q and k (in place)
    rope_kernel<<<dim3(NQH + NKVH, T), dim3(64), 0, stream>>>(Cbuf, pos_ids);

    // 4. flash attention -> ctx (reuse Bbuf)
    flash_attn_kernel<<<dim3(NQH, T / QT), blk, 0, stream>>>(Cbuf, Bbuf);

    // 5. resid2 = ctx @ w_dense + resid   -> out1
    gemm_f32<<<dim3(HD / TBN, (T + TBM - 1) / TBM), blk, 0, stream>>>(
        Bbuf, w_dense, out1, T, HD, HD, 0, 0, Abuf, 0);

    // 6. x2 = rmsnorm(resid2)*rms2_w  -> Abuf
    add_rmsnorm_kernel<<<dim3(T), blk, 0, stream>>>(out1, nullptr, rms2_w, nullptr, Abuf);

    // 7. router logits = x2 @ gate_w  (T,16)
    gemm_f32<<<dim3(1, (T + TBM - 1) / TBM), blk, 0, stream>>>(
        Abuf, gate_w, L1, T, NEXP, HD, 0, 0, nullptr, 0);

    // 8. comb (T,16)
    router_kernel<<<dim3((T + 255) / 256), blk, 0, stream>>>(L1, L2, T);

    // 9. shared gu = x2 @ sw13  (T,2048) -> Cbuf
    gemm_f32<<<dim3(2 * SSI / TBN, (T + TBM - 1) / TBM), blk, 0, stream>>>(
        Abuf, sw13, Cbuf, T, 2 * SSI, HD, 0, 0, nullptr, 0);

    // 10. shared act -> Bbuf (T,1024)
    silu_mul_kernel<<<dim3(2048), blk, 0, stream>>>(Cbuf, Bbuf, T, SSI);

    // 11. out0 = shared_act @ sw2  (T,2048)
    gemm_f32<<<dim3(HD / TBN, (T + TBM - 1) / TBM), blk, 0, stream>>>(
        Bbuf, sw2, out0, T, HD, SSI, 0, 0, nullptr, 0);

    // 12. experts, 4 at a time: gu = x2 @ w13[e] ; act = silu-mul * comb
    for (int g = 0; g < 4; ++g) {
        int e0 = g * 4;
        gemm_f32<<<dim3(1024 / TBN, (T + TBM - 1) / TBM, 4), blk, 0, stream>>>(
            Abuf, w13 + (size_t)e0 * HD * 1024, Dbuf, T, 1024, HD,
            (long long)HD * 1024, (long long)T * 1024, nullptr, 0);
        silu_mul_moe_kernel<<<dim3(2048), blk, 0, stream>>>(Dbuf, L2, e0, 4, Ebuf, T);
    }

    // 13. out0 += ACT @ w2.reshape(8192, 2048)
    gemm_f32<<<dim3(HD / TBN, (T + TBM - 1) / TBM), blk, 0, stream>>>(
        Ebuf, w2, out0, T, HD, NEXP * EI, 0, 0, nullptr, 1);
}

// Round 3
// 938.868 us; speedup vs baseline: 8.0547x; 5.7964x over previous
//
#include <hip/hip_runtime.h>
#include <math.h>

// ---------------------------------------------------------------------------
// Problem constants
// ---------------------------------------------------------------------------
#define HD 2048      // hidden size h
#define NQH 16       // num q heads
#define NKVH 4       // num kv heads
#define HEADD 128    // head dim
#define QKVN 3072    // qkv cols
#define NEXP 16      // experts
#define EI 512       // expert intermediate
#define SSI 1024     // shared intermediate
#define TOPK 4
#define TT 1024      // tokens

typedef __bf16 bf16x8 __attribute__((ext_vector_type(8)));
typedef float f32x4 __attribute__((ext_vector_type(4)));

static __device__ __forceinline__ unsigned short f2bf(float f) {
    union { float f; unsigned int u; } v; v.f = f;
    unsigned int r = v.u + 0x7fff + ((v.u >> 16) & 1);
    return (unsigned short)(r >> 16);
}

// ---------------------------------------------------------------------------
// Fused add + RMSNorm. resid_out(f32 opt) ; x_bf (bf16) ; x_f32 (opt)
// ---------------------------------------------------------------------------
__global__ __launch_bounds__(256) void add_rmsnorm_kernel(
    const float* __restrict__ a, const float* __restrict__ b,
    const float* __restrict__ w, float* __restrict__ resid_out,
    unsigned short* __restrict__ x_bf, float* __restrict__ x_f32)
{
    int t = blockIdx.x;
    int tid = threadIdx.x;
    const float4* a4 = (const float4*)(a + (size_t)t * HD);
    const float4* b4 = b ? (const float4*)(b + (size_t)t * HD) : nullptr;
    float4* r4 = resid_out ? (float4*)(resid_out + (size_t)t * HD) : nullptr;
    const float4* w4 = (const float4*)w;

    float4 v[2];
    float ss = 0.f;
#pragma unroll
    for (int l = 0; l < 2; ++l) {
        int idx = tid + l * 256;
        float4 va = a4[idx];
        if (b4) {
            float4 vb = b4[idx];
            va.x += vb.x; va.y += vb.y; va.z += vb.z; va.w += vb.w;
        }
        if (r4) r4[idx] = va;
        v[l] = va;
        ss += va.x * va.x + va.y * va.y + va.z * va.z + va.w * va.w;
    }
    for (int off = 32; off > 0; off >>= 1) ss += __shfl_down(ss, off);
    __shared__ float red[4];
    int lane = tid & 63, wv = tid >> 6;
    if (lane == 0) red[wv] = ss;
    __syncthreads();
    if (tid == 0) {
        float s = red[0] + red[1] + red[2] + red[3];
        red[0] = rsqrtf(s / (float)HD + 1e-6f);
    }
    __syncthreads();
    float inv = red[0];
#pragma unroll
    for (int l = 0; l < 2; ++l) {
        int idx = tid + l * 256;
        float4 va = v[l], vw = w4[idx];
        float4 o;
        o.x = va.x * inv * vw.x;
        o.y = va.y * inv * vw.y;
        o.z = va.z * inv * vw.z;
        o.w = va.w * inv * vw.w;
        ushort4 ob;
        ob.x = f2bf(o.x); ob.y = f2bf(o.y); ob.z = f2bf(o.z); ob.w = f2bf(o.w);
        ((ushort4*)(x_bf + (size_t)t * HD))[idx] = ob;
        if (x_f32) ((float4*)(x_f32 + (size_t)t * HD))[idx] = o;
    }
}

// ---------------------------------------------------------------------------
// Transpose + convert: f32 in [K][N] -> bf16 out [N][K]   (per-z strides)
// ---------------------------------------------------------------------------
__global__ __launch_bounds__(256) void transpose_convert(
    const float* __restrict__ in, unsigned short* __restrict__ out,
    int K, int N, long long strideIn, long long strideOut)
{
    __shared__ float tile[32][33];
    const int n0 = blockIdx.x * 32;
    const int k0 = blockIdx.y * 32;
    const float* ip = in + (size_t)blockIdx.z * strideIn;
    unsigned short* op = out + (size_t)blockIdx.z * strideOut;
    int tid = threadIdx.x;
    int r = tid >> 3, c = (tid & 7) * 4;
    float4 v = *(const float4*)(ip + (size_t)(k0 + r) * N + n0 + c);
    tile[r][c] = v.x; tile[r][c + 1] = v.y; tile[r][c + 2] = v.z; tile[r][c + 3] = v.w;
    __syncthreads();
    ushort4 o;
    o.x = f2bf(tile[c + 0][r]);
    o.y = f2bf(tile[c + 1][r]);
    o.z = f2bf(tile[c + 2][r]);
    o.w = f2bf(tile[c + 3][r]);
    *(ushort4*)(op + (size_t)(n0 + r) * K + k0 + c) = o;
}

// ---------------------------------------------------------------------------
// bf16 MFMA GEMM (m97 structure): C[M,N] = A[M,K](bf16) @ B^T[N,K](bf16)
// 128x128 tile, BK=32, 4 waves (2x2), 4x4 16x16x32 fragments per wave.
// optional addend (f32), accumulate, batch-z strides.
// ---------------------------------------------------------------------------
#define GBM 128
#define GBN 128
#define GBK 32

__global__ __launch_bounds__(256) void gemm_bf16(
    const unsigned short* __restrict__ A, const unsigned short* __restrict__ B,
    float* __restrict__ C, int M, int N, int K,
    long long strideB, long long strideC,
    const float* __restrict__ addend, int accumulate)
{
    __shared__ unsigned short As[GBM * GBK];
    __shared__ unsigned short Bs[GBN * GBK];

    const int tid = threadIdx.x;
    const int wave = tid >> 6;
    const int lane = tid & 63;
    const int wr = wave >> 1, wc = wave & 1;
    const int row0 = blockIdx.y * GBM;
    const int col0 = blockIdx.x * GBN;
    const unsigned short* Bp = B + (size_t)blockIdx.z * strideB;
    float* Cp = C + (size_t)blockIdx.z * strideC;

    const int l15 = lane & 15;
    const int kc = (lane >> 4) * 8;
    const int r_st = tid >> 2;          // staging row (0..63 per 256-chunk)
    const int c_st = (tid & 3) * 8;     // staging col chunk (8 bf16 = 16B)

    f32x4 acc[4][4] = {};

    for (int k0 = 0; k0 < K; k0 += GBK) {
#pragma unroll
        for (int i = 0; i < 2; ++i) {
            int row = i * 64 + r_st;
            __builtin_amdgcn_global_load_lds(
                (const __attribute__((address_space(1))) unsigned int*)
                    (A + (size_t)(row0 + row) * K + k0 + c_st),
                (__attribute__((address_space(3))) unsigned int*)
                    (As + row * GBK + c_st), 16, 0, 0);
            __builtin_amdgcn_global_load_lds(
                (const __attribute__((address_space(1))) unsigned int*)
                    (Bp + (size_t)(col0 + row) * K + k0 + c_st),
                (__attribute__((address_space(3))) unsigned int*)
                    (Bs + row * GBK + c_st), 16, 0, 0);
        }
        __syncthreads();

        bf16x8 af[4], bfr[4];
#pragma unroll
        for (int i = 0; i < 4; ++i) {
            af[i]  = *(const bf16x8*)&As[(wr * 64 + i * 16 + l15) * GBK + kc];
            bfr[i] = *(const bf16x8*)&Bs[(wc * 64 + i * 16 + l15) * GBK + kc];
        }
#pragma unroll
        for (int mi = 0; mi < 4; ++mi)
#pragma unroll
            for (int nj = 0; nj < 4; ++nj)
                acc[mi][nj] = __builtin_amdgcn_mfma_f32_16x16x32_bf16(
                    af[mi], bfr[nj], acc[mi][nj], 0, 0, 0);
        __syncthreads();
    }

#pragma unroll
    for (int mi = 0; mi < 4; ++mi) {
#pragma unroll
        for (int nj = 0; nj < 4; ++nj) {
#pragma unroll
            for (int r = 0; r < 4; ++r) {
                int row = row0 + wr * 64 + mi * 16 + (lane >> 4) * 4 + r;
                int col = col0 + wc * 64 + nj * 16 + l15;
                size_t o = (size_t)row * N + col;
                float v = acc[mi][nj][r];
                if (accumulate) Cp[o] += v;
                else Cp[o] = addend ? v + addend[o] : v;
            }
        }
    }
}

// ---------------------------------------------------------------------------
// NeoX RoPE in-place (f32 qkv).  grid (20, T), block 64.
// ---------------------------------------------------------------------------
__global__ void rope_kernel(float* __restrict__ qkv,
                            const int* __restrict__ pos_ids)
{
    int head = blockIdx.x;
    int t = blockIdx.y;
    int i = threadIdx.x;
    float* base = qkv + (size_t)t * QKVN +
                  (head < NQH ? head * HEADD : NQH * HEADD + (head - NQH) * HEADD);
    float pos = (float)pos_ids[t];
    float inv_freq = powf(10000.0f, -(2.0f * (float)i) / (float)HEADD);
    float ang = pos * inv_freq;
    float c = cosf(ang);
    float s = sinf(ang);
    float x1 = base[i];
    float x2 = base[i + 64];
    base[i] = x1 * c - x2 * s;
    base[i + 64] = x2 * c + x1 * s;
}

// ---------------------------------------------------------------------------
// Flash attention (fp32 VALU), output bf16 ctx.  grid (NQH, T/64), 256 thr.
// ---------------------------------------------------------------------------
#define QT 64
#define KT 64

__global__ __launch_bounds__(256) void flash_attn_kernel(
    const float* __restrict__ qkv, unsigned short* __restrict__ ctx)
{
    __shared__ float Qs[QT * HEADD];
    __shared__ float Ks[KT * HEADD];
    __shared__ float Vs[KT * HEADD];
    __shared__ float Ps[QT * 68];
    __shared__ float aL[QT];
    __shared__ float lL[QT];

    const int h   = blockIdx.x;
    const int qt  = blockIdx.y;
    const int q0  = qt * QT;
    const int kvh = h >> 2;
    const int tid = threadIdx.x;

    const int tx  = tid & 15, ty  = tid >> 4;
    const int tx5 = tid & 31, ty3 = tid >> 5;

#pragma unroll
    for (int l = 0; l < 8; ++l) {
        int idx = tid + l * 256;
        int r = idx >> 5, cc = idx & 31;
        float4 v = ((const float4*)(qkv + (size_t)(q0 + r) * QKVN + h * HEADD))[cc];
        ((float4*)Qs)[r * 32 + (cc ^ ((r >> 2) & 7))] = v;
    }

    float m_i[4], l_i[4];
#pragma unroll
    for (int i = 0; i < 4; ++i) { m_i[i] = -1e30f; l_i[i] = 0.f; }
    float oacc[8][4] = {};

    const float scale = 0.08838834764831843f;
    __syncthreads();

    for (int kt = 0; kt <= qt; ++kt) {
        const int s0 = kt * KT;
#pragma unroll
        for (int l = 0; l < 8; ++l) {
            int idx = tid + l * 256;
            int r = idx >> 5, cc = idx & 31;
            int sw = r * 32 + (cc ^ ((r >> 2) & 7));
            const float* krow = qkv + (size_t)(s0 + r) * QKVN + NQH * HEADD + kvh * HEADD;
            ((float4*)Ks)[sw] = ((const float4*)krow)[cc];
            ((float4*)Vs)[sw] = ((const float4*)(krow + NKVH * HEADD))[cc];
        }
        __syncthreads();

        float sacc[4][4] = {};
        const int qsw = ty & 7;
        const int ksw = tx & 7;
#pragma unroll 8
        for (int k4 = 0; k4 < 32; ++k4) {
            float4 qv[4], kv[4];
#pragma unroll
            for (int i = 0; i < 4; ++i)
                qv[i] = ((const float4*)Qs)[(4 * ty + i) * 32 + (k4 ^ qsw)];
#pragma unroll
            for (int j = 0; j < 4; ++j)
                kv[j] = ((const float4*)Ks)[(4 * tx + j) * 32 + (k4 ^ ksw)];
#pragma unroll
            for (int i = 0; i < 4; ++i)
#pragma unroll
                for (int j = 0; j < 4; ++j)
                    sacc[i][j] += qv[i].x * kv[j].x + qv[i].y * kv[j].y +
                                  qv[i].z * kv[j].z + qv[i].w * kv[j].w;
        }

        const bool diag = (kt == qt);
#pragma unroll
        for (int i = 0; i < 4; ++i) {
            float rm = -1e30f;
#pragma unroll
            for (int j = 0; j < 4; ++j) {
                float s = sacc[i][j] * scale;
                if (diag && (4 * tx + j) > (4 * ty + i)) s = -1e30f;
                sacc[i][j] = s;
                rm = fmaxf(rm, s);
            }
            rm = fmaxf(rm, __shfl_xor(rm, 1));
            rm = fmaxf(rm, __shfl_xor(rm, 2));
            rm = fmaxf(rm, __shfl_xor(rm, 4));
            rm = fmaxf(rm, __shfl_xor(rm, 8));
            float mnew  = fmaxf(m_i[i], rm);
            float alpha = __expf(m_i[i] - mnew);
            float4 p4;
            p4.x = __expf(sacc[i][0] - mnew);
            p4.y = __expf(sacc[i][1] - mnew);
            p4.z = __expf(sacc[i][2] - mnew);
            p4.w = __expf(sacc[i][3] - mnew);
            float rs = p4.x + p4.y + p4.z + p4.w;
            rs += __shfl_xor(rs, 1);
            rs += __shfl_xor(rs, 2);
            rs += __shfl_xor(rs, 4);
            rs += __shfl_xor(rs, 8);
            l_i[i] = l_i[i] * alpha + rs;
            m_i[i] = mnew;
            ((float4*)Ps)[(4 * ty + i) * 17 + tx] = p4;
            if (tx == 0) aL[4 * ty + i] = alpha;
        }
        __syncthreads();

#pragma unroll
        for (int i = 0; i < 8; ++i) {
            float a = aL[ty3 * 8 + i];
#pragma unroll
            for (int c = 0; c < 4; ++c) oacc[i][c] *= a;
        }
#pragma unroll 2
        for (int s4 = 0; s4 < 16; ++s4) {
            float4 p4[8];
#pragma unroll
            for (int i = 0; i < 8; ++i)
                p4[i] = ((const float4*)Ps)[(ty3 * 8 + i) * 17 + s4];
#pragma unroll
            for (int q = 0; q < 4; ++q) {
                int s = 4 * s4 + q;
                float4 v4 = ((const float4*)Vs)[s * 32 + (tx5 ^ ((s >> 2) & 7))];
#pragma unroll
                for (int i = 0; i < 8; ++i) {
                    float p = (q == 0) ? p4[i].x : (q == 1) ? p4[i].y
                            : (q == 2) ? p4[i].z : p4[i].w;
                    oacc[i][0] = fmaf(p, v4.x, oacc[i][0]);
                    oacc[i][1] = fmaf(p, v4.y, oacc[i][1]);
                    oacc[i][2] = fmaf(p, v4.z, oacc[i][2]);
                    oacc[i][3] = fmaf(p, v4.w, oacc[i][3]);
                }
            }
        }
        __syncthreads();
    }

    if (tx == 0) {
#pragma unroll
        for (int i = 0; i < 4; ++i) lL[4 * ty + i] = 1.f / l_i[i];
    }
    __syncthreads();
#pragma unroll
    for (int i = 0; i < 8; ++i) {
        int r = ty3 * 8 + i;
        float inv = lL[r];
        ushort4 o;
        o.x = f2bf(oacc[i][0] * inv);
        o.y = f2bf(oacc[i][1] * inv);
        o.z = f2bf(oacc[i][2] * inv);
        o.w = f2bf(oacc[i][3] * inv);
        *(ushort4*)(ctx + (size_t)(q0 + r) * (NQH * HEADD) + h * HEADD + tx5 * 4) = o;
    }
}

// ---------------------------------------------------------------------------
// Router logits: per-token block; logits[t][e] = x2f[t] . gate_w[:,e]
// ---------------------------------------------------------------------------
__global__ __launch_bounds__(256) void router_logits_kernel(
    const float* __restrict__ x2f, const float* __restrict__ gate_w,
    float* __restrict__ logits)
{
    int t = blockIdx.x;
    int tid = threadIdx.x;
    const float4* xr = (const float4*)(x2f + (size_t)t * HD);
    float4 xa = xr[tid * 2], xb = xr[tid * 2 + 1];
    float xs[8] = {xa.x, xa.y, xa.z, xa.w, xb.x, xb.y, xb.z, xb.w};
    float acc[16] = {};
    int kbase = tid * 8;
#pragma unroll
    for (int j = 0; j < 8; ++j) {
        float xv = xs[j];
        const float4* wrow = (const float4*)(gate_w + (size_t)(kbase + j) * NEXP);
        float4 w0 = wrow[0], w1 = wrow[1], w2 = wrow[2], w3 = wrow[3];
        acc[0] += xv * w0.x;  acc[1] += xv * w0.y;  acc[2] += xv * w0.z;  acc[3] += xv * w0.w;
        acc[4] += xv * w1.x;  acc[5] += xv * w1.y;  acc[6] += xv * w1.z;  acc[7] += xv * w1.w;
        acc[8] += xv * w2.x;  acc[9] += xv * w2.y;  acc[10] += xv * w2.z; acc[11] += xv * w2.w;
        acc[12] += xv * w3.x; acc[13] += xv * w3.y; acc[14] += xv * w3.z; acc[15] += xv * w3.w;
    }
    __shared__ float red2[4][16];
    int lane = tid & 63, wv = tid >> 6;
#pragma unroll
    for (int e = 0; e < 16; ++e) {
        float v = acc[e];
        v += __shfl_xor(v, 1);
        v += __shfl_xor(v, 2);
        v += __shfl_xor(v, 4);
        v += __shfl_xor(v, 8);
        v += __shfl_xor(v, 16);
        v += __shfl_xor(v, 32);
        if (lane == 0) red2[wv][e] = v;
    }
    __syncthreads();
    if (tid < 16)
        logits[(size_t)t * NEXP + tid] =
            red2[0][tid] + red2[1][tid] + red2[2][tid] + red2[3][tid];
}

// ---------------------------------------------------------------------------
// Router top-k -> comb (T,16)
// ---------------------------------------------------------------------------
__global__ void router_kernel(const float* __restrict__ logits,
                              float* __restrict__ comb, int T)
{
    int t = blockIdx.x * blockDim.x + threadIdx.x;
    if (t >= T) return;
    float l[NEXP];
#pragma unroll
    for (int e = 0; e < NEXP; ++e) l[e] = logits[t * NEXP + e];

    int sel[TOPK];
    float selv[TOPK];
    bool used[NEXP] = {};
#pragma unroll
    for (int r = 0; r < TOPK; ++r) {
        int best = -1;
        float bv = -1e30f;
        for (int e = 0; e < NEXP; ++e) {
            if (!used[e] && l[e] > bv) { bv = l[e]; best = e; }
        }
        used[best] = true;
        sel[r] = best;
        selv[r] = bv;
    }
    float mx = selv[0];
    float wsum = 0.f, wv[TOPK];
#pragma unroll
    for (int r = 0; r < TOPK; ++r) { wv[r] = __expf(selv[r] - mx); wsum += wv[r]; }
    float out16[NEXP] = {};
#pragma unroll
    for (int r = 0; r < TOPK; ++r) out16[sel[r]] = wv[r] / wsum;
#pragma unroll
    for (int e = 0; e < NEXP; ++e) comb[t * NEXP + e] = out16[e];
}

// ---------------------------------------------------------------------------
// SwiGLU (shared): sact(bf16)[t][i] = silu(gu[t][i]) * gu[t][SSI+i]
// ---------------------------------------------------------------------------
__global__ void silu_mul_kernel(const float* __restrict__ gu,
                                unsigned short* __restrict__ out, int T, int I)
{
    size_t n = (size_t)T * I;
    for (size_t idx = (size_t)blockIdx.x * blockDim.x + threadIdx.x; idx < n;
         idx += (size_t)gridDim.x * blockDim.x) {
        size_t t = idx / I;
        int i = (int)(idx % I);
        float g = gu[t * 2 * I + i];
        float u = gu[t * 2 * I + I + i];
        out[idx] = f2bf((g / (1.f + __expf(-g))) * u);
    }
}

// ---------------------------------------------------------------------------
// Expert SwiGLU weighted by comb -> act (bf16) [t][e*EI+i]
// ---------------------------------------------------------------------------
__global__ void silu_mul_moe_kernel(const float* __restrict__ gu,
                                    const float* __restrict__ comb, int e0, int G,
                                    unsigned short* __restrict__ act, int T)
{
    size_t n = (size_t)G * T * EI;
    for (size_t idx = (size_t)blockIdx.x * blockDim.x + threadIdx.x; idx < n;
         idx += (size_t)gridDim.x * blockDim.x) {
        int i = (int)(idx % EI);
        size_t tg = idx / EI;
        int t = (int)(tg % T);
        int g = (int)(tg / T);
        int e = e0 + g;
        size_t base = ((size_t)g * T + t) * (2 * EI);
        float gv = gu[base + i];
        float uv = gu[base + EI + i];
        float s = (gv / (1.f + __expf(-gv))) * uv * comb[t * NEXP + e];
        act[(size_t)t * (NEXP * EI) + e * EI + i] = f2bf(s);
    }
}

// ---------------------------------------------------------------------------
extern "C" void kernel_launch(void* const* d_in, const int* in_sizes, int n_in,
                              void* d_out, int out_size, void* d_ws, size_t ws_size,
                              hipStream_t stream)
{
    const float* hidden   = (const float*)d_in[0];
    const float* residual = (const float*)d_in[1];
    const float* rms1_w   = (const float*)d_in[2];
    const float* rms2_w   = (const float*)d_in[3];
    const float* w_qkv    = (const float*)d_in[4];
    const float* w_dense  = (const float*)d_in[5];
    const float* gate_w   = (const float*)d_in[6];
    const float* w13      = (const float*)d_in[7];
    const float* w2       = (const float*)d_in[8];
    const float* sw13     = (const float*)d_in[9];
    const float* sw2      = (const float*)d_in[10];
    const int*   pos_ids  = (const int*)d_in[11];

    const int T = TT;

    float* out0 = (float*)d_out;
    float* out1 = (float*)d_out + (size_t)T * HD;

    // ---- workspace layout (256B-aligned regions) ----
    char* p = (char*)d_ws;
    auto alloc = [&](size_t bytes) {
        char* r = p;
        p += (bytes + 255) & ~(size_t)255;
        return r;
    };
    float* residF = (float*)alloc((size_t)T * HD * 4);
    float* x2F    = (float*)alloc((size_t)T * HD * 4);
    float* qkvF   = (float*)alloc((size_t)T * QKVN * 4);    // reused as guF
    unsigned short* xB    = (unsigned short*)alloc((size_t)T * HD * 2);
    unsigned short* ctxB  = (unsigned short*)alloc((size_t)T * HD * 2);
    unsigned short* x2B   = (unsigned short*)alloc((size_t)T * HD * 2);
    unsigned short* sactB = (unsigned short*)alloc((size_t)T * SSI * 2);
    unsigned short* actB  = (unsigned short*)alloc((size_t)T * NEXP * EI * 2);
    float* logits = (float*)alloc((size_t)T * NEXP * 4);
    float* comb   = (float*)alloc((size_t)T * NEXP * 4);
    unsigned short* wqkvT   = (unsigned short*)alloc((size_t)QKVN * HD * 2);
    unsigned short* wdenseT = (unsigned short*)alloc((size_t)HD * HD * 2);
    unsigned short* sw13T   = (unsigned short*)alloc((size_t)HD * HD * 2);
    unsigned short* sw2T    = (unsigned short*)alloc((size_t)HD * SSI * 2);
    unsigned short* w2T     = (unsigned short*)alloc((size_t)HD * NEXP * EI * 2);
    unsigned short* w13Tg   = (unsigned short*)alloc((size_t)4 * 1024 * HD * 2);
    // expert gu group (f32, 16.78MB) aliases the wqkvT+wdenseT region (20.97MB),
    // both dead before the expert phase.
    float* eguF = (float*)wqkvT;

    float* guF = qkvF;  // shared-expert gu reuses qkv buffer (dead after attn)

    dim3 blk(256);

    // ---- weight transpose+convert (per launch, deterministic) ----
    transpose_convert<<<dim3(QKVN / 32, HD / 32), blk, 0, stream>>>(
        w_qkv, wqkvT, HD, QKVN, 0, 0);
    transpose_convert<<<dim3(HD / 32, HD / 32), blk, 0, stream>>>(
        w_dense, wdenseT, HD, HD, 0, 0);
    transpose_convert<<<dim3(HD / 32, HD / 32), blk, 0, stream>>>(
        sw13, sw13T, HD, HD, 0, 0);
    transpose_convert<<<dim3(HD / 32, SSI / 32), blk, 0, stream>>>(
        sw2, sw2T, SSI, HD, 0, 0);
    transpose_convert<<<dim3(HD / 32, (NEXP * EI) / 32), blk, 0, stream>>>(
        w2, w2T, NEXP * EI, HD, 0, 0);

    // 1. resid = hidden + residual ; x = rmsnorm -> bf16
    add_rmsnorm_kernel<<<dim3(T), blk, 0, stream>>>(
        hidden, residual, rms1_w, residF, xB, nullptr);

    // 2. qkv = x @ w_qkv
    gemm_bf16<<<dim3(QKVN / GBN, T / GBM), blk, 0, stream>>>(
        xB, wqkvT, qkvF, T, QKVN, HD, 0, 0, nullptr, 0);

    // 3. RoPE
    rope_kernel<<<dim3(NQH + NKVH, T), dim3(64), 0, stream>>>(qkvF, pos_ids);

    // 4. flash attention -> ctx (bf16)
    flash_attn_kernel<<<dim3(NQH, T / QT), blk, 0, stream>>>(qkvF, ctxB);

    // 5. resid2 = ctx @ w_dense + resid -> out1
    gemm_bf16<<<dim3(HD / GBN, T / GBM), blk, 0, stream>>>(
        ctxB, wdenseT, out1, T, HD, HD, 0, 0, residF, 0);

    // 6. x2 = rmsnorm(resid2)
    add_rmsnorm_kernel<<<dim3(T), blk, 0, stream>>>(
        out1, nullptr, rms2_w, nullptr, x2B, x2F);

    // 7. router logits (f32)
    router_logits_kernel<<<dim3(T), blk, 0, stream>>>(x2F, gate_w, logits);

    // 8. top-k -> comb
    router_kernel<<<dim3((T + 255) / 256), blk, 0, stream>>>(logits, comb, T);

    // 9. shared gu = x2 @ sw13
    gemm_bf16<<<dim3(2 * SSI / GBN, T / GBM), blk, 0, stream>>>(
        x2B, sw13T, guF, T, 2 * SSI, HD, 0, 0, nullptr, 0);

    // 10. shared act (bf16)
    silu_mul_kernel<<<dim3(2048), blk, 0, stream>>>(guF, sactB, T, SSI);

    // 11. out0 = shared_act @ sw2
    gemm_bf16<<<dim3(HD / GBN, T / GBM), blk, 0, stream>>>(
        sactB, sw2T, out0, T, HD, SSI, 0, 0, nullptr, 0);

    // 12. experts, 4 at a time
    for (int g = 0; g < 4; ++g) {
        int e0 = g * 4;
        transpose_convert<<<dim3(1024 / 32, HD / 32, 4), blk, 0, stream>>>(
            w13 + (size_t)e0 * HD * 1024, w13Tg, HD, 1024,
            (long long)HD * 1024, (long long)HD * 1024);
        gemm_bf16<<<dim3(1024 / GBN, T / GBM, 4), blk, 0, stream>>>(
            x2B, w13Tg, eguF, T, 1024, HD,
            (long long)1024 * HD, (long long)T * 1024, nullptr, 0);
        silu_mul_moe_kernel<<<dim3(2048), blk, 0, stream>>>(
            eguF, comb, e0, 4, actB, T);
    }

    // 13. out0 += act @ w2
    gemm_bf16<<<dim3(HD / GBN, T / GBM), blk, 0, stream>>>(
        actB, w2T, out0, T, HD, NEXP * EI, 0, 0, nullptr, 1);
}

// Round 4
// 577.308 us; speedup vs baseline: 13.0992x; 1.6263x over previous
//
#include <hip/hip_runtime.h>
#include <math.h>

// ---------------------------------------------------------------------------
// Problem constants
// ---------------------------------------------------------------------------
#define HD 2048      // hidden size h
#define NQH 16       // num q heads
#define NKVH 4       // num kv heads
#define HEADD 128    // head dim
#define QKVN 3072    // qkv cols
#define NEXP 16      // experts
#define EI 512       // expert intermediate
#define SSI 1024     // shared intermediate
#define TOPK 4
#define TT 1024      // tokens

typedef __bf16 bf16x8 __attribute__((ext_vector_type(8)));
typedef float f32x4 __attribute__((ext_vector_type(4)));

static __device__ __forceinline__ unsigned short f2bf(float f) {
    union { float f; unsigned int u; } v; v.f = f;
    unsigned int r = v.u + 0x7fff + ((v.u >> 16) & 1);
    return (unsigned short)(r >> 16);
}

static __device__ __forceinline__ void gl_lds16(const unsigned short* g,
                                                unsigned short* l) {
    __builtin_amdgcn_global_load_lds(
        (const __attribute__((address_space(1))) unsigned int*)g,
        (__attribute__((address_space(3))) unsigned int*)l, 16, 0, 0);
}

// ---------------------------------------------------------------------------
// Fused add + RMSNorm. resid_out(f32 opt) ; x_bf (bf16)
// ---------------------------------------------------------------------------
__global__ __launch_bounds__(256) void add_rmsnorm_kernel(
    const float* __restrict__ a, const float* __restrict__ b,
    const float* __restrict__ w, float* __restrict__ resid_out,
    unsigned short* __restrict__ x_bf)
{
    int t = blockIdx.x;
    int tid = threadIdx.x;
    const float4* a4 = (const float4*)(a + (size_t)t * HD);
    const float4* b4 = b ? (const float4*)(b + (size_t)t * HD) : nullptr;
    float4* r4 = resid_out ? (float4*)(resid_out + (size_t)t * HD) : nullptr;
    const float4* w4 = (const float4*)w;

    float4 v[2];
    float ss = 0.f;
#pragma unroll
    for (int l = 0; l < 2; ++l) {
        int idx = tid + l * 256;
        float4 va = a4[idx];
        if (b4) {
            float4 vb = b4[idx];
            va.x += vb.x; va.y += vb.y; va.z += vb.z; va.w += vb.w;
        }
        if (r4) r4[idx] = va;
        v[l] = va;
        ss += va.x * va.x + va.y * va.y + va.z * va.z + va.w * va.w;
    }
    for (int off = 32; off > 0; off >>= 1) ss += __shfl_down(ss, off);
    __shared__ float red[4];
    int lane = tid & 63, wv = tid >> 6;
    if (lane == 0) red[wv] = ss;
    __syncthreads();
    if (tid == 0) {
        float s = red[0] + red[1] + red[2] + red[3];
        red[0] = rsqrtf(s / (float)HD + 1e-6f);
    }
    __syncthreads();
    float inv = red[0];
#pragma unroll
    for (int l = 0; l < 2; ++l) {
        int idx = tid + l * 256;
        float4 va = v[l], vw = w4[idx];
        ushort4 ob;
        ob.x = f2bf(va.x * inv * vw.x);
        ob.y = f2bf(va.y * inv * vw.y);
        ob.z = f2bf(va.z * inv * vw.z);
        ob.w = f2bf(va.w * inv * vw.w);
        ((ushort4*)(x_bf + (size_t)t * HD))[idx] = ob;
    }
}

// ---------------------------------------------------------------------------
// Transpose + convert: f32 in [K][N] -> bf16 out [N][K]   (per-z strides)
// ---------------------------------------------------------------------------
__global__ __launch_bounds__(256) void transpose_convert(
    const float* __restrict__ in, unsigned short* __restrict__ out,
    int K, int N, long long strideIn, long long strideOut)
{
    __shared__ float tile[32][33];
    const int n0 = blockIdx.x * 32;
    const int k0 = blockIdx.y * 32;
    const float* ip = in + (size_t)blockIdx.z * strideIn;
    unsigned short* op = out + (size_t)blockIdx.z * strideOut;
    int tid = threadIdx.x;
    int r = tid >> 3, c = (tid & 7) * 4;
    float4 v = *(const float4*)(ip + (size_t)(k0 + r) * N + n0 + c);
    tile[r][c] = v.x; tile[r][c + 1] = v.y; tile[r][c + 2] = v.z; tile[r][c + 3] = v.w;
    __syncthreads();
    ushort4 o;
    o.x = f2bf(tile[c + 0][r]);
    o.y = f2bf(tile[c + 1][r]);
    o.z = f2bf(tile[c + 2][r]);
    o.w = f2bf(tile[c + 3][r]);
    *(ushort4*)(op + (size_t)(n0 + r) * K + k0 + c) = o;
}

// ---------------------------------------------------------------------------
// Split-K bf16 MFMA GEMM, STAGE-early double-buffered, BK=64.
// C_part[z] = A[M, z*Kc : (z+1)*Kc] @ B^T[N, z*Kc : (z+1)*Kc]
// grid (N/128, M/128, NS).  LDS source-pre-swizzled (chunk ^= row&7).
// ---------------------------------------------------------------------------
#define SBK 64

__global__ __launch_bounds__(256) void gemm_splitk(
    const unsigned short* __restrict__ A, const unsigned short* __restrict__ B,
    float* __restrict__ Cpart, int M, int N, int Kc, int ldA, int ldB)
{
    __shared__ unsigned short As[2][128 * SBK];
    __shared__ unsigned short Bs[2][128 * SBK];

    const int tid = threadIdx.x;
    const int wave = tid >> 6;
    const int lane = tid & 63;
    const int wr = wave >> 1, wc = wave & 1;
    const int l15 = lane & 15;
    const int row0 = blockIdx.y * 128;
    const int col0 = blockIdx.x * 128;
    const int z = blockIdx.z;

    const unsigned short* Ap = A + (size_t)row0 * ldA + (size_t)z * Kc;
    const unsigned short* Bp = B + (size_t)col0 * ldB + (size_t)z * Kc;

    // staging: lane -> (row=tid>>3, chunk=tid&7); dest lane-linear (tid*16B)
    const int r_st = tid >> 3;
    const int q_st = tid & 7;
    const int csrc = (q_st ^ (r_st & 7)) << 3;   // inverse-swizzled source col

    f32x4 acc[4][4] = {};

    const int nsteps = Kc / SBK;

#define STAGE_SK(buf, k0s)                                                    \
    {                                                                         \
        _Pragma("unroll")                                                     \
        for (int i = 0; i < 4; ++i) {                                         \
            int rr = r_st + i * 32;                                           \
            gl_lds16(Ap + (size_t)rr * ldA + (k0s) + csrc,                    \
                     &As[buf][rr * SBK + q_st * 8]);                          \
            gl_lds16(Bp + (size_t)rr * ldB + (k0s) + csrc,                    \
                     &Bs[buf][rr * SBK + q_st * 8]);                          \
        }                                                                     \
    }

    STAGE_SK(0, 0);
    __syncthreads();

    for (int s = 0; s < nsteps; ++s) {
        const int cur = s & 1;
        if (s + 1 < nsteps) STAGE_SK(cur ^ 1, (s + 1) * SBK);

#pragma unroll
        for (int half = 0; half < 2; ++half) {
            const int q = half * 4 + (lane >> 4);   // logical chunk 0..7
            bf16x8 af[4], bfv[4];
#pragma unroll
            for (int i = 0; i < 4; ++i) {
                int R = wr * 64 + i * 16 + l15;
                af[i] = *(const bf16x8*)&As[cur][R * SBK + ((q ^ (R & 7)) << 3)];
            }
#pragma unroll
            for (int j = 0; j < 4; ++j) {
                int R = wc * 64 + j * 16 + l15;
                bfv[j] = *(const bf16x8*)&Bs[cur][R * SBK + ((q ^ (R & 7)) << 3)];
            }
#pragma unroll
            for (int mi = 0; mi < 4; ++mi)
#pragma unroll
                for (int nj = 0; nj < 4; ++nj)
                    acc[mi][nj] = __builtin_amdgcn_mfma_f32_16x16x32_bf16(
                        af[mi], bfv[nj], acc[mi][nj], 0, 0, 0);
        }
        __syncthreads();
    }

    float* Cp = Cpart + (size_t)z * M * N;
#pragma unroll
    for (int mi = 0; mi < 4; ++mi)
#pragma unroll
        for (int nj = 0; nj < 4; ++nj)
#pragma unroll
            for (int r = 0; r < 4; ++r) {
                int row = row0 + wr * 64 + mi * 16 + (lane >> 4) * 4 + r;
                int col = col0 + wc * 64 + nj * 16 + l15;
                Cp[(size_t)row * N + col] = acc[mi][nj][r];
            }
}

// ---------------------------------------------------------------------------
// Reduce split-K partials: out = sum_z part[z] (+ add) (+= out if acc)
// ---------------------------------------------------------------------------
__global__ __launch_bounds__(256) void reduce_partials(
    const float* __restrict__ part, int ns, int n4,
    const float* __restrict__ add, float* __restrict__ out, int acc)
{
    const float4* p4 = (const float4*)part;
    const float4* a4 = (const float4*)add;
    float4* o4 = (float4*)out;
    for (int idx = blockIdx.x * 256 + threadIdx.x; idx < n4;
         idx += gridDim.x * 256) {
        float4 s = p4[idx];
        for (int z = 1; z < ns; ++z) {
            float4 q = p4[(size_t)z * n4 + idx];
            s.x += q.x; s.y += q.y; s.z += q.z; s.w += q.w;
        }
        if (add) {
            float4 q = a4[idx];
            s.x += q.x; s.y += q.y; s.z += q.z; s.w += q.w;
        }
        if (acc) {
            float4 q = o4[idx];
            s.x += q.x; s.y += q.y; s.z += q.z; s.w += q.w;
        }
        o4[idx] = s;
    }
}

// ---------------------------------------------------------------------------
// MoE expert-up + fused SwiGLU + comb weighting.
// grid (EI/128=4, T/128=8, 16).  A=x2B, B=w13T[e] ([1024][2048], rows 0..511
// gate, 512..1023 up).  Writes actB[t][e*512+n] = silu(g)*u*comb[t][e]  (bf16)
// BK=32, double-buffered, source-pre-swizzled (chunk ^= row&3).
// ---------------------------------------------------------------------------
__global__ __launch_bounds__(256) void moe_up_swiglu(
    const unsigned short* __restrict__ x2B,
    const unsigned short* __restrict__ w13T,
    const float* __restrict__ comb,
    unsigned short* __restrict__ actB)
{
    __shared__ unsigned short As[2][128 * 32];
    __shared__ unsigned short Bgs[2][128 * 32];
    __shared__ unsigned short Bus[2][128 * 32];

    const int tid = threadIdx.x;
    const int wave = tid >> 6;
    const int lane = tid & 63;
    const int wr = wave >> 1, wc = wave & 1;
    const int l15 = lane & 15;
    const int e  = blockIdx.z;
    const int n0 = blockIdx.x * 128;
    const int m0 = blockIdx.y * 128;

    const unsigned short* Ap = x2B + (size_t)m0 * HD;
    const unsigned short* Bg = w13T + (size_t)e * 1024 * HD + (size_t)n0 * HD;
    const unsigned short* Bu = Bg + (size_t)512 * HD;

    const int r_st = tid >> 2;          // 0..63
    const int q_st = tid & 3;           // chunk 0..3

    f32x4 accg[4][4] = {};
    f32x4 accu[4][4] = {};

#define STAGE_MOE(buf, k0s)                                                   \
    {                                                                         \
        _Pragma("unroll")                                                     \
        for (int i = 0; i < 2; ++i) {                                         \
            int rr = r_st + i * 64;                                           \
            int cs = (k0s) + ((q_st ^ (rr & 3)) << 3);                        \
            gl_lds16(Ap + (size_t)rr * HD + cs, &As[buf][rr * 32 + q_st * 8]);\
            gl_lds16(Bg + (size_t)rr * HD + cs, &Bgs[buf][rr * 32 + q_st * 8]);\
            gl_lds16(Bu + (size_t)rr * HD + cs, &Bus[buf][rr * 32 + q_st * 8]);\
        }                                                                     \
    }

    STAGE_MOE(0, 0);
    __syncthreads();

    const int nsteps = HD / 32;
    for (int s = 0; s < nsteps; ++s) {
        const int cur = s & 1;
        if (s + 1 < nsteps) STAGE_MOE(cur ^ 1, (s + 1) * 32);

        const int q = lane >> 4;  // logical chunk 0..3
        bf16x8 af[4], bg[4], bu[4];
#pragma unroll
        for (int i = 0; i < 4; ++i) {
            int R = wr * 64 + i * 16 + l15;
            int off = R * 32 + ((q ^ (R & 3)) << 3);
            af[i] = *(const bf16x8*)&As[cur][off];
        }
#pragma unroll
        for (int j = 0; j < 4; ++j) {
            int R = wc * 64 + j * 16 + l15;
            int off = R * 32 + ((q ^ (R & 3)) << 3);
            bg[j] = *(const bf16x8*)&Bgs[cur][off];
            bu[j] = *(const bf16x8*)&Bus[cur][off];
        }
#pragma unroll
        for (int mi = 0; mi < 4; ++mi)
#pragma unroll
            for (int nj = 0; nj < 4; ++nj) {
                accg[mi][nj] = __builtin_amdgcn_mfma_f32_16x16x32_bf16(
                    af[mi], bg[nj], accg[mi][nj], 0, 0, 0);
                accu[mi][nj] = __builtin_amdgcn_mfma_f32_16x16x32_bf16(
                    af[mi], bu[nj], accu[mi][nj], 0, 0, 0);
            }
        __syncthreads();
    }

    // comb weight per output row
    float cw[4][4];
#pragma unroll
    for (int mi = 0; mi < 4; ++mi)
#pragma unroll
        for (int r = 0; r < 4; ++r) {
            int row = m0 + wr * 64 + mi * 16 + (lane >> 4) * 4 + r;
            cw[mi][r] = comb[(size_t)row * NEXP + e];
        }

#pragma unroll
    for (int mi = 0; mi < 4; ++mi)
#pragma unroll
        for (int nj = 0; nj < 4; ++nj)
#pragma unroll
            for (int r = 0; r < 4; ++r) {
                int row = m0 + wr * 64 + mi * 16 + (lane >> 4) * 4 + r;
                int col = n0 + wc * 64 + nj * 16 + l15;
                float g = accg[mi][nj][r];
                float u = accu[mi][nj][r];
                float v = (g / (1.f + __expf(-g))) * u * cw[mi][r];
                actB[(size_t)row * (NEXP * EI) + e * EI + col] = f2bf(v);
            }
}

// ---------------------------------------------------------------------------
// NeoX RoPE in-place (f32 qkv).  grid (20, T), block 64.
// ---------------------------------------------------------------------------
__global__ void rope_kernel(float* __restrict__ qkv,
                            const int* __restrict__ pos_ids)
{
    int head = blockIdx.x;
    int t = blockIdx.y;
    int i = threadIdx.x;
    float* base = qkv + (size_t)t * QKVN +
                  (head < NQH ? head * HEADD : NQH * HEADD + (head - NQH) * HEADD);
    float pos = (float)pos_ids[t];
    float inv_freq = powf(10000.0f, -(2.0f * (float)i) / (float)HEADD);
    float ang = pos * inv_freq;
    float c = cosf(ang);
    float s = sinf(ang);
    float x1 = base[i];
    float x2 = base[i + 64];
    base[i] = x1 * c - x2 * s;
    base[i + 64] = x2 * c + x1 * s;
}

// ---------------------------------------------------------------------------
// Flash attention (fp32 VALU), output bf16 ctx.  grid (NQH, T/64), 256 thr.
// ---------------------------------------------------------------------------
#define QT 64
#define KT 64

__global__ __launch_bounds__(256) void flash_attn_kernel(
    const float* __restrict__ qkv, unsigned short* __restrict__ ctx)
{
    __shared__ float Qs[QT * HEADD];
    __shared__ float Ks[KT * HEADD];
    __shared__ float Vs[KT * HEADD];
    __shared__ float Ps[QT * 68];
    __shared__ float aL[QT];
    __shared__ float lL[QT];

    const int h   = blockIdx.x;
    const int qt  = blockIdx.y;
    const int q0  = qt * QT;
    const int kvh = h >> 2;
    const int tid = threadIdx.x;

    const int tx  = tid & 15, ty  = tid >> 4;
    const int tx5 = tid & 31, ty3 = tid >> 5;

#pragma unroll
    for (int l = 0; l < 8; ++l) {
        int idx = tid + l * 256;
        int r = idx >> 5, cc = idx & 31;
        float4 v = ((const float4*)(qkv + (size_t)(q0 + r) * QKVN + h * HEADD))[cc];
        ((float4*)Qs)[r * 32 + (cc ^ ((r >> 2) & 7))] = v;
    }

    float m_i[4], l_i[4];
#pragma unroll
    for (int i = 0; i < 4; ++i) { m_i[i] = -1e30f; l_i[i] = 0.f; }
    float oacc[8][4] = {};

    const float scale = 0.08838834764831843f;
    __syncthreads();

    for (int kt = 0; kt <= qt; ++kt) {
        const int s0 = kt * KT;
#pragma unroll
        for (int l = 0; l < 8; ++l) {
            int idx = tid + l * 256;
            int r = idx >> 5, cc = idx & 31;
            int sw = r * 32 + (cc ^ ((r >> 2) & 7));
            const float* krow = qkv + (size_t)(s0 + r) * QKVN + NQH * HEADD + kvh * HEADD;
            ((float4*)Ks)[sw] = ((const float4*)krow)[cc];
            ((float4*)Vs)[sw] = ((const float4*)(krow + NKVH * HEADD))[cc];
        }
        __syncthreads();

        float sacc[4][4] = {};
        const int qsw = ty & 7;
        const int ksw = tx & 7;
#pragma unroll 8
        for (int k4 = 0; k4 < 32; ++k4) {
            float4 qv[4], kv[4];
#pragma unroll
            for (int i = 0; i < 4; ++i)
                qv[i] = ((const float4*)Qs)[(4 * ty + i) * 32 + (k4 ^ qsw)];
#pragma unroll
            for (int j = 0; j < 4; ++j)
                kv[j] = ((const float4*)Ks)[(4 * tx + j) * 32 + (k4 ^ ksw)];
#pragma unroll
            for (int i = 0; i < 4; ++i)
#pragma unroll
                for (int j = 0; j < 4; ++j)
                    sacc[i][j] += qv[i].x * kv[j].x + qv[i].y * kv[j].y +
                                  qv[i].z * kv[j].z + qv[i].w * kv[j].w;
        }

        const bool diag = (kt == qt);
#pragma unroll
        for (int i = 0; i < 4; ++i) {
            float rm = -1e30f;
#pragma unroll
            for (int j = 0; j < 4; ++j) {
                float s = sacc[i][j] * scale;
                if (diag && (4 * tx + j) > (4 * ty + i)) s = -1e30f;
                sacc[i][j] = s;
                rm = fmaxf(rm, s);
            }
            rm = fmaxf(rm, __shfl_xor(rm, 1));
            rm = fmaxf(rm, __shfl_xor(rm, 2));
            rm = fmaxf(rm, __shfl_xor(rm, 4));
            rm = fmaxf(rm, __shfl_xor(rm, 8));
            float mnew  = fmaxf(m_i[i], rm);
            float alpha = __expf(m_i[i] - mnew);
            float4 p4;
            p4.x = __expf(sacc[i][0] - mnew);
            p4.y = __expf(sacc[i][1] - mnew);
            p4.z = __expf(sacc[i][2] - mnew);
            p4.w = __expf(sacc[i][3] - mnew);
            float rs = p4.x + p4.y + p4.z + p4.w;
            rs += __shfl_xor(rs, 1);
            rs += __shfl_xor(rs, 2);
            rs += __shfl_xor(rs, 4);
            rs += __shfl_xor(rs, 8);
            l_i[i] = l_i[i] * alpha + rs;
            m_i[i] = mnew;
            ((float4*)Ps)[(4 * ty + i) * 17 + tx] = p4;
            if (tx == 0) aL[4 * ty + i] = alpha;
        }
        __syncthreads();

#pragma unroll
        for (int i = 0; i < 8; ++i) {
            float a = aL[ty3 * 8 + i];
#pragma unroll
            for (int c = 0; c < 4; ++c) oacc[i][c] *= a;
        }
#pragma unroll 2
        for (int s4 = 0; s4 < 16; ++s4) {
            float4 p4[8];
#pragma unroll
            for (int i = 0; i < 8; ++i)
                p4[i] = ((const float4*)Ps)[(ty3 * 8 + i) * 17 + s4];
#pragma unroll
            for (int q = 0; q < 4; ++q) {
                int s = 4 * s4 + q;
                float4 v4 = ((const float4*)Vs)[s * 32 + (tx5 ^ ((s >> 2) & 7))];
#pragma unroll
                for (int i = 0; i < 8; ++i) {
                    float p = (q == 0) ? p4[i].x : (q == 1) ? p4[i].y
                            : (q == 2) ? p4[i].z : p4[i].w;
                    oacc[i][0] = fmaf(p, v4.x, oacc[i][0]);
                    oacc[i][1] = fmaf(p, v4.y, oacc[i][1]);
                    oacc[i][2] = fmaf(p, v4.z, oacc[i][2]);
                    oacc[i][3] = fmaf(p, v4.w, oacc[i][3]);
                }
            }
        }
        __syncthreads();
    }

    if (tx == 0) {
#pragma unroll
        for (int i = 0; i < 4; ++i) lL[4 * ty + i] = 1.f / l_i[i];
    }
    __syncthreads();
#pragma unroll
    for (int i = 0; i < 8; ++i) {
        int r = ty3 * 8 + i;
        float inv = lL[r];
        ushort4 o;
        o.x = f2bf(oacc[i][0] * inv);
        o.y = f2bf(oacc[i][1] * inv);
        o.z = f2bf(oacc[i][2] * inv);
        o.w = f2bf(oacc[i][3] * inv);
        *(ushort4*)(ctx + (size_t)(q0 + r) * (NQH * HEADD) + h * HEADD + tx5 * 4) = o;
    }
}

// ---------------------------------------------------------------------------
// Fused router: rmsnorm(resid2)*w dotted with gate_w (f32), softmax top-4,
// renormalize, scatter -> comb (T,16).  One block per token.
// ---------------------------------------------------------------------------
__global__ __launch_bounds__(256) void router_fused(
    const float* __restrict__ resid2, const float* __restrict__ w,
    const float* __restrict__ gate_w, float* __restrict__ comb)
{
    int t = blockIdx.x;
    int tid = threadIdx.x;
    int lane = tid & 63, wv = tid >> 6;

    const float4* r4 = (const float4*)(resid2 + (size_t)t * HD);
    float4 xa = r4[tid * 2], xb = r4[tid * 2 + 1];
    float ss = xa.x * xa.x + xa.y * xa.y + xa.z * xa.z + xa.w * xa.w +
               xb.x * xb.x + xb.y * xb.y + xb.z * xb.z + xb.w * xb.w;
    for (int off = 32; off > 0; off >>= 1) ss += __shfl_down(ss, off);
    __shared__ float red[4];
    if (lane == 0) red[wv] = ss;
    __syncthreads();
    float inv = rsqrtf((red[0] + red[1] + red[2] + red[3]) / (float)HD + 1e-6f);

    const float4* w4 = (const float4*)w;
    float4 wa = w4[tid * 2], wb = w4[tid * 2 + 1];
    float xs[8] = {xa.x * wa.x * inv, xa.y * wa.y * inv, xa.z * wa.z * inv,
                   xa.w * wa.w * inv, xb.x * wb.x * inv, xb.y * wb.y * inv,
                   xb.z * wb.z * inv, xb.w * wb.w * inv};

    float acc[16] = {};
    int kbase = tid * 8;
#pragma unroll
    for (int j = 0; j < 8; ++j) {
        float xv = xs[j];
        const float4* wrow = (const float4*)(gate_w + (size_t)(kbase + j) * NEXP);
        float4 w0 = wrow[0], w1 = wrow[1], w2 = wrow[2], w3 = wrow[3];
        acc[0] += xv * w0.x;  acc[1] += xv * w0.y;  acc[2] += xv * w0.z;  acc[3] += xv * w0.w;
        acc[4] += xv * w1.x;  acc[5] += xv * w1.y;  acc[6] += xv * w1.z;  acc[7] += xv * w1.w;
        acc[8] += xv * w2.x;  acc[9] += xv * w2.y;  acc[10] += xv * w2.z; acc[11] += xv * w2.w;
        acc[12] += xv * w3.x; acc[13] += xv * w3.y; acc[14] += xv * w3.z; acc[15] += xv * w3.w;
    }
    __shared__ float red2[4][16];
#pragma unroll
    for (int e = 0; e < 16; ++e) {
        float v = acc[e];
        v += __shfl_xor(v, 1);
        v += __shfl_xor(v, 2);
        v += __shfl_xor(v, 4);
        v += __shfl_xor(v, 8);
        v += __shfl_xor(v, 16);
        v += __shfl_xor(v, 32);
        if (lane == 0) red2[wv][e] = v;
    }
    __syncthreads();

    if (tid == 0) {
        float l[NEXP];
#pragma unroll
        for (int e = 0; e < NEXP; ++e)
            l[e] = red2[0][e] + red2[1][e] + red2[2][e] + red2[3][e];
        int sel[TOPK];
        float selv[TOPK];
        bool used[NEXP] = {};
#pragma unroll
        for (int r = 0; r < TOPK; ++r) {
            int best = -1;
            float bv = -1e30f;
            for (int e = 0; e < NEXP; ++e)
                if (!used[e] && l[e] > bv) { bv = l[e]; best = e; }
            used[best] = true;
            sel[r] = best;
            selv[r] = bv;
        }
        float mx = selv[0];
        float wsum = 0.f, wvv[TOPK];
#pragma unroll
        for (int r = 0; r < TOPK; ++r) { wvv[r] = __expf(selv[r] - mx); wsum += wvv[r]; }
        float out16[NEXP] = {};
#pragma unroll
        for (int r = 0; r < TOPK; ++r) out16[sel[r]] = wvv[r] / wsum;
#pragma unroll
        for (int e = 0; e < NEXP; ++e) comb[(size_t)t * NEXP + e] = out16[e];
    }
}

// ---------------------------------------------------------------------------
// SwiGLU (shared): sact(bf16)[t][i] = silu(gu[t][i]) * gu[t][SSI+i]
// ---------------------------------------------------------------------------
__global__ void silu_mul_kernel(const float* __restrict__ gu,
                                unsigned short* __restrict__ out, int T, int I)
{
    size_t n = (size_t)T * I;
    for (size_t idx = (size_t)blockIdx.x * blockDim.x + threadIdx.x; idx < n;
         idx += (size_t)gridDim.x * blockDim.x) {
        size_t t = idx / I;
        int i = (int)(idx % I);
        float g = gu[t * 2 * I + i];
        float u = gu[t * 2 * I + I + i];
        out[idx] = f2bf((g / (1.f + __expf(-g))) * u);
    }
}

// ---------------------------------------------------------------------------
extern "C" void kernel_launch(void* const* d_in, const int* in_sizes, int n_in,
                              void* d_out, int out_size, void* d_ws, size_t ws_size,
                              hipStream_t stream)
{
    const float* hidden   = (const float*)d_in[0];
    const float* residual = (const float*)d_in[1];
    const float* rms1_w   = (const float*)d_in[2];
    const float* rms2_w   = (const float*)d_in[3];
    const float* w_qkv    = (const float*)d_in[4];
    const float* w_dense  = (const float*)d_in[5];
    const float* gate_w   = (const float*)d_in[6];
    const float* w13      = (const float*)d_in[7];
    const float* w2       = (const float*)d_in[8];
    const float* sw13     = (const float*)d_in[9];
    const float* sw2      = (const float*)d_in[10];
    const int*   pos_ids  = (const int*)d_in[11];

    const int T = TT;

    float* out0 = (float*)d_out;
    float* out1 = (float*)d_out + (size_t)T * HD;

    // ---- workspace layout (total 136.4 MB; round-3's 144.8 MB passed) ----
    char* base = (char*)d_ws;
    float*          residF = (float*)(base);                    //  8.39 MB
    unsigned short* xB     = (unsigned short*)(base + 8388608); //  4.19 MB
    unsigned short* ctxB   = (unsigned short*)(base + 12582912);//  4.19 MB
    unsigned short* actB   = (unsigned short*)(base);           // 16.78 MB alias {residF,xB,ctxB}
    float*          qkvF   = (float*)(base + 16777216);         // 12.58 MB
    float*          guF    = qkvF;                              //  8.39 MB alias (qkv dead after attn)
    unsigned short* x2B    = (unsigned short*)(base + 29360128);//  4.19 MB
    unsigned short* sactB  = (unsigned short*)(base + 33554432);//  2.10 MB
    float*          comb   = (float*)(base + 35651584);         //  0.07 MB
    float*          part   = (float*)(base + 35717120);         // 33.55 MB (split-K partials, reused)
    unsigned short* Wbuf   = (unsigned short*)(base + 69271552);// 67.11 MB (weights, phase-reused)

    dim3 blk(256);

    // 1. resid = hidden + residual ; x = rmsnorm -> bf16
    add_rmsnorm_kernel<<<dim3(T), blk, 0, stream>>>(
        hidden, residual, rms1_w, residF, xB);

    // 2. qkv = x @ w_qkv   (split-K x2)
    transpose_convert<<<dim3(QKVN / 32, HD / 32), blk, 0, stream>>>(
        w_qkv, Wbuf, HD, QKVN, 0, 0);
    gemm_splitk<<<dim3(QKVN / 128, T / 128, 2), blk, 0, stream>>>(
        xB, Wbuf, part, T, QKVN, 1024, HD, HD);
    reduce_partials<<<dim3(1024), blk, 0, stream>>>(
        part, 2, T * QKVN / 4, nullptr, qkvF, 0);

    // 3. RoPE
    rope_kernel<<<dim3(NQH + NKVH, T), dim3(64), 0, stream>>>(qkvF, pos_ids);

    // 4. flash attention -> ctx (bf16)
    flash_attn_kernel<<<dim3(NQH, T / QT), blk, 0, stream>>>(qkvF, ctxB);

    // 5. resid2 = ctx @ w_dense + resid -> out1   (split-K x4)
    transpose_convert<<<dim3(HD / 32, HD / 32), blk, 0, stream>>>(
        w_dense, Wbuf, HD, HD, 0, 0);
    gemm_splitk<<<dim3(HD / 128, T / 128, 4), blk, 0, stream>>>(
        ctxB, Wbuf, part, T, HD, 512, HD, HD);
    reduce_partials<<<dim3(1024), blk, 0, stream>>>(
        part, 4, T * HD / 4, residF, out1, 0);

    // 6. x2 = rmsnorm(resid2) -> bf16
    add_rmsnorm_kernel<<<dim3(T), blk, 0, stream>>>(
        out1, nullptr, rms2_w, nullptr, x2B);

    // 7+8. fused router (rmsnorm inline, f32 logits, top-4) -> comb
    router_fused<<<dim3(T), blk, 0, stream>>>(out1, rms2_w, gate_w, comb);

    // 9. shared gu = x2 @ sw13  (split-K x4) -> guF
    transpose_convert<<<dim3(HD / 32, HD / 32), blk, 0, stream>>>(
        sw13, Wbuf, HD, 2 * SSI, 0, 0);
    gemm_splitk<<<dim3(HD / 128, T / 128, 4), blk, 0, stream>>>(
        x2B, Wbuf, part, T, 2 * SSI, 512, HD, HD);
    reduce_partials<<<dim3(1024), blk, 0, stream>>>(
        part, 4, T * 2 * SSI / 4, nullptr, guF, 0);

    // 10. shared act (bf16)
    silu_mul_kernel<<<dim3(1024), blk, 0, stream>>>(guF, sactB, T, SSI);

    // 11. out0 = shared_act @ sw2  (split-K x4)
    transpose_convert<<<dim3(HD / 32, SSI / 32), blk, 0, stream>>>(
        sw2, Wbuf, SSI, HD, 0, 0);
    gemm_splitk<<<dim3(HD / 128, T / 128, 4), blk, 0, stream>>>(
        sactB, Wbuf, part, T, HD, 256, SSI, SSI);
    reduce_partials<<<dim3(1024), blk, 0, stream>>>(
        part, 4, T * HD / 4, nullptr, out0, 0);

    // 12. expert up + fused SwiGLU*comb -> actB   (all 16 experts, z=16)
    transpose_convert<<<dim3(1024 / 32, HD / 32, NEXP), blk, 0, stream>>>(
        w13, Wbuf, HD, 1024, (long long)HD * 1024, (long long)1024 * HD);
    moe_up_swiglu<<<dim3(EI / 128, T / 128, NEXP), blk, 0, stream>>>(
        x2B, Wbuf, comb, actB);

    // 13. out0 += act @ w2   (split-K x4 over K=8192)
    transpose_convert<<<dim3(HD / 32, (NEXP * EI) / 32), blk, 0, stream>>>(
        w2, Wbuf, NEXP * EI, HD, 0, 0);
    gemm_splitk<<<dim3(HD / 128, T / 128, 4), blk, 0, stream>>>(
        actB, Wbuf, part, T, HD, 2048, NEXP * EI, NEXP * EI);
    reduce_partials<<<dim3(1024), blk, 0, stream>>>(
        part, 4, T * HD / 4, nullptr, out0, 1);
}

// Round 5
// 499.088 us; speedup vs baseline: 15.1522x; 1.1567x over previous
//
#include <hip/hip_runtime.h>
#include <math.h>

// ---------------------------------------------------------------------------
// Problem constants
// ---------------------------------------------------------------------------
#define HD 2048      // hidden size h
#define NQH 16       // num q heads
#define NKVH 4       // num kv heads
#define HEADD 128    // head dim
#define QKVN 3072    // qkv cols
#define NEXP 16      // experts
#define EI 512       // expert intermediate
#define SSI 1024     // shared intermediate
#define TOPK 4
#define TT 1024      // tokens

typedef __bf16 bf16x8 __attribute__((ext_vector_type(8)));
typedef float f32x4 __attribute__((ext_vector_type(4)));

static __device__ __forceinline__ unsigned short f2bf(float f) {
    union { float f; unsigned int u; } v; v.f = f;
    unsigned int r = v.u + 0x7fff + ((v.u >> 16) & 1);
    return (unsigned short)(r >> 16);
}

static __device__ __forceinline__ void gl_lds16(const unsigned short* g,
                                                unsigned short* l) {
    __builtin_amdgcn_global_load_lds(
        (const __attribute__((address_space(1))) unsigned int*)g,
        (__attribute__((address_space(3))) unsigned int*)l, 16, 0, 0);
}

// ---------------------------------------------------------------------------
// Fused add + RMSNorm. resid_out(f32 opt) ; x_bf (bf16)
// ---------------------------------------------------------------------------
__global__ __launch_bounds__(256) void add_rmsnorm_kernel(
    const float* __restrict__ a, const float* __restrict__ b,
    const float* __restrict__ w, float* __restrict__ resid_out,
    unsigned short* __restrict__ x_bf)
{
    int t = blockIdx.x;
    int tid = threadIdx.x;
    const float4* a4 = (const float4*)(a + (size_t)t * HD);
    const float4* b4 = b ? (const float4*)(b + (size_t)t * HD) : nullptr;
    float4* r4 = resid_out ? (float4*)(resid_out + (size_t)t * HD) : nullptr;
    const float4* w4 = (const float4*)w;

    float4 v[2];
    float ss = 0.f;
#pragma unroll
    for (int l = 0; l < 2; ++l) {
        int idx = tid + l * 256;
        float4 va = a4[idx];
        if (b4) {
            float4 vb = b4[idx];
            va.x += vb.x; va.y += vb.y; va.z += vb.z; va.w += vb.w;
        }
        if (r4) r4[idx] = va;
        v[l] = va;
        ss += va.x * va.x + va.y * va.y + va.z * va.z + va.w * va.w;
    }
    for (int off = 32; off > 0; off >>= 1) ss += __shfl_down(ss, off);
    __shared__ float red[4];
    int lane = tid & 63, wv = tid >> 6;
    if (lane == 0) red[wv] = ss;
    __syncthreads();
    if (tid == 0) {
        float s = red[0] + red[1] + red[2] + red[3];
        red[0] = rsqrtf(s / (float)HD + 1e-6f);
    }
    __syncthreads();
    float inv = red[0];
#pragma unroll
    for (int l = 0; l < 2; ++l) {
        int idx = tid + l * 256;
        float4 va = v[l], vw = w4[idx];
        ushort4 ob;
        ob.x = f2bf(va.x * inv * vw.x);
        ob.y = f2bf(va.y * inv * vw.y);
        ob.z = f2bf(va.z * inv * vw.z);
        ob.w = f2bf(va.w * inv * vw.w);
        ((ushort4*)(x_bf + (size_t)t * HD))[idx] = ob;
    }
}

// ---------------------------------------------------------------------------
// Transpose + convert: f32 in [K][N] -> bf16 out [N][K]   (per-z strides)
// ---------------------------------------------------------------------------
__global__ __launch_bounds__(256) void transpose_convert(
    const float* __restrict__ in, unsigned short* __restrict__ out,
    int K, int N, long long strideIn, long long strideOut)
{
    __shared__ float tile[32][33];
    const int n0 = blockIdx.x * 32;
    const int k0 = blockIdx.y * 32;
    const float* ip = in + (size_t)blockIdx.z * strideIn;
    unsigned short* op = out + (size_t)blockIdx.z * strideOut;
    int tid = threadIdx.x;
    int r = tid >> 3, c = (tid & 7) * 4;
    float4 v = *(const float4*)(ip + (size_t)(k0 + r) * N + n0 + c);
    tile[r][c] = v.x; tile[r][c + 1] = v.y; tile[r][c + 2] = v.z; tile[r][c + 3] = v.w;
    __syncthreads();
    ushort4 o;
    o.x = f2bf(tile[c + 0][r]);
    o.y = f2bf(tile[c + 1][r]);
    o.z = f2bf(tile[c + 2][r]);
    o.w = f2bf(tile[c + 3][r]);
    *(ushort4*)(op + (size_t)(n0 + r) * K + k0 + c) = o;
}

// ---------------------------------------------------------------------------
// Split-K bf16 MFMA GEMM, STAGE-early double-buffered, BK=64.
// ---------------------------------------------------------------------------
#define SBK 64

__global__ __launch_bounds__(256) void gemm_splitk(
    const unsigned short* __restrict__ A, const unsigned short* __restrict__ B,
    float* __restrict__ Cpart, int M, int N, int Kc, int ldA, int ldB)
{
    __shared__ unsigned short As[2][128 * SBK];
    __shared__ unsigned short Bs[2][128 * SBK];

    const int tid = threadIdx.x;
    const int wave = tid >> 6;
    const int lane = tid & 63;
    const int wr = wave >> 1, wc = wave & 1;
    const int l15 = lane & 15;
    const int row0 = blockIdx.y * 128;
    const int col0 = blockIdx.x * 128;
    const int z = blockIdx.z;

    const unsigned short* Ap = A + (size_t)row0 * ldA + (size_t)z * Kc;
    const unsigned short* Bp = B + (size_t)col0 * ldB + (size_t)z * Kc;

    const int r_st = tid >> 3;
    const int q_st = tid & 7;
    const int csrc = (q_st ^ (r_st & 7)) << 3;

    f32x4 acc[4][4] = {};

    const int nsteps = Kc / SBK;

#define STAGE_SK(buf, k0s)                                                    \
    {                                                                         \
        _Pragma("unroll")                                                     \
        for (int i = 0; i < 4; ++i) {                                         \
            int rr = r_st + i * 32;                                           \
            gl_lds16(Ap + (size_t)rr * ldA + (k0s) + csrc,                    \
                     &As[buf][rr * SBK + q_st * 8]);                          \
            gl_lds16(Bp + (size_t)rr * ldB + (k0s) + csrc,                    \
                     &Bs[buf][rr * SBK + q_st * 8]);                          \
        }                                                                     \
    }

    STAGE_SK(0, 0);
    __syncthreads();

    for (int s = 0; s < nsteps; ++s) {
        const int cur = s & 1;
        if (s + 1 < nsteps) STAGE_SK(cur ^ 1, (s + 1) * SBK);

#pragma unroll
        for (int half = 0; half < 2; ++half) {
            const int q = half * 4 + (lane >> 4);
            bf16x8 af[4], bfv[4];
#pragma unroll
            for (int i = 0; i < 4; ++i) {
                int R = wr * 64 + i * 16 + l15;
                af[i] = *(const bf16x8*)&As[cur][R * SBK + ((q ^ (R & 7)) << 3)];
            }
#pragma unroll
            for (int j = 0; j < 4; ++j) {
                int R = wc * 64 + j * 16 + l15;
                bfv[j] = *(const bf16x8*)&Bs[cur][R * SBK + ((q ^ (R & 7)) << 3)];
            }
#pragma unroll
            for (int mi = 0; mi < 4; ++mi)
#pragma unroll
                for (int nj = 0; nj < 4; ++nj)
                    acc[mi][nj] = __builtin_amdgcn_mfma_f32_16x16x32_bf16(
                        af[mi], bfv[nj], acc[mi][nj], 0, 0, 0);
        }
        __syncthreads();
    }

    float* Cp = Cpart + (size_t)z * M * N;
#pragma unroll
    for (int mi = 0; mi < 4; ++mi)
#pragma unroll
        for (int nj = 0; nj < 4; ++nj)
#pragma unroll
            for (int r = 0; r < 4; ++r) {
                int row = row0 + wr * 64 + mi * 16 + (lane >> 4) * 4 + r;
                int col = col0 + wc * 64 + nj * 16 + l15;
                Cp[(size_t)row * N + col] = acc[mi][nj][r];
            }
}

// ---------------------------------------------------------------------------
// Reduce split-K partials: out = sum_z part[z] (+ add) (+= out if acc)
// ---------------------------------------------------------------------------
__global__ __launch_bounds__(256) void reduce_partials(
    const float* __restrict__ part, int ns, int n4,
    const float* __restrict__ add, float* __restrict__ out, int acc)
{
    const float4* p4 = (const float4*)part;
    const float4* a4 = (const float4*)add;
    float4* o4 = (float4*)out;
    for (int idx = blockIdx.x * 256 + threadIdx.x; idx < n4;
         idx += gridDim.x * 256) {
        float4 s = p4[idx];
        for (int z = 1; z < ns; ++z) {
            float4 q = p4[(size_t)z * n4 + idx];
            s.x += q.x; s.y += q.y; s.z += q.z; s.w += q.w;
        }
        if (add) {
            float4 q = a4[idx];
            s.x += q.x; s.y += q.y; s.z += q.z; s.w += q.w;
        }
        if (acc) {
            float4 q = o4[idx];
            s.x += q.x; s.y += q.y; s.z += q.z; s.w += q.w;
        }
        o4[idx] = s;
    }
}

// ---------------------------------------------------------------------------
// MoE expert-up + fused SwiGLU + comb weighting.
// ---------------------------------------------------------------------------
__global__ __launch_bounds__(256) void moe_up_swiglu(
    const unsigned short* __restrict__ x2B,
    const unsigned short* __restrict__ w13T,
    const float* __restrict__ comb,
    unsigned short* __restrict__ actB)
{
    __shared__ unsigned short As[2][128 * 32];
    __shared__ unsigned short Bgs[2][128 * 32];
    __shared__ unsigned short Bus[2][128 * 32];

    const int tid = threadIdx.x;
    const int wave = tid >> 6;
    const int lane = tid & 63;
    const int wr = wave >> 1, wc = wave & 1;
    const int l15 = lane & 15;
    const int e  = blockIdx.z;
    const int n0 = blockIdx.x * 128;
    const int m0 = blockIdx.y * 128;

    const unsigned short* Ap = x2B + (size_t)m0 * HD;
    const unsigned short* Bg = w13T + (size_t)e * 1024 * HD + (size_t)n0 * HD;
    const unsigned short* Bu = Bg + (size_t)512 * HD;

    const int r_st = tid >> 2;
    const int q_st = tid & 3;

    f32x4 accg[4][4] = {};
    f32x4 accu[4][4] = {};

#define STAGE_MOE(buf, k0s)                                                   \
    {                                                                         \
        _Pragma("unroll")                                                     \
        for (int i = 0; i < 2; ++i) {                                         \
            int rr = r_st + i * 64;                                           \
            int cs = (k0s) + ((q_st ^ (rr & 3)) << 3);                        \
            gl_lds16(Ap + (size_t)rr * HD + cs, &As[buf][rr * 32 + q_st * 8]);\
            gl_lds16(Bg + (size_t)rr * HD + cs, &Bgs[buf][rr * 32 + q_st * 8]);\
            gl_lds16(Bu + (size_t)rr * HD + cs, &Bus[buf][rr * 32 + q_st * 8]);\
        }                                                                     \
    }

    STAGE_MOE(0, 0);
    __syncthreads();

    const int nsteps = HD / 32;
    for (int s = 0; s < nsteps; ++s) {
        const int cur = s & 1;
        if (s + 1 < nsteps) STAGE_MOE(cur ^ 1, (s + 1) * 32);

        const int q = lane >> 4;
        bf16x8 af[4], bg[4], bu[4];
#pragma unroll
        for (int i = 0; i < 4; ++i) {
            int R = wr * 64 + i * 16 + l15;
            int off = R * 32 + ((q ^ (R & 3)) << 3);
            af[i] = *(const bf16x8*)&As[cur][off];
        }
#pragma unroll
        for (int j = 0; j < 4; ++j) {
            int R = wc * 64 + j * 16 + l15;
            int off = R * 32 + ((q ^ (R & 3)) << 3);
            bg[j] = *(const bf16x8*)&Bgs[cur][off];
            bu[j] = *(const bf16x8*)&Bus[cur][off];
        }
#pragma unroll
        for (int mi = 0; mi < 4; ++mi)
#pragma unroll
            for (int nj = 0; nj < 4; ++nj) {
                accg[mi][nj] = __builtin_amdgcn_mfma_f32_16x16x32_bf16(
                    af[mi], bg[nj], accg[mi][nj], 0, 0, 0);
                accu[mi][nj] = __builtin_amdgcn_mfma_f32_16x16x32_bf16(
                    af[mi], bu[nj], accu[mi][nj], 0, 0, 0);
            }
        __syncthreads();
    }

    float cw[4][4];
#pragma unroll
    for (int mi = 0; mi < 4; ++mi)
#pragma unroll
        for (int r = 0; r < 4; ++r) {
            int row = m0 + wr * 64 + mi * 16 + (lane >> 4) * 4 + r;
            cw[mi][r] = comb[(size_t)row * NEXP + e];
        }

#pragma unroll
    for (int mi = 0; mi < 4; ++mi)
#pragma unroll
        for (int nj = 0; nj < 4; ++nj)
#pragma unroll
            for (int r = 0; r < 4; ++r) {
                int row = m0 + wr * 64 + mi * 16 + (lane >> 4) * 4 + r;
                int col = n0 + wc * 64 + nj * 16 + l15;
                float g = accg[mi][nj][r];
                float u = accu[mi][nj][r];
                float v = (g / (1.f + __expf(-g))) * u * cw[mi][r];
                actB[(size_t)row * (NEXP * EI) + e * EI + col] = f2bf(v);
            }
}

// ---------------------------------------------------------------------------
// RoPE + pack to head-major bf16.  One block per token, 256 threads.
// Q scaled by 1/sqrt(128).  Layout: Qb[h][t][128], Kb[kvh][t][128],
// Vb[kvh][t][128].
// ---------------------------------------------------------------------------
__global__ __launch_bounds__(256) void rope_pack(
    const float* __restrict__ qkv, const int* __restrict__ pos_ids,
    unsigned short* __restrict__ Qb, unsigned short* __restrict__ Kb,
    unsigned short* __restrict__ Vb)
{
    const float SCALE = 0.08838834764831843f;
    int t = blockIdx.x;
    int tid = threadIdx.x;
    int w = tid >> 6, lane = tid & 63;
    float pos = (float)pos_ids[t];
    float invf = powf(10000.0f, -(float)lane * (1.0f / 64.0f));
    float ang = pos * invf;
    float c = cosf(ang);
    float s = sinf(ang);
    const float* row = qkv + (size_t)t * QKVN;
#pragma unroll
    for (int j = 0; j < 5; ++j) {
        int hh = w * 5 + j;   // heads 0..19 (0..15 q, 16..19 k), contiguous
        const float* hb = row + hh * HEADD;
        float x1 = hb[lane], x2 = hb[lane + 64];
        float o1 = x1 * c - x2 * s;
        float o2 = x2 * c + x1 * s;
        if (hh < NQH) {
            unsigned short* qp = Qb + ((size_t)hh * TT + t) * HEADD;
            qp[lane] = f2bf(o1 * SCALE);
            qp[lane + 64] = f2bf(o2 * SCALE);
        } else {
            unsigned short* kp = Kb + ((size_t)(hh - NQH) * TT + t) * HEADD;
            kp[lane] = f2bf(o1);
            kp[lane + 64] = f2bf(o2);
        }
    }
    // V: elements 2560..3071 -> Vb[kvh][t][d]
    float2 v2 = *(const float2*)(row + 2560 + tid * 2);
    int kvh = tid >> 6;
    int d = (tid * 2) & 127;
    unsigned int packed = (unsigned int)f2bf(v2.x) |
                          ((unsigned int)f2bf(v2.y) << 16);
    *(unsigned int*)(Vb + ((size_t)kvh * TT + t) * HEADD + d) = packed;
}

// ---------------------------------------------------------------------------
// V transpose: Vb[kvh][t][128] -> Vt[kvh][128][t]  (bf16, LDS 32x32 tiles)
// ---------------------------------------------------------------------------
__global__ __launch_bounds__(256) void transpose_v(
    const unsigned short* __restrict__ Vb, unsigned short* __restrict__ Vt)
{
    __shared__ unsigned short tile[32][40];
    const int kvh = blockIdx.z;
    const int t0 = blockIdx.x * 32, d0 = blockIdx.y * 32;
    int tid = threadIdx.x;
    int r = tid >> 3, c4 = (tid & 7) * 4;
    ushort4 v = *(const ushort4*)(Vb + ((size_t)kvh * TT + t0 + r) * HEADD + d0 + c4);
    tile[r][c4] = v.x; tile[r][c4 + 1] = v.y;
    tile[r][c4 + 2] = v.z; tile[r][c4 + 3] = v.w;
    __syncthreads();
    ushort4 o;
    o.x = tile[c4 + 0][r];
    o.y = tile[c4 + 1][r];
    o.z = tile[c4 + 2][r];
    o.w = tile[c4 + 3][r];
    *(ushort4*)(Vt + ((size_t)kvh * HEADD + d0 + r) * TT + t0 + c4) = o;
}

// ---------------------------------------------------------------------------
// MFMA flash attention.  grid (NQH, T/64), 256 threads = 4 independent waves.
// Wave w: 16 q-rows (q0 = by*64 + w*16).  K/V read from global (L2-resident).
// QK^T: 16 mfma; online softmax in-wave; P via per-wave LDS; PV: 16 mfma.
// ---------------------------------------------------------------------------
__global__ __launch_bounds__(256) void flash_attn_mfma(
    const unsigned short* __restrict__ Qb,  // [NQH][T][128]  (pre-scaled)
    const unsigned short* __restrict__ Kb,  // [NKVH][T][128]
    const unsigned short* __restrict__ Vt,  // [NKVH][128][T]
    unsigned short* __restrict__ ctx)       // [T][NQH*128]
{
    __shared__ __align__(16) unsigned short Pl[4][16][72];

    const int h = blockIdx.x;
    const int kvh = h >> 2;
    const int tid = threadIdx.x;
    const int w = tid >> 6;
    const int lane = tid & 63;
    const int l15 = lane & 15;
    const int g = lane >> 4;              // 0..3
    const int q0 = blockIdx.y * 64 + w * 16;

    // Q fragments in registers (row = l15, k-chunk = g*8 within each kk*32)
    const unsigned short* Qrow = Qb + ((size_t)h * TT + q0 + l15) * HEADD;
    bf16x8 qf[4];
#pragma unroll
    for (int kk = 0; kk < 4; ++kk)
        qf[kk] = *(const bf16x8*)(Qrow + kk * 32 + g * 8);

    float m_i[4], l_i[4];
#pragma unroll
    for (int r = 0; r < 4; ++r) { m_i[r] = -1e30f; l_i[r] = 0.f; }
    f32x4 of[8] = {};

    const int dtile = q0 >> 6;            // diagonal s-tile index
    for (int st = 0; st <= dtile; ++st) {
        const int s0 = st * 64;

        // ---- S = Q K^T ----
        f32x4 sacc[4] = {};
        const unsigned short* Kbase = Kb + ((size_t)kvh * TT + s0) * HEADD;
#pragma unroll
        for (int kk = 0; kk < 4; ++kk) {
#pragma unroll
            for (int n = 0; n < 4; ++n) {
                bf16x8 kb = *(const bf16x8*)(Kbase +
                    (size_t)(n * 16 + l15) * HEADD + kk * 32 + g * 8);
                sacc[n] = __builtin_amdgcn_mfma_f32_16x16x32_bf16(
                    qf[kk], kb, sacc[n], 0, 0, 0);
            }
        }

        // ---- online softmax (row = q0 + g*4 + r) ----
        const bool diag = (st == dtile);
        float alpha[4];
#pragma unroll
        for (int r = 0; r < 4; ++r) {
            const int qrow = q0 + g * 4 + r;
            float sv[4] = {sacc[0][r], sacc[1][r], sacc[2][r], sacc[3][r]};
            if (diag) {
#pragma unroll
                for (int n = 0; n < 4; ++n)
                    if (s0 + n * 16 + l15 > qrow) sv[n] = -1e30f;
            }
            float rm = fmaxf(fmaxf(sv[0], sv[1]), fmaxf(sv[2], sv[3]));
            rm = fmaxf(rm, __shfl_xor(rm, 1));
            rm = fmaxf(rm, __shfl_xor(rm, 2));
            rm = fmaxf(rm, __shfl_xor(rm, 4));
            rm = fmaxf(rm, __shfl_xor(rm, 8));
            float mnew = fmaxf(m_i[r], rm);
            alpha[r] = __expf(m_i[r] - mnew);
            float p0 = __expf(sv[0] - mnew);
            float p1 = __expf(sv[1] - mnew);
            float p2 = __expf(sv[2] - mnew);
            float p3 = __expf(sv[3] - mnew);
            float rs = p0 + p1 + p2 + p3;
            rs += __shfl_xor(rs, 1);
            rs += __shfl_xor(rs, 2);
            rs += __shfl_xor(rs, 4);
            rs += __shfl_xor(rs, 8);
            l_i[r] = l_i[r] * alpha[r] + rs;
            m_i[r] = mnew;
            Pl[w][g * 4 + r][0 * 16 + l15] = f2bf(p0);
            Pl[w][g * 4 + r][1 * 16 + l15] = f2bf(p1);
            Pl[w][g * 4 + r][2 * 16 + l15] = f2bf(p2);
            Pl[w][g * 4 + r][3 * 16 + l15] = f2bf(p3);
        }

        // ---- O rescale ----
#pragma unroll
        for (int nd = 0; nd < 8; ++nd)
#pragma unroll
            for (int r = 0; r < 4; ++r)
                of[nd][r] *= alpha[r];

        // ---- PV ----
        const unsigned short* Vbase = Vt + (size_t)kvh * HEADD * TT + s0;
#pragma unroll
        for (int kk2 = 0; kk2 < 2; ++kk2) {
            bf16x8 pa = *(const bf16x8*)&Pl[w][l15][kk2 * 32 + g * 8];
#pragma unroll
            for (int nd = 0; nd < 8; ++nd) {
                bf16x8 vb = *(const bf16x8*)(Vbase +
                    (size_t)(nd * 16 + l15) * TT + kk2 * 32 + g * 8);
                of[nd] = __builtin_amdgcn_mfma_f32_16x16x32_bf16(
                    pa, vb, of[nd], 0, 0, 0);
            }
        }
    }

    // ---- finalize ----
    float invl[4];
#pragma unroll
    for (int r = 0; r < 4; ++r) invl[r] = 1.f / l_i[r];
#pragma unroll
    for (int nd = 0; nd < 8; ++nd)
#pragma unroll
        for (int r = 0; r < 4; ++r) {
            int trow = q0 + g * 4 + r;
            ctx[(size_t)trow * (NQH * HEADD) + h * HEADD + nd * 16 + l15] =
                f2bf(of[nd][r] * invl[r]);
        }
}

// ---------------------------------------------------------------------------
// Fused router: rmsnorm(resid2)*w . gate_w, softmax top-4 -> comb (T,16)
// ---------------------------------------------------------------------------
__global__ __launch_bounds__(256) void router_fused(
    const float* __restrict__ resid2, const float* __restrict__ w,
    const float* __restrict__ gate_w, float* __restrict__ comb)
{
    int t = blockIdx.x;
    int tid = threadIdx.x;
    int lane = tid & 63, wv = tid >> 6;

    const float4* r4 = (const float4*)(resid2 + (size_t)t * HD);
    float4 xa = r4[tid * 2], xb = r4[tid * 2 + 1];
    float ss = xa.x * xa.x + xa.y * xa.y + xa.z * xa.z + xa.w * xa.w +
               xb.x * xb.x + xb.y * xb.y + xb.z * xb.z + xb.w * xb.w;
    for (int off = 32; off > 0; off >>= 1) ss += __shfl_down(ss, off);
    __shared__ float red[4];
    if (lane == 0) red[wv] = ss;
    __syncthreads();
    float inv = rsqrtf((red[0] + red[1] + red[2] + red[3]) / (float)HD + 1e-6f);

    const float4* w4 = (const float4*)w;
    float4 wa = w4[tid * 2], wb = w4[tid * 2 + 1];
    float xs[8] = {xa.x * wa.x * inv, xa.y * wa.y * inv, xa.z * wa.z * inv,
                   xa.w * wa.w * inv, xb.x * wb.x * inv, xb.y * wb.y * inv,
                   xb.z * wb.z * inv, xb.w * wb.w * inv};

    float acc[16] = {};
    int kbase = tid * 8;
#pragma unroll
    for (int j = 0; j < 8; ++j) {
        float xv = xs[j];
        const float4* wrow = (const float4*)(gate_w + (size_t)(kbase + j) * NEXP);
        float4 w0 = wrow[0], w1 = wrow[1], w2 = wrow[2], w3 = wrow[3];
        acc[0] += xv * w0.x;  acc[1] += xv * w0.y;  acc[2] += xv * w0.z;  acc[3] += xv * w0.w;
        acc[4] += xv * w1.x;  acc[5] += xv * w1.y;  acc[6] += xv * w1.z;  acc[7] += xv * w1.w;
        acc[8] += xv * w2.x;  acc[9] += xv * w2.y;  acc[10] += xv * w2.z; acc[11] += xv * w2.w;
        acc[12] += xv * w3.x; acc[13] += xv * w3.y; acc[14] += xv * w3.z; acc[15] += xv * w3.w;
    }
    __shared__ float red2[4][16];
#pragma unroll
    for (int e = 0; e < 16; ++e) {
        float v = acc[e];
        v += __shfl_xor(v, 1);
        v += __shfl_xor(v, 2);
        v += __shfl_xor(v, 4);
        v += __shfl_xor(v, 8);
        v += __shfl_xor(v, 16);
        v += __shfl_xor(v, 32);
        if (lane == 0) red2[wv][e] = v;
    }
    __syncthreads();

    if (tid == 0) {
        float l[NEXP];
#pragma unroll
        for (int e = 0; e < NEXP; ++e)
            l[e] = red2[0][e] + red2[1][e] + red2[2][e] + red2[3][e];
        int sel[TOPK];
        float selv[TOPK];
        bool used[NEXP] = {};
#pragma unroll
        for (int r = 0; r < TOPK; ++r) {
            int best = -1;
            float bv = -1e30f;
            for (int e = 0; e < NEXP; ++e)
                if (!used[e] && l[e] > bv) { bv = l[e]; best = e; }
            used[best] = true;
            sel[r] = best;
            selv[r] = bv;
        }
        float mx = selv[0];
        float wsum = 0.f, wvv[TOPK];
#pragma unroll
        for (int r = 0; r < TOPK; ++r) { wvv[r] = __expf(selv[r] - mx); wsum += wvv[r]; }
        float out16[NEXP] = {};
#pragma unroll
        for (int r = 0; r < TOPK; ++r) out16[sel[r]] = wvv[r] / wsum;
#pragma unroll
        for (int e = 0; e < NEXP; ++e) comb[(size_t)t * NEXP + e] = out16[e];
    }
}

// ---------------------------------------------------------------------------
// SwiGLU (shared): sact(bf16)[t][i] = silu(gu[t][i]) * gu[t][SSI+i]
// ---------------------------------------------------------------------------
__global__ void silu_mul_kernel(const float* __restrict__ gu,
                                unsigned short* __restrict__ out, int T, int I)
{
    size_t n = (size_t)T * I;
    for (size_t idx = (size_t)blockIdx.x * blockDim.x + threadIdx.x; idx < n;
         idx += (size_t)gridDim.x * blockDim.x) {
        size_t t = idx / I;
        int i = (int)(idx % I);
        float g = gu[t * 2 * I + i];
        float u = gu[t * 2 * I + I + i];
        out[idx] = f2bf((g / (1.f + __expf(-g))) * u);
    }
}

// ---------------------------------------------------------------------------
extern "C" void kernel_launch(void* const* d_in, const int* in_sizes, int n_in,
                              void* d_out, int out_size, void* d_ws, size_t ws_size,
                              hipStream_t stream)
{
    const float* hidden   = (const float*)d_in[0];
    const float* residual = (const float*)d_in[1];
    const float* rms1_w   = (const float*)d_in[2];
    const float* rms2_w   = (const float*)d_in[3];
    const float* w_qkv    = (const float*)d_in[4];
    const float* w_dense  = (const float*)d_in[5];
    const float* gate_w   = (const float*)d_in[6];
    const float* w13      = (const float*)d_in[7];
    const float* w2       = (const float*)d_in[8];
    const float* sw13     = (const float*)d_in[9];
    const float* sw2      = (const float*)d_in[10];
    const int*   pos_ids  = (const int*)d_in[11];

    const int T = TT;

    float* out0 = (float*)d_out;
    float* out1 = (float*)d_out + (size_t)T * HD;

    // ---- workspace layout ----
    char* base = (char*)d_ws;
    float*          residF = (float*)(base);                    //  8.39 MB
    unsigned short* xB     = (unsigned short*)(base + 8388608); //  4.19 MB
    unsigned short* ctxB   = (unsigned short*)(base + 12582912);//  4.19 MB
    unsigned short* actB   = (unsigned short*)(base);           // 16.78 MB alias
    float*          qkvF   = (float*)(base + 16777216);         // 12.58 MB
    float*          guF    = qkvF;                              //  alias
    unsigned short* x2B    = (unsigned short*)(base + 29360128);//  4.19 MB
    unsigned short* sactB  = (unsigned short*)(base + 33554432);//  2.10 MB
    float*          comb   = (float*)(base + 35651584);         //  0.07 MB
    float*          part   = (float*)(base + 35717120);         // 33.55 MB
    unsigned short* Wbuf   = (unsigned short*)(base + 69271552);// 67.11 MB

    // attention bf16 buffers alias the split-K `part` region (dead there)
    unsigned short* Qb = (unsigned short*)(base + 35717120);            // 4 MB
    unsigned short* Kb = Qb + (size_t)NQH * TT * HEADD;                 // 1 MB
    unsigned short* Vb = Kb + (size_t)NKVH * TT * HEADD;                // 1 MB
    unsigned short* Vt = Vb + (size_t)NKVH * TT * HEADD;                // 1 MB

    dim3 blk(256);

    // 1. resid = hidden + residual ; x = rmsnorm -> bf16
    add_rmsnorm_kernel<<<dim3(T), blk, 0, stream>>>(
        hidden, residual, rms1_w, residF, xB);

    // 2. qkv = x @ w_qkv   (split-K x2)
    transpose_convert<<<dim3(QKVN / 32, HD / 32), blk, 0, stream>>>(
        w_qkv, Wbuf, HD, QKVN, 0, 0);
    gemm_splitk<<<dim3(QKVN / 128, T / 128, 2), blk, 0, stream>>>(
        xB, Wbuf, part, T, QKVN, 1024, HD, HD);
    reduce_partials<<<dim3(1024), blk, 0, stream>>>(
        part, 2, T * QKVN / 4, nullptr, qkvF, 0);

    // 3. RoPE + pack head-major bf16 ; V transpose
    rope_pack<<<dim3(T), blk, 0, stream>>>(qkvF, pos_ids, Qb, Kb, Vb);
    transpose_v<<<dim3(T / 32, HEADD / 32, NKVH), blk, 0, stream>>>(Vb, Vt);

    // 4. MFMA flash attention -> ctx (bf16)
    flash_attn_mfma<<<dim3(NQH, T / 64), blk, 0, stream>>>(Qb, Kb, Vt, ctxB);

    // 5. resid2 = ctx @ w_dense + resid -> out1   (split-K x4)
    transpose_convert<<<dim3(HD / 32, HD / 32), blk, 0, stream>>>(
        w_dense, Wbuf, HD, HD, 0, 0);
    gemm_splitk<<<dim3(HD / 128, T / 128, 4), blk, 0, stream>>>(
        ctxB, Wbuf, part, T, HD, 512, HD, HD);
    reduce_partials<<<dim3(1024), blk, 0, stream>>>(
        part, 4, T * HD / 4, residF, out1, 0);

    // 6. x2 = rmsnorm(resid2) -> bf16
    add_rmsnorm_kernel<<<dim3(T), blk, 0, stream>>>(
        out1, nullptr, rms2_w, nullptr, x2B);

    // 7+8. fused router -> comb
    router_fused<<<dim3(T), blk, 0, stream>>>(out1, rms2_w, gate_w, comb);

    // 9. shared gu = x2 @ sw13  (split-K x4) -> guF
    transpose_convert<<<dim3(HD / 32, HD / 32), blk, 0, stream>>>(
        sw13, Wbuf, HD, 2 * SSI, 0, 0);
    gemm_splitk<<<dim3(HD / 128, T / 128, 4), blk, 0, stream>>>(
        x2B, Wbuf, part, T, 2 * SSI, 512, HD, HD);
    reduce_partials<<<dim3(1024), blk, 0, stream>>>(
        part, 4, T * 2 * SSI / 4, nullptr, guF, 0);

    // 10. shared act (bf16)
    silu_mul_kernel<<<dim3(1024), blk, 0, stream>>>(guF, sactB, T, SSI);

    // 11. out0 = shared_act @ sw2  (split-K x4)
    transpose_convert<<<dim3(HD / 32, SSI / 32), blk, 0, stream>>>(
        sw2, Wbuf, SSI, HD, 0, 0);
    gemm_splitk<<<dim3(HD / 128, T / 128, 4), blk, 0, stream>>>(
        sactB, Wbuf, part, T, HD, 256, SSI, SSI);
    reduce_partials<<<dim3(1024), blk, 0, stream>>>(
        part, 4, T * HD / 4, nullptr, out0, 0);

    // 12. expert up + fused SwiGLU*comb -> actB   (all 16 experts)
    transpose_convert<<<dim3(1024 / 32, HD / 32, NEXP), blk, 0, stream>>>(
        w13, Wbuf, HD, 1024, (long long)HD * 1024, (long long)1024 * HD);
    moe_up_swiglu<<<dim3(EI / 128, T / 128, NEXP), blk, 0, stream>>>(
        x2B, Wbuf, comb, actB);

    // 13. out0 += act @ w2   (split-K x4 over K=8192)
    transpose_convert<<<dim3(HD / 32, (NEXP * EI) / 32), blk, 0, stream>>>(
        w2, Wbuf, NEXP * EI, HD, 0, 0);
    gemm_splitk<<<dim3(HD / 128, T / 128, 4), blk, 0, stream>>>(
        actB, Wbuf, part, T, HD, 2048, NEXP * EI, NEXP * EI);
    reduce_partials<<<dim3(1024), blk, 0, stream>>>(
        part, 4, T * HD / 4, nullptr, out0, 1);
}

// Round 6
// 477.736 us; speedup vs baseline: 15.8294x; 1.0447x over previous
//
#include <hip/hip_runtime.h>
#include <math.h>

// ---------------------------------------------------------------------------
// Problem constants
// ---------------------------------------------------------------------------
#define HD 2048      // hidden size h
#define NQH 16       // num q heads
#define NKVH 4       // num kv heads
#define HEADD 128    // head dim
#define QKVN 3072    // qkv cols
#define NEXP 16      // experts
#define EI 512       // expert intermediate
#define SSI 1024     // shared intermediate
#define TOPK 4
#define TT 1024      // tokens

typedef __bf16 bf16x8 __attribute__((ext_vector_type(8)));
typedef float f32x4 __attribute__((ext_vector_type(4)));

static __device__ __forceinline__ unsigned short f2bf(float f) {
    union { float f; unsigned int u; } v; v.f = f;
    unsigned int r = v.u + 0x7fff + ((v.u >> 16) & 1);
    return (unsigned short)(r >> 16);
}

static __device__ __forceinline__ void gl_lds16(const unsigned short* g,
                                                unsigned short* l) {
    __builtin_amdgcn_global_load_lds(
        (const __attribute__((address_space(1))) unsigned int*)g,
        (__attribute__((address_space(3))) unsigned int*)l, 16, 0, 0);
}

// ---------------------------------------------------------------------------
// Fused add + RMSNorm. resid_out(f32 opt) ; x_bf (bf16)
// ---------------------------------------------------------------------------
__global__ __launch_bounds__(256) void add_rmsnorm_kernel(
    const float* __restrict__ a, const float* __restrict__ b,
    const float* __restrict__ w, float* __restrict__ resid_out,
    unsigned short* __restrict__ x_bf)
{
    int t = blockIdx.x;
    int tid = threadIdx.x;
    const float4* a4 = (const float4*)(a + (size_t)t * HD);
    const float4* b4 = b ? (const float4*)(b + (size_t)t * HD) : nullptr;
    float4* r4 = resid_out ? (float4*)(resid_out + (size_t)t * HD) : nullptr;
    const float4* w4 = (const float4*)w;

    float4 v[2];
    float ss = 0.f;
#pragma unroll
    for (int l = 0; l < 2; ++l) {
        int idx = tid + l * 256;
        float4 va = a4[idx];
        if (b4) {
            float4 vb = b4[idx];
            va.x += vb.x; va.y += vb.y; va.z += vb.z; va.w += vb.w;
        }
        if (r4) r4[idx] = va;
        v[l] = va;
        ss += va.x * va.x + va.y * va.y + va.z * va.z + va.w * va.w;
    }
    for (int off = 32; off > 0; off >>= 1) ss += __shfl_down(ss, off);
    __shared__ float red[4];
    int lane = tid & 63, wv = tid >> 6;
    if (lane == 0) red[wv] = ss;
    __syncthreads();
    if (tid == 0) {
        float s = red[0] + red[1] + red[2] + red[3];
        red[0] = rsqrtf(s / (float)HD + 1e-6f);
    }
    __syncthreads();
    float inv = red[0];
#pragma unroll
    for (int l = 0; l < 2; ++l) {
        int idx = tid + l * 256;
        float4 va = v[l], vw = w4[idx];
        ushort4 ob;
        ob.x = f2bf(va.x * inv * vw.x);
        ob.y = f2bf(va.y * inv * vw.y);
        ob.z = f2bf(va.z * inv * vw.z);
        ob.w = f2bf(va.w * inv * vw.w);
        ((ushort4*)(x_bf + (size_t)t * HD))[idx] = ob;
    }
}

// ---------------------------------------------------------------------------
// Transpose + convert: f32 in [K][N] -> bf16 out [N][K]   (per-z strides)
// ---------------------------------------------------------------------------
__global__ __launch_bounds__(256) void transpose_convert(
    const float* __restrict__ in, unsigned short* __restrict__ out,
    int K, int N, long long strideIn, long long strideOut)
{
    __shared__ float tile[32][33];
    const int n0 = blockIdx.x * 32;
    const int k0 = blockIdx.y * 32;
    const float* ip = in + (size_t)blockIdx.z * strideIn;
    unsigned short* op = out + (size_t)blockIdx.z * strideOut;
    int tid = threadIdx.x;
    int r = tid >> 3, c = (tid & 7) * 4;
    float4 v = *(const float4*)(ip + (size_t)(k0 + r) * N + n0 + c);
    tile[r][c] = v.x; tile[r][c + 1] = v.y; tile[r][c + 2] = v.z; tile[r][c + 3] = v.w;
    __syncthreads();
    ushort4 o;
    o.x = f2bf(tile[c + 0][r]);
    o.y = f2bf(tile[c + 1][r]);
    o.z = f2bf(tile[c + 2][r]);
    o.w = f2bf(tile[c + 3][r]);
    *(ushort4*)(op + (size_t)(n0 + r) * K + k0 + c) = o;
}

// ---------------------------------------------------------------------------
// Split-K bf16 MFMA GEMM, STAGE-early double-buffered, BK=64.
// ---------------------------------------------------------------------------
#define SBK 64

__global__ __launch_bounds__(256) void gemm_splitk(
    const unsigned short* __restrict__ A, const unsigned short* __restrict__ B,
    float* __restrict__ Cpart, int M, int N, int Kc, int ldA, int ldB)
{
    __shared__ unsigned short As[2][128 * SBK];
    __shared__ unsigned short Bs[2][128 * SBK];

    const int tid = threadIdx.x;
    const int wave = tid >> 6;
    const int lane = tid & 63;
    const int wr = wave >> 1, wc = wave & 1;
    const int l15 = lane & 15;
    const int row0 = blockIdx.y * 128;
    const int col0 = blockIdx.x * 128;
    const int z = blockIdx.z;

    const unsigned short* Ap = A + (size_t)row0 * ldA + (size_t)z * Kc;
    const unsigned short* Bp = B + (size_t)col0 * ldB + (size_t)z * Kc;

    const int r_st = tid >> 3;
    const int q_st = tid & 7;
    const int csrc = (q_st ^ (r_st & 7)) << 3;

    f32x4 acc[4][4] = {};

    const int nsteps = Kc / SBK;

#define STAGE_SK(buf, k0s)                                                    \
    {                                                                         \
        _Pragma("unroll")                                                     \
        for (int i = 0; i < 4; ++i) {                                         \
            int rr = r_st + i * 32;                                           \
            gl_lds16(Ap + (size_t)rr * ldA + (k0s) + csrc,                    \
                     &As[buf][rr * SBK + q_st * 8]);                          \
            gl_lds16(Bp + (size_t)rr * ldB + (k0s) + csrc,                    \
                     &Bs[buf][rr * SBK + q_st * 8]);                          \
        }                                                                     \
    }

    STAGE_SK(0, 0);
    __syncthreads();

    for (int s = 0; s < nsteps; ++s) {
        const int cur = s & 1;
        if (s + 1 < nsteps) STAGE_SK(cur ^ 1, (s + 1) * SBK);

#pragma unroll
        for (int half = 0; half < 2; ++half) {
            const int q = half * 4 + (lane >> 4);
            bf16x8 af[4], bfv[4];
#pragma unroll
            for (int i = 0; i < 4; ++i) {
                int R = wr * 64 + i * 16 + l15;
                af[i] = *(const bf16x8*)&As[cur][R * SBK + ((q ^ (R & 7)) << 3)];
            }
#pragma unroll
            for (int j = 0; j < 4; ++j) {
                int R = wc * 64 + j * 16 + l15;
                bfv[j] = *(const bf16x8*)&Bs[cur][R * SBK + ((q ^ (R & 7)) << 3)];
            }
#pragma unroll
            for (int mi = 0; mi < 4; ++mi)
#pragma unroll
                for (int nj = 0; nj < 4; ++nj)
                    acc[mi][nj] = __builtin_amdgcn_mfma_f32_16x16x32_bf16(
                        af[mi], bfv[nj], acc[mi][nj], 0, 0, 0);
        }
        __syncthreads();
    }

    float* Cp = Cpart + (size_t)z * M * N;
#pragma unroll
    for (int mi = 0; mi < 4; ++mi)
#pragma unroll
        for (int nj = 0; nj < 4; ++nj)
#pragma unroll
            for (int r = 0; r < 4; ++r) {
                int row = row0 + wr * 64 + mi * 16 + (lane >> 4) * 4 + r;
                int col = col0 + wc * 64 + nj * 16 + l15;
                Cp[(size_t)row * N + col] = acc[mi][nj][r];
            }
}

// ---------------------------------------------------------------------------
// Reduce split-K partials: out = sum_z part[z] (+ add) (+= out if acc)
// ---------------------------------------------------------------------------
__global__ __launch_bounds__(256) void reduce_partials(
    const float* __restrict__ part, int ns, int n4,
    const float* __restrict__ add, float* __restrict__ out, int acc)
{
    const float4* p4 = (const float4*)part;
    const float4* a4 = (const float4*)add;
    float4* o4 = (float4*)out;
    for (int idx = blockIdx.x * 256 + threadIdx.x; idx < n4;
         idx += gridDim.x * 256) {
        float4 s = p4[idx];
        for (int z = 1; z < ns; ++z) {
            float4 q = p4[(size_t)z * n4 + idx];
            s.x += q.x; s.y += q.y; s.z += q.z; s.w += q.w;
        }
        if (add) {
            float4 q = a4[idx];
            s.x += q.x; s.y += q.y; s.z += q.z; s.w += q.w;
        }
        if (acc) {
            float4 q = o4[idx];
            s.x += q.x; s.y += q.y; s.z += q.z; s.w += q.w;
        }
        o4[idx] = s;
    }
}

// ---------------------------------------------------------------------------
// Reduce split-K partials of shared-expert gu [T][2048] + SwiGLU -> bf16
// out[t][i] = silu(sum_z g) * (sum_z u),  i < SSI.  One elem4 per thread.
// ---------------------------------------------------------------------------
__global__ __launch_bounds__(256) void reduce_swiglu(
    const float* __restrict__ part, int ns, unsigned short* __restrict__ out)
{
    int idx4 = blockIdx.x * 256 + threadIdx.x;       // over T*SSI/4
    int t = idx4 >> 8;                                // SSI/4 = 256
    int i4 = (idx4 & 255) * 4;
    const float4* pg = (const float4*)(part + (size_t)t * (2 * SSI) + i4);
    const float4* pu = (const float4*)(part + (size_t)t * (2 * SSI) + SSI + i4);
    float4 g = pg[0], u = pu[0];
    for (int z = 1; z < ns; ++z) {
        float4 g2 = *(const float4*)((const float*)pg + (size_t)z * TT * 2 * SSI);
        float4 u2 = *(const float4*)((const float*)pu + (size_t)z * TT * 2 * SSI);
        g.x += g2.x; g.y += g2.y; g.z += g2.z; g.w += g2.w;
        u.x += u2.x; u.y += u2.y; u.z += u2.z; u.w += u2.w;
    }
    ushort4 o;
    o.x = f2bf((g.x / (1.f + __expf(-g.x))) * u.x);
    o.y = f2bf((g.y / (1.f + __expf(-g.y))) * u.y);
    o.z = f2bf((g.z / (1.f + __expf(-g.z))) * u.z);
    o.w = f2bf((g.w / (1.f + __expf(-g.w))) * u.w);
    *(ushort4*)(out + (size_t)t * SSI + i4) = o;
}

// ---------------------------------------------------------------------------
// Build per-expert token lists from comb (token-ordered, deterministic).
// One block per expert; block-wide inclusive scan.
// ---------------------------------------------------------------------------
__global__ __launch_bounds__(256) void build_lists(
    const float* __restrict__ comb, int* __restrict__ lists,
    int* __restrict__ cnts)
{
    int e = blockIdx.x;
    int tid = threadIdx.x;
    __shared__ int sc[256];
    int loc[4];
    int c = 0;
#pragma unroll
    for (int j = 0; j < 4; ++j) {
        int t = tid * 4 + j;
        if (comb[(size_t)t * NEXP + e] > 0.f) loc[c++] = t;
    }
    sc[tid] = c;
    __syncthreads();
    for (int off = 1; off < 256; off <<= 1) {
        int v = (tid >= off) ? sc[tid - off] : 0;
        __syncthreads();
        sc[tid] += v;
        __syncthreads();
    }
    int base = sc[tid] - c;
    for (int i = 0; i < c; ++i) lists[e * TT + base + i] = loc[i];
    if (tid == 255) cnts[e] = sc[255];
}

// ---------------------------------------------------------------------------
// Sparse MoE expert-up + fused SwiGLU*comb -> dense actB (zero-filled).
// grid (EI/128=4, 16 m-tiles, 16 experts); M-tile 64 gathered tokens,
// N-tile 128 (dual gate/up), BK=32, double-buffered, src-pre-swizzled.
// Wave w owns cols w*32..w*32+31; A-frags shared across waves.
// ---------------------------------------------------------------------------
__global__ __launch_bounds__(256) void moe_up_gather(
    const unsigned short* __restrict__ x2B,
    const unsigned short* __restrict__ w13T,
    const float* __restrict__ comb,
    const int* __restrict__ lists,
    const int* __restrict__ cnts,
    unsigned short* __restrict__ actB)
{
    __shared__ unsigned short As[2][64 * 32];
    __shared__ unsigned short Bgs[2][128 * 32];
    __shared__ unsigned short Bus[2][128 * 32];

    const int e = blockIdx.z;
    const int cnt = cnts[e];
    const int m0 = blockIdx.y * 64;
    if (m0 >= cnt) return;
    const int n0 = blockIdx.x * 128;

    const int tid = threadIdx.x;
    const int w = tid >> 6;
    const int lane = tid & 63;
    const int l15 = lane & 15;
    const int g = lane >> 4;

    // staging coords: row = tid>>2 (0..63), chunk = tid&3 (16B each)
    const int r_st = tid >> 2;
    const int q_st = tid & 3;
    const int swz = (q_st ^ (r_st & 3)) << 3;   // inverse-swizzled src col

    int arow = m0 + r_st;
    int atok = lists[e * TT + (arow < cnt ? arow : cnt - 1)];
    const unsigned short* Asrc = x2B + (size_t)atok * HD;
    const unsigned short* Bbase = w13T + (size_t)e * 1024 * HD;

    f32x4 ag[4][2] = {};
    f32x4 au[4][2] = {};

#define STAGE_UP(buf, k0s)                                                    \
    {                                                                         \
        gl_lds16(Asrc + (k0s) + swz, &As[buf][r_st * 32 + q_st * 8]);         \
        _Pragma("unroll")                                                     \
        for (int i = 0; i < 2; ++i) {                                         \
            int rr = r_st + i * 64;                                           \
            gl_lds16(Bbase + (size_t)(n0 + rr) * HD + (k0s) + swz,            \
                     &Bgs[buf][rr * 32 + q_st * 8]);                          \
            gl_lds16(Bbase + (size_t)(512 + n0 + rr) * HD + (k0s) + swz,      \
                     &Bus[buf][rr * 32 + q_st * 8]);                          \
        }                                                                     \
    }

    STAGE_UP(0, 0);
    __syncthreads();

    const int nsteps = HD / 32;
    for (int s = 0; s < nsteps; ++s) {
        const int cur = s & 1;
        if (s + 1 < nsteps) STAGE_UP(cur ^ 1, (s + 1) * 32);

        bf16x8 af[4], bg[2], bu[2];
#pragma unroll
        for (int i = 0; i < 4; ++i) {
            int R = i * 16 + l15;
            af[i] = *(const bf16x8*)&As[cur][R * 32 + ((g ^ (R & 3)) << 3)];
        }
#pragma unroll
        for (int j = 0; j < 2; ++j) {
            int R = w * 32 + j * 16 + l15;
            int off = R * 32 + ((g ^ (R & 3)) << 3);
            bg[j] = *(const bf16x8*)&Bgs[cur][off];
            bu[j] = *(const bf16x8*)&Bus[cur][off];
        }
#pragma unroll
        for (int mi = 0; mi < 4; ++mi)
#pragma unroll
            for (int nj = 0; nj < 2; ++nj) {
                ag[mi][nj] = __builtin_amdgcn_mfma_f32_16x16x32_bf16(
                    af[mi], bg[nj], ag[mi][nj], 0, 0, 0);
                au[mi][nj] = __builtin_amdgcn_mfma_f32_16x16x32_bf16(
                    af[mi], bu[nj], au[mi][nj], 0, 0, 0);
            }
        __syncthreads();
    }

#pragma unroll
    for (int mi = 0; mi < 4; ++mi) {
#pragma unroll
        for (int r = 0; r < 4; ++r) {
            int grow = m0 + mi * 16 + g * 4 + r;
            if (grow >= cnt) continue;
            int tok = lists[e * TT + grow];
            float cw = comb[(size_t)tok * NEXP + e];
#pragma unroll
            for (int nj = 0; nj < 2; ++nj) {
                int col = n0 + w * 32 + nj * 16 + l15;
                float gg = ag[mi][nj][r];
                float uu = au[mi][nj][r];
                float v = (gg / (1.f + __expf(-gg))) * uu * cw;
                actB[(size_t)tok * (NEXP * EI) + e * EI + col] = f2bf(v);
            }
        }
    }
}

// ---------------------------------------------------------------------------
// RoPE + pack to head-major bf16.  One block per token, 256 threads.
// ---------------------------------------------------------------------------
__global__ __launch_bounds__(256) void rope_pack(
    const float* __restrict__ qkv, const int* __restrict__ pos_ids,
    unsigned short* __restrict__ Qb, unsigned short* __restrict__ Kb,
    unsigned short* __restrict__ Vb)
{
    const float SCALE = 0.08838834764831843f;
    int t = blockIdx.x;
    int tid = threadIdx.x;
    int w = tid >> 6, lane = tid & 63;
    float pos = (float)pos_ids[t];
    float invf = powf(10000.0f, -(float)lane * (1.0f / 64.0f));
    float ang = pos * invf;
    float c = cosf(ang);
    float s = sinf(ang);
    const float* row = qkv + (size_t)t * QKVN;
#pragma unroll
    for (int j = 0; j < 5; ++j) {
        int hh = w * 5 + j;
        const float* hb = row + hh * HEADD;
        float x1 = hb[lane], x2 = hb[lane + 64];
        float o1 = x1 * c - x2 * s;
        float o2 = x2 * c + x1 * s;
        if (hh < NQH) {
            unsigned short* qp = Qb + ((size_t)hh * TT + t) * HEADD;
            qp[lane] = f2bf(o1 * SCALE);
            qp[lane + 64] = f2bf(o2 * SCALE);
        } else {
            unsigned short* kp = Kb + ((size_t)(hh - NQH) * TT + t) * HEADD;
            kp[lane] = f2bf(o1);
            kp[lane + 64] = f2bf(o2);
        }
    }
    float2 v2 = *(const float2*)(row + 2560 + tid * 2);
    int kvh = tid >> 6;
    int d = (tid * 2) & 127;
    unsigned int packed = (unsigned int)f2bf(v2.x) |
                          ((unsigned int)f2bf(v2.y) << 16);
    *(unsigned int*)(Vb + ((size_t)kvh * TT + t) * HEADD + d) = packed;
}

// ---------------------------------------------------------------------------
// V transpose: Vb[kvh][t][128] -> Vt[kvh][128][t]
// ---------------------------------------------------------------------------
__global__ __launch_bounds__(256) void transpose_v(
    const unsigned short* __restrict__ Vb, unsigned short* __restrict__ Vt)
{
    __shared__ unsigned short tile[32][40];
    const int kvh = blockIdx.z;
    const int t0 = blockIdx.x * 32, d0 = blockIdx.y * 32;
    int tid = threadIdx.x;
    int r = tid >> 3, c4 = (tid & 7) * 4;
    ushort4 v = *(const ushort4*)(Vb + ((size_t)kvh * TT + t0 + r) * HEADD + d0 + c4);
    tile[r][c4] = v.x; tile[r][c4 + 1] = v.y;
    tile[r][c4 + 2] = v.z; tile[r][c4 + 3] = v.w;
    __syncthreads();
    ushort4 o;
    o.x = tile[c4 + 0][r];
    o.y = tile[c4 + 1][r];
    o.z = tile[c4 + 2][r];
    o.w = tile[c4 + 3][r];
    *(ushort4*)(Vt + ((size_t)kvh * HEADD + d0 + r) * TT + t0 + c4) = o;
}

// ---------------------------------------------------------------------------
// MFMA flash attention.  grid (NQH, T/64), 256 threads = 4 independent waves.
// ---------------------------------------------------------------------------
__global__ __launch_bounds__(256) void flash_attn_mfma(
    const unsigned short* __restrict__ Qb,
    const unsigned short* __restrict__ Kb,
    const unsigned short* __restrict__ Vt,
    unsigned short* __restrict__ ctx)
{
    __shared__ __align__(16) unsigned short Pl[4][16][72];

    const int h = blockIdx.x;
    const int kvh = h >> 2;
    const int tid = threadIdx.x;
    const int w = tid >> 6;
    const int lane = tid & 63;
    const int l15 = lane & 15;
    const int g = lane >> 4;
    const int q0 = blockIdx.y * 64 + w * 16;

    const unsigned short* Qrow = Qb + ((size_t)h * TT + q0 + l15) * HEADD;
    bf16x8 qf[4];
#pragma unroll
    for (int kk = 0; kk < 4; ++kk)
        qf[kk] = *(const bf16x8*)(Qrow + kk * 32 + g * 8);

    float m_i[4], l_i[4];
#pragma unroll
    for (int r = 0; r < 4; ++r) { m_i[r] = -1e30f; l_i[r] = 0.f; }
    f32x4 of[8] = {};

    const int dtile = q0 >> 6;
    for (int st = 0; st <= dtile; ++st) {
        const int s0 = st * 64;

        f32x4 sacc[4] = {};
        const unsigned short* Kbase = Kb + ((size_t)kvh * TT + s0) * HEADD;
#pragma unroll
        for (int kk = 0; kk < 4; ++kk) {
#pragma unroll
            for (int n = 0; n < 4; ++n) {
                bf16x8 kb = *(const bf16x8*)(Kbase +
                    (size_t)(n * 16 + l15) * HEADD + kk * 32 + g * 8);
                sacc[n] = __builtin_amdgcn_mfma_f32_16x16x32_bf16(
                    qf[kk], kb, sacc[n], 0, 0, 0);
            }
        }

        const bool diag = (st == dtile);
        float alpha[4];
#pragma unroll
        for (int r = 0; r < 4; ++r) {
            const int qrow = q0 + g * 4 + r;
            float sv[4] = {sacc[0][r], sacc[1][r], sacc[2][r], sacc[3][r]};
            if (diag) {
#pragma unroll
                for (int n = 0; n < 4; ++n)
                    if (s0 + n * 16 + l15 > qrow) sv[n] = -1e30f;
            }
            float rm = fmaxf(fmaxf(sv[0], sv[1]), fmaxf(sv[2], sv[3]));
            rm = fmaxf(rm, __shfl_xor(rm, 1));
            rm = fmaxf(rm, __shfl_xor(rm, 2));
            rm = fmaxf(rm, __shfl_xor(rm, 4));
            rm = fmaxf(rm, __shfl_xor(rm, 8));
            float mnew = fmaxf(m_i[r], rm);
            alpha[r] = __expf(m_i[r] - mnew);
            float p0 = __expf(sv[0] - mnew);
            float p1 = __expf(sv[1] - mnew);
            float p2 = __expf(sv[2] - mnew);
            float p3 = __expf(sv[3] - mnew);
            float rs = p0 + p1 + p2 + p3;
            rs += __shfl_xor(rs, 1);
            rs += __shfl_xor(rs, 2);
            rs += __shfl_xor(rs, 4);
            rs += __shfl_xor(rs, 8);
            l_i[r] = l_i[r] * alpha[r] + rs;
            m_i[r] = mnew;
            Pl[w][g * 4 + r][0 * 16 + l15] = f2bf(p0);
            Pl[w][g * 4 + r][1 * 16 + l15] = f2bf(p1);
            Pl[w][g * 4 + r][2 * 16 + l15] = f2bf(p2);
            Pl[w][g * 4 + r][3 * 16 + l15] = f2bf(p3);
        }

#pragma unroll
        for (int nd = 0; nd < 8; ++nd)
#pragma unroll
            for (int r = 0; r < 4; ++r)
                of[nd][r] *= alpha[r];

        const unsigned short* Vbase = Vt + (size_t)kvh * HEADD * TT + s0;
#pragma unroll
        for (int kk2 = 0; kk2 < 2; ++kk2) {
            bf16x8 pa = *(const bf16x8*)&Pl[w][l15][kk2 * 32 + g * 8];
#pragma unroll
            for (int nd = 0; nd < 8; ++nd) {
                bf16x8 vb = *(const bf16x8*)(Vbase +
                    (size_t)(nd * 16 + l15) * TT + kk2 * 32 + g * 8);
                of[nd] = __builtin_amdgcn_mfma_f32_16x16x32_bf16(
                    pa, vb, of[nd], 0, 0, 0);
            }
        }
    }

    float invl[4];
#pragma unroll
    for (int r = 0; r < 4; ++r) invl[r] = 1.f / l_i[r];
#pragma unroll
    for (int nd = 0; nd < 8; ++nd)
#pragma unroll
        for (int r = 0; r < 4; ++r) {
            int trow = q0 + g * 4 + r;
            ctx[(size_t)trow * (NQH * HEADD) + h * HEADD + nd * 16 + l15] =
                f2bf(of[nd][r] * invl[r]);
        }
}

// ---------------------------------------------------------------------------
// Fused router: rmsnorm(resid2)*w . gate_w, softmax top-4 -> comb (T,16)
// ---------------------------------------------------------------------------
__global__ __launch_bounds__(256) void router_fused(
    const float* __restrict__ resid2, const float* __restrict__ w,
    const float* __restrict__ gate_w, float* __restrict__ comb)
{
    int t = blockIdx.x;
    int tid = threadIdx.x;
    int lane = tid & 63, wv = tid >> 6;

    const float4* r4 = (const float4*)(resid2 + (size_t)t * HD);
    float4 xa = r4[tid * 2], xb = r4[tid * 2 + 1];
    float ss = xa.x * xa.x + xa.y * xa.y + xa.z * xa.z + xa.w * xa.w +
               xb.x * xb.x + xb.y * xb.y + xb.z * xb.z + xb.w * xb.w;
    for (int off = 32; off > 0; off >>= 1) ss += __shfl_down(ss, off);
    __shared__ float red[4];
    if (lane == 0) red[wv] = ss;
    __syncthreads();
    float inv = rsqrtf((red[0] + red[1] + red[2] + red[3]) / (float)HD + 1e-6f);

    const float4* w4 = (const float4*)w;
    float4 wa = w4[tid * 2], wb = w4[tid * 2 + 1];
    float xs[8] = {xa.x * wa.x * inv, xa.y * wa.y * inv, xa.z * wa.z * inv,
                   xa.w * wa.w * inv, xb.x * wb.x * inv, xb.y * wb.y * inv,
                   xb.z * wb.z * inv, xb.w * wb.w * inv};

    float acc[16] = {};
    int kbase = tid * 8;
#pragma unroll
    for (int j = 0; j < 8; ++j) {
        float xv = xs[j];
        const float4* wrow = (const float4*)(gate_w + (size_t)(kbase + j) * NEXP);
        float4 w0 = wrow[0], w1 = wrow[1], w2 = wrow[2], w3 = wrow[3];
        acc[0] += xv * w0.x;  acc[1] += xv * w0.y;  acc[2] += xv * w0.z;  acc[3] += xv * w0.w;
        acc[4] += xv * w1.x;  acc[5] += xv * w1.y;  acc[6] += xv * w1.z;  acc[7] += xv * w1.w;
        acc[8] += xv * w2.x;  acc[9] += xv * w2.y;  acc[10] += xv * w2.z; acc[11] += xv * w2.w;
        acc[12] += xv * w3.x; acc[13] += xv * w3.y; acc[14] += xv * w3.z; acc[15] += xv * w3.w;
    }
    __shared__ float red2[4][16];
#pragma unroll
    for (int e = 0; e < 16; ++e) {
        float v = acc[e];
        v += __shfl_xor(v, 1);
        v += __shfl_xor(v, 2);
        v += __shfl_xor(v, 4);
        v += __shfl_xor(v, 8);
        v += __shfl_xor(v, 16);
        v += __shfl_xor(v, 32);
        if (lane == 0) red2[wv][e] = v;
    }
    __syncthreads();

    if (tid == 0) {
        float l[NEXP];
#pragma unroll
        for (int e = 0; e < NEXP; ++e)
            l[e] = red2[0][e] + red2[1][e] + red2[2][e] + red2[3][e];
        int sel[TOPK];
        float selv[TOPK];
        bool used[NEXP] = {};
#pragma unroll
        for (int r = 0; r < TOPK; ++r) {
            int best = -1;
            float bv = -1e30f;
            for (int e = 0; e < NEXP; ++e)
                if (!used[e] && l[e] > bv) { bv = l[e]; best = e; }
            used[best] = true;
            sel[r] = best;
            selv[r] = bv;
        }
        float mx = selv[0];
        float wsum = 0.f, wvv[TOPK];
#pragma unroll
        for (int r = 0; r < TOPK; ++r) { wvv[r] = __expf(selv[r] - mx); wsum += wvv[r]; }
        float out16[NEXP] = {};
#pragma unroll
        for (int r = 0; r < TOPK; ++r) out16[sel[r]] = wvv[r] / wsum;
#pragma unroll
        for (int e = 0; e < NEXP; ++e) comb[(size_t)t * NEXP + e] = out16[e];
    }
}

// ---------------------------------------------------------------------------
extern "C" void kernel_launch(void* const* d_in, const int* in_sizes, int n_in,
                              void* d_out, int out_size, void* d_ws, size_t ws_size,
                              hipStream_t stream)
{
    const float* hidden   = (const float*)d_in[0];
    const float* residual = (const float*)d_in[1];
    const float* rms1_w   = (const float*)d_in[2];
    const float* rms2_w   = (const float*)d_in[3];
    const float* w_qkv    = (const float*)d_in[4];
    const float* w_dense  = (const float*)d_in[5];
    const float* gate_w   = (const float*)d_in[6];
    const float* w13      = (const float*)d_in[7];
    const float* w2       = (const float*)d_in[8];
    const float* sw13     = (const float*)d_in[9];
    const float* sw2      = (const float*)d_in[10];
    const int*   pos_ids  = (const int*)d_in[11];

    const int T = TT;

    float* out0 = (float*)d_out;
    float* out1 = (float*)d_out + (size_t)T * HD;

    // ---- workspace layout ----
    char* base = (char*)d_ws;
    float*          residF = (float*)(base);                    //  8.39 MB
    unsigned short* xB     = (unsigned short*)(base + 8388608); //  4.19 MB
    unsigned short* ctxB   = (unsigned short*)(base + 12582912);//  4.19 MB
    unsigned short* actB   = (unsigned short*)(base);           // 16.78 MB alias (residF,xB,ctxB dead)
    float*          qkvF   = (float*)(base + 16777216);         // 12.58 MB
    unsigned short* x2B    = (unsigned short*)(base + 29360128);//  4.19 MB
    unsigned short* sactB  = (unsigned short*)(base + 33554432);//  2.10 MB
    float*          comb   = (float*)(base + 35651584);         //  0.07 MB
    float*          part   = (float*)(base + 35717120);         // 33.55 MB
    unsigned short* Wbuf   = (unsigned short*)(base + 69271552);// 67.11 MB
    int*            lists  = (int*)(base + 139526144);          //  0.07 MB
    int*            cnts   = (int*)(base + 139591680);          //  64 B

    // attention bf16 buffers alias the split-K `part` region (dead there)
    unsigned short* Qb = (unsigned short*)(base + 35717120);            // 4 MB
    unsigned short* Kb = Qb + (size_t)NQH * TT * HEADD;                 // 1 MB
    unsigned short* Vb = Kb + (size_t)NKVH * TT * HEADD;                // 1 MB
    unsigned short* Vt = Vb + (size_t)NKVH * TT * HEADD;                // 1 MB

    dim3 blk(256);

    // 1. resid = hidden + residual ; x = rmsnorm -> bf16
    add_rmsnorm_kernel<<<dim3(T), blk, 0, stream>>>(
        hidden, residual, rms1_w, residF, xB);

    // 2. qkv = x @ w_qkv   (split-K x2)
    transpose_convert<<<dim3(QKVN / 32, HD / 32), blk, 0, stream>>>(
        w_qkv, Wbuf, HD, QKVN, 0, 0);
    gemm_splitk<<<dim3(QKVN / 128, T / 128, 2), blk, 0, stream>>>(
        xB, Wbuf, part, T, QKVN, 1024, HD, HD);
    reduce_partials<<<dim3(1024), blk, 0, stream>>>(
        part, 2, T * QKVN / 4, nullptr, qkvF, 0);

    // 3. RoPE + pack head-major bf16 ; V transpose
    rope_pack<<<dim3(T), blk, 0, stream>>>(qkvF, pos_ids, Qb, Kb, Vb);
    transpose_v<<<dim3(T / 32, HEADD / 32, NKVH), blk, 0, stream>>>(Vb, Vt);

    // 4. MFMA flash attention -> ctx (bf16)
    flash_attn_mfma<<<dim3(NQH, T / 64), blk, 0, stream>>>(Qb, Kb, Vt, ctxB);

    // 5. resid2 = ctx @ w_dense + resid -> out1   (split-K x4)
    transpose_convert<<<dim3(HD / 32, HD / 32), blk, 0, stream>>>(
        w_dense, Wbuf, HD, HD, 0, 0);
    gemm_splitk<<<dim3(HD / 128, T / 128, 4), blk, 0, stream>>>(
        ctxB, Wbuf, part, T, HD, 512, HD, HD);
    reduce_partials<<<dim3(1024), blk, 0, stream>>>(
        part, 4, T * HD / 4, residF, out1, 0);

    // 6. x2 = rmsnorm(resid2) -> bf16
    add_rmsnorm_kernel<<<dim3(T), blk, 0, stream>>>(
        out1, nullptr, rms2_w, nullptr, x2B);

    // 7. fused router -> comb ; 8. expert token lists
    router_fused<<<dim3(T), blk, 0, stream>>>(out1, rms2_w, gate_w, comb);
    build_lists<<<dim3(NEXP), blk, 0, stream>>>(comb, lists, cnts);

    // 9. shared gu = x2 @ sw13  (split-K x4) -> part
    transpose_convert<<<dim3(HD / 32, HD / 32), blk, 0, stream>>>(
        sw13, Wbuf, HD, 2 * SSI, 0, 0);
    gemm_splitk<<<dim3(HD / 128, T / 128, 4), blk, 0, stream>>>(
        x2B, Wbuf, part, T, 2 * SSI, 512, HD, HD);

    // 10. fused reduce + SwiGLU -> sactB (bf16)
    reduce_swiglu<<<dim3(T * SSI / 4 / 256), blk, 0, stream>>>(part, 4, sactB);

    // 11. out0 = shared_act @ sw2  (split-K x4)
    transpose_convert<<<dim3(HD / 32, SSI / 32), blk, 0, stream>>>(
        sw2, Wbuf, SSI, HD, 0, 0);
    gemm_splitk<<<dim3(HD / 128, T / 128, 4), blk, 0, stream>>>(
        sactB, Wbuf, part, T, HD, 256, SSI, SSI);
    reduce_partials<<<dim3(1024), blk, 0, stream>>>(
        part, 4, T * HD / 4, nullptr, out0, 0);

    // 12. sparse expert up + fused SwiGLU*comb -> dense actB (zeroed first)
    hipMemsetAsync(actB, 0, (size_t)T * NEXP * EI * 2, stream);
    transpose_convert<<<dim3(1024 / 32, HD / 32, NEXP), blk, 0, stream>>>(
        w13, Wbuf, HD, 1024, (long long)HD * 1024, (long long)1024 * HD);
    moe_up_gather<<<dim3(EI / 128, 16, NEXP), blk, 0, stream>>>(
        x2B, Wbuf, comb, lists, cnts, actB);

    // 13. out0 += act @ w2   (split-K x4 over K=8192)
    transpose_convert<<<dim3(HD / 32, (NEXP * EI) / 32), blk, 0, stream>>>(
        w2, Wbuf, NEXP * EI, HD, 0, 0);
    gemm_splitk<<<dim3(HD / 128, T / 128, 4), blk, 0, stream>>>(
        actB, Wbuf, part, T, HD, 2048, NEXP * EI, NEXP * EI);
    reduce_partials<<<dim3(1024), blk, 0, stream>>>(
        part, 4, T * HD / 4, nullptr, out0, 1);
}

// Round 7
// 404.850 us; speedup vs baseline: 18.6792x; 1.1800x over previous
//
#include <hip/hip_runtime.h>
#include <math.h>

// ---------------------------------------------------------------------------
// Problem constants
// ---------------------------------------------------------------------------
#define HD 2048      // hidden size h
#define NQH 16       // num q heads
#define NKVH 4       // num kv heads
#define HEADD 128    // head dim
#define QKVN 3072    // qkv cols
#define NEXP 16      // experts
#define EI 512       // expert intermediate
#define SSI 1024     // shared intermediate
#define TOPK 4
#define TT 1024      // tokens

typedef __bf16 bf16x8 __attribute__((ext_vector_type(8)));
typedef float f32x4 __attribute__((ext_vector_type(4)));

static __device__ __forceinline__ unsigned short f2bf(float f) {
    union { float f; unsigned int u; } v; v.f = f;
    unsigned int r = v.u + 0x7fff + ((v.u >> 16) & 1);
    return (unsigned short)(r >> 16);
}

static __device__ __forceinline__ void gl_lds16(const unsigned short* g,
                                                unsigned short* l) {
    __builtin_amdgcn_global_load_lds(
        (const __attribute__((address_space(1))) unsigned int*)g,
        (__attribute__((address_space(3))) unsigned int*)l, 16, 0, 0);
}

// ---------------------------------------------------------------------------
// Fused add + RMSNorm. resid_out(f32 opt) ; x_bf (bf16)
// ---------------------------------------------------------------------------
__global__ __launch_bounds__(256) void add_rmsnorm_kernel(
    const float* __restrict__ a, const float* __restrict__ b,
    const float* __restrict__ w, float* __restrict__ resid_out,
    unsigned short* __restrict__ x_bf)
{
    int t = blockIdx.x;
    int tid = threadIdx.x;
    const float4* a4 = (const float4*)(a + (size_t)t * HD);
    const float4* b4 = b ? (const float4*)(b + (size_t)t * HD) : nullptr;
    float4* r4 = resid_out ? (float4*)(resid_out + (size_t)t * HD) : nullptr;
    const float4* w4 = (const float4*)w;

    float4 v[2];
    float ss = 0.f;
#pragma unroll
    for (int l = 0; l < 2; ++l) {
        int idx = tid + l * 256;
        float4 va = a4[idx];
        if (b4) {
            float4 vb = b4[idx];
            va.x += vb.x; va.y += vb.y; va.z += vb.z; va.w += vb.w;
        }
        if (r4) r4[idx] = va;
        v[l] = va;
        ss += va.x * va.x + va.y * va.y + va.z * va.z + va.w * va.w;
    }
    for (int off = 32; off > 0; off >>= 1) ss += __shfl_down(ss, off);
    __shared__ float red[4];
    int lane = tid & 63, wv = tid >> 6;
    if (lane == 0) red[wv] = ss;
    __syncthreads();
    if (tid == 0) {
        float s = red[0] + red[1] + red[2] + red[3];
        red[0] = rsqrtf(s / (float)HD + 1e-6f);
    }
    __syncthreads();
    float inv = red[0];
#pragma unroll
    for (int l = 0; l < 2; ++l) {
        int idx = tid + l * 256;
        float4 va = v[l], vw = w4[idx];
        ushort4 ob;
        ob.x = f2bf(va.x * inv * vw.x);
        ob.y = f2bf(va.y * inv * vw.y);
        ob.z = f2bf(va.z * inv * vw.z);
        ob.w = f2bf(va.w * inv * vw.w);
        ((ushort4*)(x_bf + (size_t)t * HD))[idx] = ob;
    }
}

// ---------------------------------------------------------------------------
// Transpose + convert: f32 in [K][N] -> bf16 out [N][K]   (per-z strides)
// ---------------------------------------------------------------------------
__global__ __launch_bounds__(256) void transpose_convert(
    const float* __restrict__ in, unsigned short* __restrict__ out,
    int K, int N, long long strideIn, long long strideOut)
{
    __shared__ float tile[32][33];
    const int n0 = blockIdx.x * 32;
    const int k0 = blockIdx.y * 32;
    const float* ip = in + (size_t)blockIdx.z * strideIn;
    unsigned short* op = out + (size_t)blockIdx.z * strideOut;
    int tid = threadIdx.x;
    int r = tid >> 3, c = (tid & 7) * 4;
    float4 v = *(const float4*)(ip + (size_t)(k0 + r) * N + n0 + c);
    tile[r][c] = v.x; tile[r][c + 1] = v.y; tile[r][c + 2] = v.z; tile[r][c + 3] = v.w;
    __syncthreads();
    ushort4 o;
    o.x = f2bf(tile[c + 0][r]);
    o.y = f2bf(tile[c + 1][r]);
    o.z = f2bf(tile[c + 2][r]);
    o.w = f2bf(tile[c + 3][r]);
    *(ushort4*)(op + (size_t)(n0 + r) * K + k0 + c) = o;
}

// ---------------------------------------------------------------------------
// Split-K bf16 MFMA GEMM, STAGE-early double-buffered, BK=64.
// ---------------------------------------------------------------------------
#define SBK 64

__global__ __launch_bounds__(256) void gemm_splitk(
    const unsigned short* __restrict__ A, const unsigned short* __restrict__ B,
    float* __restrict__ Cpart, int M, int N, int Kc, int ldA, int ldB)
{
    __shared__ unsigned short As[2][128 * SBK];
    __shared__ unsigned short Bs[2][128 * SBK];

    const int tid = threadIdx.x;
    const int wave = tid >> 6;
    const int lane = tid & 63;
    const int wr = wave >> 1, wc = wave & 1;
    const int l15 = lane & 15;
    const int row0 = blockIdx.y * 128;
    const int col0 = blockIdx.x * 128;
    const int z = blockIdx.z;

    const unsigned short* Ap = A + (size_t)row0 * ldA + (size_t)z * Kc;
    const unsigned short* Bp = B + (size_t)col0 * ldB + (size_t)z * Kc;

    const int r_st = tid >> 3;
    const int q_st = tid & 7;
    const int csrc = (q_st ^ (r_st & 7)) << 3;

    f32x4 acc[4][4] = {};

    const int nsteps = Kc / SBK;

#define STAGE_SK(buf, k0s)                                                    \
    {                                                                         \
        _Pragma("unroll")                                                     \
        for (int i = 0; i < 4; ++i) {                                         \
            int rr = r_st + i * 32;                                           \
            gl_lds16(Ap + (size_t)rr * ldA + (k0s) + csrc,                    \
                     &As[buf][rr * SBK + q_st * 8]);                          \
            gl_lds16(Bp + (size_t)rr * ldB + (k0s) + csrc,                    \
                     &Bs[buf][rr * SBK + q_st * 8]);                          \
        }                                                                     \
    }

    STAGE_SK(0, 0);
    __syncthreads();

    for (int s = 0; s < nsteps; ++s) {
        const int cur = s & 1;
        if (s + 1 < nsteps) STAGE_SK(cur ^ 1, (s + 1) * SBK);

#pragma unroll
        for (int half = 0; half < 2; ++half) {
            const int q = half * 4 + (lane >> 4);
            bf16x8 af[4], bfv[4];
#pragma unroll
            for (int i = 0; i < 4; ++i) {
                int R = wr * 64 + i * 16 + l15;
                af[i] = *(const bf16x8*)&As[cur][R * SBK + ((q ^ (R & 7)) << 3)];
            }
#pragma unroll
            for (int j = 0; j < 4; ++j) {
                int R = wc * 64 + j * 16 + l15;
                bfv[j] = *(const bf16x8*)&Bs[cur][R * SBK + ((q ^ (R & 7)) << 3)];
            }
#pragma unroll
            for (int mi = 0; mi < 4; ++mi)
#pragma unroll
                for (int nj = 0; nj < 4; ++nj)
                    acc[mi][nj] = __builtin_amdgcn_mfma_f32_16x16x32_bf16(
                        af[mi], bfv[nj], acc[mi][nj], 0, 0, 0);
        }
        __syncthreads();
    }

    float* Cp = Cpart + (size_t)z * M * N;
#pragma unroll
    for (int mi = 0; mi < 4; ++mi)
#pragma unroll
        for (int nj = 0; nj < 4; ++nj)
#pragma unroll
            for (int r = 0; r < 4; ++r) {
                int row = row0 + wr * 64 + mi * 16 + (lane >> 4) * 4 + r;
                int col = col0 + wc * 64 + nj * 16 + l15;
                Cp[(size_t)row * N + col] = acc[mi][nj][r];
            }
}

// ---------------------------------------------------------------------------
// Reduce split-K partials: out = sum_z part[z] (+ add) (+= out if acc)
// ---------------------------------------------------------------------------
__global__ __launch_bounds__(256) void reduce_partials(
    const float* __restrict__ part, int ns, int n4,
    const float* __restrict__ add, float* __restrict__ out, int acc)
{
    const float4* p4 = (const float4*)part;
    const float4* a4 = (const float4*)add;
    float4* o4 = (float4*)out;
    for (int idx = blockIdx.x * 256 + threadIdx.x; idx < n4;
         idx += gridDim.x * 256) {
        float4 s = p4[idx];
        for (int z = 1; z < ns; ++z) {
            float4 q = p4[(size_t)z * n4 + idx];
            s.x += q.x; s.y += q.y; s.z += q.z; s.w += q.w;
        }
        if (add) {
            float4 q = a4[idx];
            s.x += q.x; s.y += q.y; s.z += q.z; s.w += q.w;
        }
        if (acc) {
            float4 q = o4[idx];
            s.x += q.x; s.y += q.y; s.z += q.z; s.w += q.w;
        }
        o4[idx] = s;
    }
}

// ---------------------------------------------------------------------------
// Reduce split-K partials of shared-expert gu [T][2048] + SwiGLU -> bf16
// ---------------------------------------------------------------------------
__global__ __launch_bounds__(256) void reduce_swiglu(
    const float* __restrict__ part, int ns, unsigned short* __restrict__ out)
{
    int idx4 = blockIdx.x * 256 + threadIdx.x;
    int t = idx4 >> 8;
    int i4 = (idx4 & 255) * 4;
    const float4* pg = (const float4*)(part + (size_t)t * (2 * SSI) + i4);
    const float4* pu = (const float4*)(part + (size_t)t * (2 * SSI) + SSI + i4);
    float4 g = pg[0], u = pu[0];
    for (int z = 1; z < ns; ++z) {
        float4 g2 = *(const float4*)((const float*)pg + (size_t)z * TT * 2 * SSI);
        float4 u2 = *(const float4*)((const float*)pu + (size_t)z * TT * 2 * SSI);
        g.x += g2.x; g.y += g2.y; g.z += g2.z; g.w += g2.w;
        u.x += u2.x; u.y += u2.y; u.z += u2.z; u.w += u2.w;
    }
    ushort4 o;
    o.x = f2bf((g.x / (1.f + __expf(-g.x))) * u.x);
    o.y = f2bf((g.y / (1.f + __expf(-g.y))) * u.y);
    o.z = f2bf((g.z / (1.f + __expf(-g.z))) * u.z);
    o.w = f2bf((g.w / (1.f + __expf(-g.w))) * u.w);
    *(ushort4*)(out + (size_t)t * SSI + i4) = o;
}

// ---------------------------------------------------------------------------
// Build per-expert token lists from comb (token-ordered, deterministic).
// ---------------------------------------------------------------------------
__global__ __launch_bounds__(256) void build_lists(
    const float* __restrict__ comb, int* __restrict__ lists,
    int* __restrict__ cnts)
{
    int e = blockIdx.x;
    int tid = threadIdx.x;
    __shared__ int sc[256];
    int loc[4];
    int c = 0;
#pragma unroll
    for (int j = 0; j < 4; ++j) {
        int t = tid * 4 + j;
        if (comb[(size_t)t * NEXP + e] > 0.f) loc[c++] = t;
    }
    sc[tid] = c;
    __syncthreads();
    for (int off = 1; off < 256; off <<= 1) {
        int v = (tid >= off) ? sc[tid - off] : 0;
        __syncthreads();
        sc[tid] += v;
        __syncthreads();
    }
    int base = sc[tid] - c;
    for (int i = 0; i < c; ++i) lists[e * TT + base + i] = loc[i];
    if (tid == 255) cnts[e] = sc[255];
}

// ---------------------------------------------------------------------------
// Sparse MoE expert-up + fused SwiGLU*comb -> dense actB (zero-filled).
// ---------------------------------------------------------------------------
__global__ __launch_bounds__(256) void moe_up_gather(
    const unsigned short* __restrict__ x2B,
    const unsigned short* __restrict__ w13T,
    const float* __restrict__ comb,
    const int* __restrict__ lists,
    const int* __restrict__ cnts,
    unsigned short* __restrict__ actB)
{
    __shared__ unsigned short As[2][64 * 32];
    __shared__ unsigned short Bgs[2][128 * 32];
    __shared__ unsigned short Bus[2][128 * 32];

    const int e = blockIdx.z;
    const int cnt = cnts[e];
    const int m0 = blockIdx.y * 64;
    if (m0 >= cnt) return;
    const int n0 = blockIdx.x * 128;

    const int tid = threadIdx.x;
    const int w = tid >> 6;
    const int lane = tid & 63;
    const int l15 = lane & 15;
    const int g = lane >> 4;

    const int r_st = tid >> 2;
    const int q_st = tid & 3;
    const int swz = (q_st ^ (r_st & 3)) << 3;

    int arow = m0 + r_st;
    int atok = lists[e * TT + (arow < cnt ? arow : cnt - 1)];
    const unsigned short* Asrc = x2B + (size_t)atok * HD;
    const unsigned short* Bbase = w13T + (size_t)e * 1024 * HD;

    f32x4 ag[4][2] = {};
    f32x4 au[4][2] = {};

#define STAGE_UP(buf, k0s)                                                    \
    {                                                                         \
        gl_lds16(Asrc + (k0s) + swz, &As[buf][r_st * 32 + q_st * 8]);         \
        _Pragma("unroll")                                                     \
        for (int i = 0; i < 2; ++i) {                                         \
            int rr = r_st + i * 64;                                           \
            gl_lds16(Bbase + (size_t)(n0 + rr) * HD + (k0s) + swz,            \
                     &Bgs[buf][rr * 32 + q_st * 8]);                          \
            gl_lds16(Bbase + (size_t)(512 + n0 + rr) * HD + (k0s) + swz,      \
                     &Bus[buf][rr * 32 + q_st * 8]);                          \
        }                                                                     \
    }

    STAGE_UP(0, 0);
    __syncthreads();

    const int nsteps = HD / 32;
    for (int s = 0; s < nsteps; ++s) {
        const int cur = s & 1;
        if (s + 1 < nsteps) STAGE_UP(cur ^ 1, (s + 1) * 32);

        bf16x8 af[4], bg[2], bu[2];
#pragma unroll
        for (int i = 0; i < 4; ++i) {
            int R = i * 16 + l15;
            af[i] = *(const bf16x8*)&As[cur][R * 32 + ((g ^ (R & 3)) << 3)];
        }
#pragma unroll
        for (int j = 0; j < 2; ++j) {
            int R = w * 32 + j * 16 + l15;
            int off = R * 32 + ((g ^ (R & 3)) << 3);
            bg[j] = *(const bf16x8*)&Bgs[cur][off];
            bu[j] = *(const bf16x8*)&Bus[cur][off];
        }
#pragma unroll
        for (int mi = 0; mi < 4; ++mi)
#pragma unroll
            for (int nj = 0; nj < 2; ++nj) {
                ag[mi][nj] = __builtin_amdgcn_mfma_f32_16x16x32_bf16(
                    af[mi], bg[nj], ag[mi][nj], 0, 0, 0);
                au[mi][nj] = __builtin_amdgcn_mfma_f32_16x16x32_bf16(
                    af[mi], bu[nj], au[mi][nj], 0, 0, 0);
            }
        __syncthreads();
    }

#pragma unroll
    for (int mi = 0; mi < 4; ++mi) {
#pragma unroll
        for (int r = 0; r < 4; ++r) {
            int grow = m0 + mi * 16 + g * 4 + r;
            if (grow >= cnt) continue;
            int tok = lists[e * TT + grow];
            float cw = comb[(size_t)tok * NEXP + e];
#pragma unroll
            for (int nj = 0; nj < 2; ++nj) {
                int col = n0 + w * 32 + nj * 16 + l15;
                float gg = ag[mi][nj][r];
                float uu = au[mi][nj][r];
                float v = (gg / (1.f + __expf(-gg))) * uu * cw;
                actB[(size_t)tok * (NEXP * EI) + e * EI + col] = f2bf(v);
            }
        }
    }
}

// ---------------------------------------------------------------------------
// RoPE + pack to head-major bf16.  One block per token, 256 threads.
// ---------------------------------------------------------------------------
__global__ __launch_bounds__(256) void rope_pack(
    const float* __restrict__ qkv, const int* __restrict__ pos_ids,
    unsigned short* __restrict__ Qb, unsigned short* __restrict__ Kb,
    unsigned short* __restrict__ Vb)
{
    const float SCALE = 0.08838834764831843f;
    int t = blockIdx.x;
    int tid = threadIdx.x;
    int w = tid >> 6, lane = tid & 63;
    float pos = (float)pos_ids[t];
    float invf = powf(10000.0f, -(float)lane * (1.0f / 64.0f));
    float ang = pos * invf;
    float c = cosf(ang);
    float s = sinf(ang);
    const float* row = qkv + (size_t)t * QKVN;
#pragma unroll
    for (int j = 0; j < 5; ++j) {
        int hh = w * 5 + j;
        const float* hb = row + hh * HEADD;
        float x1 = hb[lane], x2 = hb[lane + 64];
        float o1 = x1 * c - x2 * s;
        float o2 = x2 * c + x1 * s;
        if (hh < NQH) {
            unsigned short* qp = Qb + ((size_t)hh * TT + t) * HEADD;
            qp[lane] = f2bf(o1 * SCALE);
            qp[lane + 64] = f2bf(o2 * SCALE);
        } else {
            unsigned short* kp = Kb + ((size_t)(hh - NQH) * TT + t) * HEADD;
            kp[lane] = f2bf(o1);
            kp[lane + 64] = f2bf(o2);
        }
    }
    float2 v2 = *(const float2*)(row + 2560 + tid * 2);
    int kvh = tid >> 6;
    int d = (tid * 2) & 127;
    unsigned int packed = (unsigned int)f2bf(v2.x) |
                          ((unsigned int)f2bf(v2.y) << 16);
    *(unsigned int*)(Vb + ((size_t)kvh * TT + t) * HEADD + d) = packed;
}

// ---------------------------------------------------------------------------
// V transpose: Vb[kvh][t][128] -> Vt[kvh][128][t]
// ---------------------------------------------------------------------------
__global__ __launch_bounds__(256) void transpose_v(
    const unsigned short* __restrict__ Vb, unsigned short* __restrict__ Vt)
{
    __shared__ unsigned short tile[32][40];
    const int kvh = blockIdx.z;
    const int t0 = blockIdx.x * 32, d0 = blockIdx.y * 32;
    int tid = threadIdx.x;
    int r = tid >> 3, c4 = (tid & 7) * 4;
    ushort4 v = *(const ushort4*)(Vb + ((size_t)kvh * TT + t0 + r) * HEADD + d0 + c4);
    tile[r][c4] = v.x; tile[r][c4 + 1] = v.y;
    tile[r][c4 + 2] = v.z; tile[r][c4 + 3] = v.w;
    __syncthreads();
    ushort4 o;
    o.x = tile[c4 + 0][r];
    o.y = tile[c4 + 1][r];
    o.z = tile[c4 + 2][r];
    o.w = tile[c4 + 3][r];
    *(ushort4*)(Vt + ((size_t)kvh * HEADD + d0 + r) * TT + t0 + c4) = o;
}

// ---------------------------------------------------------------------------
// MFMA flash attention v2 — LDS-staged K/V, double-buffered, triangle-paired.
// grid (NQH, 8 pairs, 2 row-halves), 128 threads = 2 waves.
// Block processes q-tile p then q-tile 15-p (17 s-tiles total, uniform).
// Each wave owns 16 q-rows.  K tile [64][128], V^T tile [128][64] in LDS,
// source-pre-swizzled (chunk ^= row&7) for conflict-free ds_read_b128.
// ---------------------------------------------------------------------------
__global__ __launch_bounds__(128) void flash_attn_mfma(
    const unsigned short* __restrict__ Qb,  // [NQH][T][128] (pre-scaled)
    const unsigned short* __restrict__ Kb,  // [NKVH][T][128]
    const unsigned short* __restrict__ Vt,  // [NKVH][128][T]
    unsigned short* __restrict__ ctx)       // [T][NQH*128]
{
    __shared__ __align__(16) unsigned short Ks[2][64 * 128];
    __shared__ __align__(16) unsigned short Vs[2][128 * 64];
    __shared__ __align__(16) unsigned short Pl[2][16][72];

    const int h   = blockIdx.x;
    const int p   = blockIdx.y;
    const int rh  = blockIdx.z;
    const int kvh = h >> 2;
    const int tid = threadIdx.x;
    const int w   = tid >> 6;
    const int lane = tid & 63;
    const int l15 = lane & 15;
    const int g   = lane >> 4;

    // staging coords
    const int krow = tid >> 4;           // K: rows 0..63 over 2 iters? no:
    const int kch  = tid & 15;           // 1024 chunks, idx = tid + i*128
    const int vch  = tid & 7;            // V: row = idx>>3

    const unsigned short* Kh = Kb + (size_t)kvh * TT * HEADD;
    const unsigned short* Vh = Vt + (size_t)kvh * HEADD * TT;

#define STAGE_KV(buf, s0s)                                                    \
    {                                                                         \
        _Pragma("unroll")                                                     \
        for (int i = 0; i < 8; ++i) {                                         \
            int idx = tid + i * 128;                                          \
            int r = idx >> 4, c = idx & 15;                                   \
            int csw = (c & 8) | ((c ^ r) & 7);                                \
            gl_lds16(Kh + (size_t)((s0s) + r) * HEADD + csw * 8,              \
                     &Ks[buf][idx * 8]);                                      \
        }                                                                     \
        _Pragma("unroll")                                                     \
        for (int i = 0; i < 8; ++i) {                                         \
            int idx = tid + i * 128;                                          \
            int r = idx >> 3, c = idx & 7;                                    \
            int csw = (c ^ r) & 7;                                            \
            gl_lds16(Vh + (size_t)r * TT + (s0s) + csw * 8,                   \
                     &Vs[buf][idx * 8]);                                      \
        }                                                                     \
    }

    const int qts[2] = {p, 15 - p};

#pragma unroll
    for (int qi = 0; qi < 2; ++qi) {
        const int qt = qts[qi];
        const int q0 = qt * 64 + rh * 32 + w * 16;
        const int ntiles = qt + 1;

        // Q fragments (row l15, chunk g*8 within each 32-k block)
        const unsigned short* Qrow = Qb + ((size_t)h * TT + q0 + l15) * HEADD;
        bf16x8 qf[4];
#pragma unroll
        for (int kk = 0; kk < 4; ++kk)
            qf[kk] = *(const bf16x8*)(Qrow + kk * 32 + g * 8);

        float m_i[4], l_i[4];
#pragma unroll
        for (int r = 0; r < 4; ++r) { m_i[r] = -1e30f; l_i[r] = 0.f; }
        f32x4 of[8] = {};

        STAGE_KV(0, 0);
        __syncthreads();

        for (int st = 0; st < ntiles; ++st) {
            const int cur = st & 1;
            const int s0 = st * 64;
            if (st + 1 < ntiles) STAGE_KV(cur ^ 1, (st + 1) * 64);

            // ---- S = Q K^T  (K from LDS, swizzled) ----
            f32x4 sacc[4] = {};
#pragma unroll
            for (int kk = 0; kk < 4; ++kk) {
#pragma unroll
                for (int n = 0; n < 4; ++n) {
                    int R = n * 16 + l15;
                    int cidx = kk * 4 + g;
                    int cs = (cidx & 8) | ((cidx ^ R) & 7);
                    bf16x8 kb = *(const bf16x8*)&Ks[cur][R * 128 + cs * 8];
                    sacc[n] = __builtin_amdgcn_mfma_f32_16x16x32_bf16(
                        qf[kk], kb, sacc[n], 0, 0, 0);
                }
            }

            // ---- online softmax ----
            const bool diag = (st == qt);
            float alpha[4];
#pragma unroll
            for (int r = 0; r < 4; ++r) {
                const int qrow = q0 + g * 4 + r;
                float sv[4] = {sacc[0][r], sacc[1][r], sacc[2][r], sacc[3][r]};
                if (diag) {
#pragma unroll
                    for (int n = 0; n < 4; ++n)
                        if (s0 + n * 16 + l15 > qrow) sv[n] = -1e30f;
                }
                float rm = fmaxf(fmaxf(sv[0], sv[1]), fmaxf(sv[2], sv[3]));
                rm = fmaxf(rm, __shfl_xor(rm, 1));
                rm = fmaxf(rm, __shfl_xor(rm, 2));
                rm = fmaxf(rm, __shfl_xor(rm, 4));
                rm = fmaxf(rm, __shfl_xor(rm, 8));
                float mnew = fmaxf(m_i[r], rm);
                alpha[r] = __expf(m_i[r] - mnew);
                float p0 = __expf(sv[0] - mnew);
                float p1 = __expf(sv[1] - mnew);
                float p2 = __expf(sv[2] - mnew);
                float p3 = __expf(sv[3] - mnew);
                float rs = p0 + p1 + p2 + p3;
                rs += __shfl_xor(rs, 1);
                rs += __shfl_xor(rs, 2);
                rs += __shfl_xor(rs, 4);
                rs += __shfl_xor(rs, 8);
                l_i[r] = l_i[r] * alpha[r] + rs;
                m_i[r] = mnew;
                Pl[w][g * 4 + r][0 * 16 + l15] = f2bf(p0);
                Pl[w][g * 4 + r][1 * 16 + l15] = f2bf(p1);
                Pl[w][g * 4 + r][2 * 16 + l15] = f2bf(p2);
                Pl[w][g * 4 + r][3 * 16 + l15] = f2bf(p3);
            }

            // ---- O rescale ----
#pragma unroll
            for (int nd = 0; nd < 8; ++nd)
#pragma unroll
                for (int r = 0; r < 4; ++r)
                    of[nd][r] *= alpha[r];

            // ---- PV  (V from LDS, swizzled) ----
#pragma unroll
            for (int kk2 = 0; kk2 < 2; ++kk2) {
                bf16x8 pa = *(const bf16x8*)&Pl[w][l15][kk2 * 32 + g * 8];
#pragma unroll
                for (int nd = 0; nd < 8; ++nd) {
                    int R = nd * 16 + l15;
                    int cidx = kk2 * 4 + g;
                    int cs = (cidx ^ R) & 7;
                    bf16x8 vb = *(const bf16x8*)&Vs[cur][R * 64 + cs * 8];
                    of[nd] = __builtin_amdgcn_mfma_f32_16x16x32_bf16(
                        pa, vb, of[nd], 0, 0, 0);
                }
            }
            __syncthreads();
        }

        // ---- finalize ----
        float invl[4];
#pragma unroll
        for (int r = 0; r < 4; ++r) invl[r] = 1.f / l_i[r];
#pragma unroll
        for (int nd = 0; nd < 8; ++nd)
#pragma unroll
            for (int r = 0; r < 4; ++r) {
                int trow = q0 + g * 4 + r;
                ctx[(size_t)trow * (NQH * HEADD) + h * HEADD + nd * 16 + l15] =
                    f2bf(of[nd][r] * invl[r]);
            }
    }
}

// ---------------------------------------------------------------------------
// Fused router: rmsnorm(resid2)*w . gate_w, softmax top-4 -> comb (T,16)
// ---------------------------------------------------------------------------
__global__ __launch_bounds__(256) void router_fused(
    const float* __restrict__ resid2, const float* __restrict__ w,
    const float* __restrict__ gate_w, float* __restrict__ comb)
{
    int t = blockIdx.x;
    int tid = threadIdx.x;
    int lane = tid & 63, wv = tid >> 6;

    const float4* r4 = (const float4*)(resid2 + (size_t)t * HD);
    float4 xa = r4[tid * 2], xb = r4[tid * 2 + 1];
    float ss = xa.x * xa.x + xa.y * xa.y + xa.z * xa.z + xa.w * xa.w +
               xb.x * xb.x + xb.y * xb.y + xb.z * xb.z + xb.w * xb.w;
    for (int off = 32; off > 0; off >>= 1) ss += __shfl_down(ss, off);
    __shared__ float red[4];
    if (lane == 0) red[wv] = ss;
    __syncthreads();
    float inv = rsqrtf((red[0] + red[1] + red[2] + red[3]) / (float)HD + 1e-6f);

    const float4* w4 = (const float4*)w;
    float4 wa = w4[tid * 2], wb = w4[tid * 2 + 1];
    float xs[8] = {xa.x * wa.x * inv, xa.y * wa.y * inv, xa.z * wa.z * inv,
                   xa.w * wa.w * inv, xb.x * wb.x * inv, xb.y * wb.y * inv,
                   xb.z * wb.z * inv, xb.w * wb.w * inv};

    float acc[16] = {};
    int kbase = tid * 8;
#pragma unroll
    for (int j = 0; j < 8; ++j) {
        float xv = xs[j];
        const float4* wrow = (const float4*)(gate_w + (size_t)(kbase + j) * NEXP);
        float4 w0 = wrow[0], w1 = wrow[1], w2 = wrow[2], w3 = wrow[3];
        acc[0] += xv * w0.x;  acc[1] += xv * w0.y;  acc[2] += xv * w0.z;  acc[3] += xv * w0.w;
        acc[4] += xv * w1.x;  acc[5] += xv * w1.y;  acc[6] += xv * w1.z;  acc[7] += xv * w1.w;
        acc[8] += xv * w2.x;  acc[9] += xv * w2.y;  acc[10] += xv * w2.z; acc[11] += xv * w2.w;
        acc[12] += xv * w3.x; acc[13] += xv * w3.y; acc[14] += xv * w3.z; acc[15] += xv * w3.w;
    }
    __shared__ float red2[4][16];
#pragma unroll
    for (int e = 0; e < 16; ++e) {
        float v = acc[e];
        v += __shfl_xor(v, 1);
        v += __shfl_xor(v, 2);
        v += __shfl_xor(v, 4);
        v += __shfl_xor(v, 8);
        v += __shfl_xor(v, 16);
        v += __shfl_xor(v, 32);
        if (lane == 0) red2[wv][e] = v;
    }
    __syncthreads();

    if (tid == 0) {
        float l[NEXP];
#pragma unroll
        for (int e = 0; e < NEXP; ++e)
            l[e] = red2[0][e] + red2[1][e] + red2[2][e] + red2[3][e];
        int sel[TOPK];
        float selv[TOPK];
        bool used[NEXP] = {};
#pragma unroll
        for (int r = 0; r < TOPK; ++r) {
            int best = -1;
            float bv = -1e30f;
            for (int e = 0; e < NEXP; ++e)
                if (!used[e] && l[e] > bv) { bv = l[e]; best = e; }
            used[best] = true;
            sel[r] = best;
            selv[r] = bv;
        }
        float mx = selv[0];
        float wsum = 0.f, wvv[TOPK];
#pragma unroll
        for (int r = 0; r < TOPK; ++r) { wvv[r] = __expf(selv[r] - mx); wsum += wvv[r]; }
        float out16[NEXP] = {};
#pragma unroll
        for (int r = 0; r < TOPK; ++r) out16[sel[r]] = wvv[r] / wsum;
#pragma unroll
        for (int e = 0; e < NEXP; ++e) comb[(size_t)t * NEXP + e] = out16[e];
    }
}

// ---------------------------------------------------------------------------
extern "C" void kernel_launch(void* const* d_in, const int* in_sizes, int n_in,
                              void* d_out, int out_size, void* d_ws, size_t ws_size,
                              hipStream_t stream)
{
    const float* hidden   = (const float*)d_in[0];
    const float* residual = (const float*)d_in[1];
    const float* rms1_w   = (const float*)d_in[2];
    const float* rms2_w   = (const float*)d_in[3];
    const float* w_qkv    = (const float*)d_in[4];
    const float* w_dense  = (const float*)d_in[5];
    const float* gate_w   = (const float*)d_in[6];
    const float* w13      = (const float*)d_in[7];
    const float* w2       = (const float*)d_in[8];
    const float* sw13     = (const float*)d_in[9];
    const float* sw2      = (const float*)d_in[10];
    const int*   pos_ids  = (const int*)d_in[11];

    const int T = TT;

    float* out0 = (float*)d_out;
    float* out1 = (float*)d_out + (size_t)T * HD;

    // ---- workspace layout ----
    char* base = (char*)d_ws;
    float*          residF = (float*)(base);                    //  8.39 MB
    unsigned short* xB     = (unsigned short*)(base + 8388608); //  4.19 MB
    unsigned short* ctxB   = (unsigned short*)(base + 12582912);//  4.19 MB
    unsigned short* actB   = (unsigned short*)(base);           // 16.78 MB alias
    float*          qkvF   = (float*)(base + 16777216);         // 12.58 MB
    unsigned short* x2B    = (unsigned short*)(base + 29360128);//  4.19 MB
    unsigned short* sactB  = (unsigned short*)(base + 33554432);//  2.10 MB
    float*          comb   = (float*)(base + 35651584);         //  0.07 MB
    float*          part   = (float*)(base + 35717120);         // 33.55 MB
    unsigned short* Wbuf   = (unsigned short*)(base + 69271552);// 67.11 MB
    int*            lists  = (int*)(base + 139526144);          //  0.07 MB
    int*            cnts   = (int*)(base + 139591680);          //  64 B

    // attention bf16 buffers alias the split-K `part` region (dead there)
    unsigned short* Qb = (unsigned short*)(base + 35717120);            // 4 MB
    unsigned short* Kb = Qb + (size_t)NQH * TT * HEADD;                 // 1 MB
    unsigned short* Vb = Kb + (size_t)NKVH * TT * HEADD;                // 1 MB
    unsigned short* Vt = Vb + (size_t)NKVH * TT * HEADD;                // 1 MB

    dim3 blk(256);

    // 1. resid = hidden + residual ; x = rmsnorm -> bf16
    add_rmsnorm_kernel<<<dim3(T), blk, 0, stream>>>(
        hidden, residual, rms1_w, residF, xB);

    // 2. qkv = x @ w_qkv   (split-K x2)
    transpose_convert<<<dim3(QKVN / 32, HD / 32), blk, 0, stream>>>(
        w_qkv, Wbuf, HD, QKVN, 0, 0);
    gemm_splitk<<<dim3(QKVN / 128, T / 128, 2), blk, 0, stream>>>(
        xB, Wbuf, part, T, QKVN, 1024, HD, HD);
    reduce_partials<<<dim3(1024), blk, 0, stream>>>(
        part, 2, T * QKVN / 4, nullptr, qkvF, 0);

    // 3. RoPE + pack head-major bf16 ; V transpose
    rope_pack<<<dim3(T), blk, 0, stream>>>(qkvF, pos_ids, Qb, Kb, Vb);
    transpose_v<<<dim3(T / 32, HEADD / 32, NKVH), blk, 0, stream>>>(Vb, Vt);

    // 4. MFMA flash attention v2 -> ctx (bf16)
    flash_attn_mfma<<<dim3(NQH, 8, 2), dim3(128), 0, stream>>>(Qb, Kb, Vt, ctxB);

    // 5. resid2 = ctx @ w_dense + resid -> out1   (split-K x4)
    transpose_convert<<<dim3(HD / 32, HD / 32), blk, 0, stream>>>(
        w_dense, Wbuf, HD, HD, 0, 0);
    gemm_splitk<<<dim3(HD / 128, T / 128, 4), blk, 0, stream>>>(
        ctxB, Wbuf, part, T, HD, 512, HD, HD);
    reduce_partials<<<dim3(1024), blk, 0, stream>>>(
        part, 4, T * HD / 4, residF, out1, 0);

    // 6. x2 = rmsnorm(resid2) -> bf16
    add_rmsnorm_kernel<<<dim3(T), blk, 0, stream>>>(
        out1, nullptr, rms2_w, nullptr, x2B);

    // 7. fused router -> comb ; 8. expert token lists
    router_fused<<<dim3(T), blk, 0, stream>>>(out1, rms2_w, gate_w, comb);
    build_lists<<<dim3(NEXP), blk, 0, stream>>>(comb, lists, cnts);

    // 9. shared gu = x2 @ sw13  (split-K x4) -> part
    transpose_convert<<<dim3(HD / 32, HD / 32), blk, 0, stream>>>(
        sw13, Wbuf, HD, 2 * SSI, 0, 0);
    gemm_splitk<<<dim3(HD / 128, T / 128, 4), blk, 0, stream>>>(
        x2B, Wbuf, part, T, 2 * SSI, 512, HD, HD);

    // 10. fused reduce + SwiGLU -> sactB (bf16)
    reduce_swiglu<<<dim3(T * SSI / 4 / 256), blk, 0, stream>>>(part, 4, sactB);

    // 11. out0 = shared_act @ sw2  (split-K x4)
    transpose_convert<<<dim3(HD / 32, SSI / 32), blk, 0, stream>>>(
        sw2, Wbuf, SSI, HD, 0, 0);
    gemm_splitk<<<dim3(HD / 128, T / 128, 4), blk, 0, stream>>>(
        sactB, Wbuf, part, T, HD, 256, SSI, SSI);
    reduce_partials<<<dim3(1024), blk, 0, stream>>>(
        part, 4, T * HD / 4, nullptr, out0, 0);

    // 12. sparse expert up + fused SwiGLU*comb -> dense actB (zeroed first)
    hipMemsetAsync(actB, 0, (size_t)T * NEXP * EI * 2, stream);
    transpose_convert<<<dim3(1024 / 32, HD / 32, NEXP), blk, 0, stream>>>(
        w13, Wbuf, HD, 1024, (long long)HD * 1024, (long long)1024 * HD);
    moe_up_gather<<<dim3(EI / 128, 16, NEXP), blk, 0, stream>>>(
        x2B, Wbuf, comb, lists, cnts, actB);

    // 13. out0 += act @ w2   (split-K x4 over K=8192)
    transpose_convert<<<dim3(HD / 32, (NEXP * EI) / 32), blk, 0, stream>>>(
        w2, Wbuf, NEXP * EI, HD, 0, 0);
    gemm_splitk<<<dim3(HD / 128, T / 128, 4), blk, 0, stream>>>(
        actB, Wbuf, part, T, HD, 2048, NEXP * EI, NEXP * EI);
    reduce_partials<<<dim3(1024), blk, 0, stream>>>(
        part, 4, T * HD / 4, nullptr, out0, 1);
}

// Round 8
// 380.126 us; speedup vs baseline: 19.8941x; 1.0650x over previous
//
#include <hip/hip_runtime.h>
#include <math.h>

// ---------------------------------------------------------------------------
// Problem constants
// ---------------------------------------------------------------------------
#define HD 2048      // hidden size h
#define NQH 16       // num q heads
#define NKVH 4       // num kv heads
#define HEADD 128    // head dim
#define QKVN 3072    // qkv cols
#define NEXP 16      // experts
#define EI 512       // expert intermediate
#define SSI 1024     // shared intermediate
#define TOPK 4
#define TT 1024      // tokens

typedef __bf16 bf16x8 __attribute__((ext_vector_type(8)));
typedef float f32x4 __attribute__((ext_vector_type(4)));

static __device__ __forceinline__ unsigned short f2bf(float f) {
    union { float f; unsigned int u; } v; v.f = f;
    unsigned int r = v.u + 0x7fff + ((v.u >> 16) & 1);
    return (unsigned short)(r >> 16);
}

static __device__ __forceinline__ void gl_lds16(const unsigned short* g,
                                                unsigned short* l) {
    __builtin_amdgcn_global_load_lds(
        (const __attribute__((address_space(1))) unsigned int*)g,
        (__attribute__((address_space(3))) unsigned int*)l, 16, 0, 0);
}

// ---------------------------------------------------------------------------
// Fused add + RMSNorm. resid_out(f32 opt) ; x_bf (bf16)
// ---------------------------------------------------------------------------
__global__ __launch_bounds__(256) void add_rmsnorm_kernel(
    const float* __restrict__ a, const float* __restrict__ b,
    const float* __restrict__ w, float* __restrict__ resid_out,
    unsigned short* __restrict__ x_bf)
{
    int t = blockIdx.x;
    int tid = threadIdx.x;
    const float4* a4 = (const float4*)(a + (size_t)t * HD);
    const float4* b4 = b ? (const float4*)(b + (size_t)t * HD) : nullptr;
    float4* r4 = resid_out ? (float4*)(resid_out + (size_t)t * HD) : nullptr;
    const float4* w4 = (const float4*)w;

    float4 v[2];
    float ss = 0.f;
#pragma unroll
    for (int l = 0; l < 2; ++l) {
        int idx = tid + l * 256;
        float4 va = a4[idx];
        if (b4) {
            float4 vb = b4[idx];
            va.x += vb.x; va.y += vb.y; va.z += vb.z; va.w += vb.w;
        }
        if (r4) r4[idx] = va;
        v[l] = va;
        ss += va.x * va.x + va.y * va.y + va.z * va.z + va.w * va.w;
    }
    for (int off = 32; off > 0; off >>= 1) ss += __shfl_down(ss, off);
    __shared__ float red[4];
    int lane = tid & 63, wv = tid >> 6;
    if (lane == 0) red[wv] = ss;
    __syncthreads();
    if (tid == 0) {
        float s = red[0] + red[1] + red[2] + red[3];
        red[0] = rsqrtf(s / (float)HD + 1e-6f);
    }
    __syncthreads();
    float inv = red[0];
#pragma unroll
    for (int l = 0; l < 2; ++l) {
        int idx = tid + l * 256;
        float4 va = v[l], vw = w4[idx];
        ushort4 ob;
        ob.x = f2bf(va.x * inv * vw.x);
        ob.y = f2bf(va.y * inv * vw.y);
        ob.z = f2bf(va.z * inv * vw.z);
        ob.w = f2bf(va.w * inv * vw.w);
        ((ushort4*)(x_bf + (size_t)t * HD))[idx] = ob;
    }
}

// ---------------------------------------------------------------------------
// Transpose + convert: f32 in [K][N] -> bf16 out [N][K]   (per-z strides)
// ---------------------------------------------------------------------------
__global__ __launch_bounds__(256) void transpose_convert(
    const float* __restrict__ in, unsigned short* __restrict__ out,
    int K, int N, long long strideIn, long long strideOut)
{
    __shared__ float tile[32][33];
    const int n0 = blockIdx.x * 32;
    const int k0 = blockIdx.y * 32;
    const float* ip = in + (size_t)blockIdx.z * strideIn;
    unsigned short* op = out + (size_t)blockIdx.z * strideOut;
    int tid = threadIdx.x;
    int r = tid >> 3, c = (tid & 7) * 4;
    float4 v = *(const float4*)(ip + (size_t)(k0 + r) * N + n0 + c);
    tile[r][c] = v.x; tile[r][c + 1] = v.y; tile[r][c + 2] = v.z; tile[r][c + 3] = v.w;
    __syncthreads();
    ushort4 o;
    o.x = f2bf(tile[c + 0][r]);
    o.y = f2bf(tile[c + 1][r]);
    o.z = f2bf(tile[c + 2][r]);
    o.w = f2bf(tile[c + 3][r]);
    *(ushort4*)(op + (size_t)(n0 + r) * K + k0 + c) = o;
}

// ---------------------------------------------------------------------------
// Split-K bf16 MFMA GEMM, STAGE-early double-buffered, BK=64.
// ---------------------------------------------------------------------------
#define SBK 64

__global__ __launch_bounds__(256) void gemm_splitk(
    const unsigned short* __restrict__ A, const unsigned short* __restrict__ B,
    float* __restrict__ Cpart, int M, int N, int Kc, int ldA, int ldB)
{
    __shared__ unsigned short As[2][128 * SBK];
    __shared__ unsigned short Bs[2][128 * SBK];

    const int tid = threadIdx.x;
    const int wave = tid >> 6;
    const int lane = tid & 63;
    const int wr = wave >> 1, wc = wave & 1;
    const int l15 = lane & 15;
    const int row0 = blockIdx.y * 128;
    const int col0 = blockIdx.x * 128;
    const int z = blockIdx.z;

    const unsigned short* Ap = A + (size_t)row0 * ldA + (size_t)z * Kc;
    const unsigned short* Bp = B + (size_t)col0 * ldB + (size_t)z * Kc;

    const int r_st = tid >> 3;
    const int q_st = tid & 7;
    const int csrc = (q_st ^ (r_st & 7)) << 3;

    f32x4 acc[4][4] = {};

    const int nsteps = Kc / SBK;

#define STAGE_SK(buf, k0s)                                                    \
    {                                                                         \
        _Pragma("unroll")                                                     \
        for (int i = 0; i < 4; ++i) {                                         \
            int rr = r_st + i * 32;                                           \
            gl_lds16(Ap + (size_t)rr * ldA + (k0s) + csrc,                    \
                     &As[buf][rr * SBK + q_st * 8]);                          \
            gl_lds16(Bp + (size_t)rr * ldB + (k0s) + csrc,                    \
                     &Bs[buf][rr * SBK + q_st * 8]);                          \
        }                                                                     \
    }

    STAGE_SK(0, 0);
    __syncthreads();

    for (int s = 0; s < nsteps; ++s) {
        const int cur = s & 1;
        if (s + 1 < nsteps) STAGE_SK(cur ^ 1, (s + 1) * SBK);

#pragma unroll
        for (int half = 0; half < 2; ++half) {
            const int q = half * 4 + (lane >> 4);
            bf16x8 af[4], bfv[4];
#pragma unroll
            for (int i = 0; i < 4; ++i) {
                int R = wr * 64 + i * 16 + l15;
                af[i] = *(const bf16x8*)&As[cur][R * SBK + ((q ^ (R & 7)) << 3)];
            }
#pragma unroll
            for (int j = 0; j < 4; ++j) {
                int R = wc * 64 + j * 16 + l15;
                bfv[j] = *(const bf16x8*)&Bs[cur][R * SBK + ((q ^ (R & 7)) << 3)];
            }
#pragma unroll
            for (int mi = 0; mi < 4; ++mi)
#pragma unroll
                for (int nj = 0; nj < 4; ++nj)
                    acc[mi][nj] = __builtin_amdgcn_mfma_f32_16x16x32_bf16(
                        af[mi], bfv[nj], acc[mi][nj], 0, 0, 0);
        }
        __syncthreads();
    }

    float* Cp = Cpart + (size_t)z * M * N;
#pragma unroll
    for (int mi = 0; mi < 4; ++mi)
#pragma unroll
        for (int nj = 0; nj < 4; ++nj)
#pragma unroll
            for (int r = 0; r < 4; ++r) {
                int row = row0 + wr * 64 + mi * 16 + (lane >> 4) * 4 + r;
                int col = col0 + wc * 64 + nj * 16 + l15;
                Cp[(size_t)row * N + col] = acc[mi][nj][r];
            }
}

// ---------------------------------------------------------------------------
// Reduce split-K partials: out = sum_z part[z] (+ add) (+= out if acc)
// ---------------------------------------------------------------------------
__global__ __launch_bounds__(256) void reduce_partials(
    const float* __restrict__ part, int ns, int n4,
    const float* __restrict__ add, float* __restrict__ out, int acc)
{
    const float4* p4 = (const float4*)part;
    const float4* a4 = (const float4*)add;
    float4* o4 = (float4*)out;
    for (int idx = blockIdx.x * 256 + threadIdx.x; idx < n4;
         idx += gridDim.x * 256) {
        float4 s = p4[idx];
        for (int z = 1; z < ns; ++z) {
            float4 q = p4[(size_t)z * n4 + idx];
            s.x += q.x; s.y += q.y; s.z += q.z; s.w += q.w;
        }
        if (add) {
            float4 q = a4[idx];
            s.x += q.x; s.y += q.y; s.z += q.z; s.w += q.w;
        }
        if (acc) {
            float4 q = o4[idx];
            s.x += q.x; s.y += q.y; s.z += q.z; s.w += q.w;
        }
        o4[idx] = s;
    }
}

// ---------------------------------------------------------------------------
// Reduce split-K partials of shared-expert gu [T][2048] + SwiGLU -> bf16
// ---------------------------------------------------------------------------
__global__ __launch_bounds__(256) void reduce_swiglu(
    const float* __restrict__ part, int ns, unsigned short* __restrict__ out)
{
    int idx4 = blockIdx.x * 256 + threadIdx.x;
    int t = idx4 >> 8;
    int i4 = (idx4 & 255) * 4;
    const float4* pg = (const float4*)(part + (size_t)t * (2 * SSI) + i4);
    const float4* pu = (const float4*)(part + (size_t)t * (2 * SSI) + SSI + i4);
    float4 g = pg[0], u = pu[0];
    for (int z = 1; z < ns; ++z) {
        float4 g2 = *(const float4*)((const float*)pg + (size_t)z * TT * 2 * SSI);
        float4 u2 = *(const float4*)((const float*)pu + (size_t)z * TT * 2 * SSI);
        g.x += g2.x; g.y += g2.y; g.z += g2.z; g.w += g2.w;
        u.x += u2.x; u.y += u2.y; u.z += u2.z; u.w += u2.w;
    }
    ushort4 o;
    o.x = f2bf((g.x / (1.f + __expf(-g.x))) * u.x);
    o.y = f2bf((g.y / (1.f + __expf(-g.y))) * u.y);
    o.z = f2bf((g.z / (1.f + __expf(-g.z))) * u.z);
    o.w = f2bf((g.w / (1.f + __expf(-g.w))) * u.w);
    *(ushort4*)(out + (size_t)t * SSI + i4) = o;
}

// ---------------------------------------------------------------------------
// Build per-expert token lists + slot ranks (token-ordered, deterministic).
// ---------------------------------------------------------------------------
__global__ __launch_bounds__(256) void build_lists(
    const float* __restrict__ comb, int* __restrict__ lists,
    int* __restrict__ slots, int* __restrict__ cnts)
{
    int e = blockIdx.x;
    int tid = threadIdx.x;
    __shared__ int sc[256];
    int loc[4];
    int c = 0;
#pragma unroll
    for (int j = 0; j < 4; ++j) {
        int t = tid * 4 + j;
        if (comb[(size_t)t * NEXP + e] > 0.f) loc[c++] = t;
    }
    sc[tid] = c;
    __syncthreads();
    for (int off = 1; off < 256; off <<= 1) {
        int v = (tid >= off) ? sc[tid - off] : 0;
        __syncthreads();
        sc[tid] += v;
        __syncthreads();
    }
    int base = sc[tid] - c;
    for (int i = 0; i < c; ++i) {
        int t = loc[i];
        int s = 0;
        for (int e2 = 0; e2 < e; ++e2)
            s += (comb[(size_t)t * NEXP + e2] > 0.f) ? 1 : 0;
        lists[e * TT + base + i] = t;
        slots[e * TT + base + i] = s;
    }
    if (tid == 255) cnts[e] = sc[255];
}

// ---------------------------------------------------------------------------
// Prefix-scan expert counts -> bases[17]
// ---------------------------------------------------------------------------
__global__ void scan_cnts(const int* __restrict__ cnts, int* __restrict__ bases)
{
    if (threadIdx.x == 0 && blockIdx.x == 0) {
        int a = 0;
        for (int e = 0; e < NEXP; ++e) { bases[e] = a; a += cnts[e]; }
        bases[NEXP] = a;
    }
}

// ---------------------------------------------------------------------------
// Sparse MoE expert-up + fused SwiGLU*comb -> compact ragged actC (bf16).
// grid (EI/64=8 n-blocks, 16 m-tiles, 16 experts), 256 thr.  M-tile 64,
// N-tile 64 (dual gate/up), BK=64, double-buffered, src-pre-swizzled.
// Wave w owns cols w*16..w*16+15.
// ---------------------------------------------------------------------------
__global__ __launch_bounds__(256) void moe_up_gather(
    const unsigned short* __restrict__ x2B,
    const unsigned short* __restrict__ w13T,
    const float* __restrict__ comb,
    const int* __restrict__ lists,
    const int* __restrict__ cnts,
    const int* __restrict__ bases,
    unsigned short* __restrict__ actC)
{
    __shared__ unsigned short As[2][64 * 64];
    __shared__ unsigned short Bgs[2][64 * 64];
    __shared__ unsigned short Bus[2][64 * 64];

    const int e = blockIdx.z;
    const int cnt = cnts[e];
    const int m0 = blockIdx.y * 64;
    if (m0 >= cnt) return;
    const int n0 = blockIdx.x * 64;
    const int base_e = bases[e];

    const int tid = threadIdx.x;
    const int w = tid >> 6;
    const int lane = tid & 63;
    const int l15 = lane & 15;
    const int g = lane >> 4;

    // staging coords: 512 chunks (64 rows x 8 chunks), 2 per thread
    const int r0 = tid >> 3;          // 0..31
    const int q_st = tid & 7;
    const int swz = (q_st ^ (r0 & 7)) << 3;   // (r0+32)&7 == r0&7

    int a0 = m0 + r0, a1 = m0 + r0 + 32;
    int tok0 = lists[e * TT + (a0 < cnt ? a0 : cnt - 1)];
    int tok1 = lists[e * TT + (a1 < cnt ? a1 : cnt - 1)];
    const unsigned short* Asrc0 = x2B + (size_t)tok0 * HD;
    const unsigned short* Asrc1 = x2B + (size_t)tok1 * HD;
    const unsigned short* Bbase = w13T + (size_t)e * 1024 * HD;
    const unsigned short* Bg0 = Bbase + (size_t)(n0 + r0) * HD;
    const unsigned short* Bg1 = Bbase + (size_t)(n0 + r0 + 32) * HD;
    const unsigned short* Bu0 = Bg0 + (size_t)512 * HD;
    const unsigned short* Bu1 = Bg1 + (size_t)512 * HD;

    f32x4 ag[4] = {};
    f32x4 au[4] = {};

#define STAGE_UP(buf, k0s)                                                    \
    {                                                                         \
        gl_lds16(Asrc0 + (k0s) + swz, &As[buf][(tid) * 8]);                   \
        gl_lds16(Asrc1 + (k0s) + swz, &As[buf][(tid + 256) * 8]);             \
        gl_lds16(Bg0 + (k0s) + swz, &Bgs[buf][(tid) * 8]);                    \
        gl_lds16(Bg1 + (k0s) + swz, &Bgs[buf][(tid + 256) * 8]);              \
        gl_lds16(Bu0 + (k0s) + swz, &Bus[buf][(tid) * 8]);                    \
        gl_lds16(Bu1 + (k0s) + swz, &Bus[buf][(tid + 256) * 8]);              \
    }

    STAGE_UP(0, 0);
    __syncthreads();

    const int nsteps = HD / 64;   // 32
    for (int s = 0; s < nsteps; ++s) {
        const int cur = s & 1;
        if (s + 1 < nsteps) STAGE_UP(cur ^ 1, (s + 1) * 64);

#pragma unroll
        for (int kk2 = 0; kk2 < 2; ++kk2) {
            const int q = kk2 * 4 + g;
            bf16x8 af[4], bg, bu;
#pragma unroll
            for (int i = 0; i < 4; ++i) {
                int R = i * 16 + l15;
                af[i] = *(const bf16x8*)&As[cur][R * 64 + ((q ^ (R & 7)) << 3)];
            }
            {
                int R = w * 16 + l15;
                int off = R * 64 + ((q ^ (R & 7)) << 3);
                bg = *(const bf16x8*)&Bgs[cur][off];
                bu = *(const bf16x8*)&Bus[cur][off];
            }
#pragma unroll
            for (int mi = 0; mi < 4; ++mi) {
                ag[mi] = __builtin_amdgcn_mfma_f32_16x16x32_bf16(
                    af[mi], bg, ag[mi], 0, 0, 0);
                au[mi] = __builtin_amdgcn_mfma_f32_16x16x32_bf16(
                    af[mi], bu, au[mi], 0, 0, 0);
            }
        }
        __syncthreads();
    }

#pragma unroll
    for (int mi = 0; mi < 4; ++mi) {
#pragma unroll
        for (int r = 0; r < 4; ++r) {
            int grow = m0 + mi * 16 + g * 4 + r;
            if (grow >= cnt) continue;
            int tok = lists[e * TT + grow];
            float cw = comb[(size_t)tok * NEXP + e];
            int col = n0 + w * 16 + l15;
            float gg = ag[mi][r];
            float uu = au[mi][r];
            float v = (gg / (1.f + __expf(-gg))) * uu * cw;
            actC[(size_t)(base_e + grow) * EI + col] = f2bf(v);
        }
    }
}

// ---------------------------------------------------------------------------
// Sparse MoE down: actC[cnt_e][512](bf16) @ w2T-slice -> slot partials (f32).
// grid (HD/128=16 n-blocks, 16 m-tiles, 16 experts), 256 thr.  M-tile 64,
// N-tile 128, BK=64.  Wave w owns cols w*32..w*32+31 (nj=2).
// slotpart[s][tok][HD] written exactly once per (tok, slot) -- no atomics.
// ---------------------------------------------------------------------------
__global__ __launch_bounds__(256) void moe_down_gather(
    const unsigned short* __restrict__ actC,
    const unsigned short* __restrict__ w2T,   // [HD][NEXP*EI]
    const int* __restrict__ lists,
    const int* __restrict__ slots,
    const int* __restrict__ cnts,
    const int* __restrict__ bases,
    float* __restrict__ slotpart)
{
    __shared__ unsigned short As[2][64 * 64];
    __shared__ unsigned short Bs[2][128 * 64];

    const int e = blockIdx.z;
    const int cnt = cnts[e];
    const int m0 = blockIdx.y * 64;
    if (m0 >= cnt) return;
    const int n0 = blockIdx.x * 128;
    const int base_e = bases[e];

    const int tid = threadIdx.x;
    const int w = tid >> 6;
    const int lane = tid & 63;
    const int l15 = lane & 15;
    const int g = lane >> 4;

    const int r0 = tid >> 3;          // 0..31
    const int q_st = tid & 7;
    const int swz = (q_st ^ (r0 & 7)) << 3;

    int a0 = m0 + r0, a1 = m0 + r0 + 32;
    const unsigned short* Asrc0 =
        actC + (size_t)(base_e + (a0 < cnt ? a0 : cnt - 1)) * EI;
    const unsigned short* Asrc1 =
        actC + (size_t)(base_e + (a1 < cnt ? a1 : cnt - 1)) * EI;
    const unsigned short* Bbase = w2T + (size_t)e * EI;   // col offset e*512

#define STAGE_DN(buf, k0s)                                                    \
    {                                                                         \
        gl_lds16(Asrc0 + (k0s) + swz, &As[buf][(tid) * 8]);                   \
        gl_lds16(Asrc1 + (k0s) + swz, &As[buf][(tid + 256) * 8]);             \
        _Pragma("unroll")                                                     \
        for (int i = 0; i < 4; ++i) {                                         \
            int rr = r0 + i * 32;                                             \
            gl_lds16(Bbase + (size_t)(n0 + rr) * (NEXP * EI) + (k0s) + swz,   \
                     &Bs[buf][(tid + i * 256) * 8]);                          \
        }                                                                     \
    }

    f32x4 acc[4][2] = {};

    STAGE_DN(0, 0);
    __syncthreads();

    const int nsteps = EI / 64;   // 8
    for (int s = 0; s < nsteps; ++s) {
        const int cur = s & 1;
        if (s + 1 < nsteps) STAGE_DN(cur ^ 1, (s + 1) * 64);

#pragma unroll
        for (int kk2 = 0; kk2 < 2; ++kk2) {
            const int q = kk2 * 4 + g;
            bf16x8 af[4], bf[2];
#pragma unroll
            for (int i = 0; i < 4; ++i) {
                int R = i * 16 + l15;
                af[i] = *(const bf16x8*)&As[cur][R * 64 + ((q ^ (R & 7)) << 3)];
            }
#pragma unroll
            for (int j = 0; j < 2; ++j) {
                int R = w * 32 + j * 16 + l15;
                bf[j] = *(const bf16x8*)&Bs[cur][R * 64 + ((q ^ (R & 7)) << 3)];
            }
#pragma unroll
            for (int mi = 0; mi < 4; ++mi)
#pragma unroll
                for (int nj = 0; nj < 2; ++nj)
                    acc[mi][nj] = __builtin_amdgcn_mfma_f32_16x16x32_bf16(
                        af[mi], bf[nj], acc[mi][nj], 0, 0, 0);
        }
        __syncthreads();
    }

#pragma unroll
    for (int mi = 0; mi < 4; ++mi) {
#pragma unroll
        for (int r = 0; r < 4; ++r) {
            int grow = m0 + mi * 16 + g * 4 + r;
            if (grow >= cnt) continue;
            int tok = lists[e * TT + grow];
            int sl  = slots[e * TT + grow];
            float* orow = slotpart + (size_t)sl * TT * HD + (size_t)tok * HD;
#pragma unroll
            for (int nj = 0; nj < 2; ++nj) {
                int col = n0 + w * 32 + nj * 16 + l15;
                orow[col] = acc[mi][nj][r];
            }
        }
    }
}

// ---------------------------------------------------------------------------
// RoPE + pack to head-major bf16.  One block per token, 256 threads.
// ---------------------------------------------------------------------------
__global__ __launch_bounds__(256) void rope_pack(
    const float* __restrict__ qkv, const int* __restrict__ pos_ids,
    unsigned short* __restrict__ Qb, unsigned short* __restrict__ Kb,
    unsigned short* __restrict__ Vb)
{
    const float SCALE = 0.08838834764831843f;
    int t = blockIdx.x;
    int tid = threadIdx.x;
    int w = tid >> 6, lane = tid & 63;
    float pos = (float)pos_ids[t];
    float invf = powf(10000.0f, -(float)lane * (1.0f / 64.0f));
    float ang = pos * invf;
    float c = cosf(ang);
    float s = sinf(ang);
    const float* row = qkv + (size_t)t * QKVN;
#pragma unroll
    for (int j = 0; j < 5; ++j) {
        int hh = w * 5 + j;
        const float* hb = row + hh * HEADD;
        float x1 = hb[lane], x2 = hb[lane + 64];
        float o1 = x1 * c - x2 * s;
        float o2 = x2 * c + x1 * s;
        if (hh < NQH) {
            unsigned short* qp = Qb + ((size_t)hh * TT + t) * HEADD;
            qp[lane] = f2bf(o1 * SCALE);
            qp[lane + 64] = f2bf(o2 * SCALE);
        } else {
            unsigned short* kp = Kb + ((size_t)(hh - NQH) * TT + t) * HEADD;
            kp[lane] = f2bf(o1);
            kp[lane + 64] = f2bf(o2);
        }
    }
    float2 v2 = *(const float2*)(row + 2560 + tid * 2);
    int kvh = tid >> 6;
    int d = (tid * 2) & 127;
    unsigned int packed = (unsigned int)f2bf(v2.x) |
                          ((unsigned int)f2bf(v2.y) << 16);
    *(unsigned int*)(Vb + ((size_t)kvh * TT + t) * HEADD + d) = packed;
}

// ---------------------------------------------------------------------------
// V transpose: Vb[kvh][t][128] -> Vt[kvh][128][t]
// ---------------------------------------------------------------------------
__global__ __launch_bounds__(256) void transpose_v(
    const unsigned short* __restrict__ Vb, unsigned short* __restrict__ Vt)
{
    __shared__ unsigned short tile[32][40];
    const int kvh = blockIdx.z;
    const int t0 = blockIdx.x * 32, d0 = blockIdx.y * 32;
    int tid = threadIdx.x;
    int r = tid >> 3, c4 = (tid & 7) * 4;
    ushort4 v = *(const ushort4*)(Vb + ((size_t)kvh * TT + t0 + r) * HEADD + d0 + c4);
    tile[r][c4] = v.x; tile[r][c4 + 1] = v.y;
    tile[r][c4 + 2] = v.z; tile[r][c4 + 3] = v.w;
    __syncthreads();
    ushort4 o;
    o.x = tile[c4 + 0][r];
    o.y = tile[c4 + 1][r];
    o.z = tile[c4 + 2][r];
    o.w = tile[c4 + 3][r];
    *(ushort4*)(Vt + ((size_t)kvh * HEADD + d0 + r) * TT + t0 + c4) = o;
}

// ---------------------------------------------------------------------------
// MFMA flash attention v2 — LDS-staged K/V, double-buffered, triangle-paired.
// ---------------------------------------------------------------------------
__global__ __launch_bounds__(128) void flash_attn_mfma(
    const unsigned short* __restrict__ Qb,
    const unsigned short* __restrict__ Kb,
    const unsigned short* __restrict__ Vt,
    unsigned short* __restrict__ ctx)
{
    __shared__ __align__(16) unsigned short Ks[2][64 * 128];
    __shared__ __align__(16) unsigned short Vs[2][128 * 64];
    __shared__ __align__(16) unsigned short Pl[2][16][72];

    const int h   = blockIdx.x;
    const int p   = blockIdx.y;
    const int rh  = blockIdx.z;
    const int kvh = h >> 2;
    const int tid = threadIdx.x;
    const int w   = tid >> 6;
    const int lane = tid & 63;
    const int l15 = lane & 15;
    const int g   = lane >> 4;

    const unsigned short* Kh = Kb + (size_t)kvh * TT * HEADD;
    const unsigned short* Vh = Vt + (size_t)kvh * HEADD * TT;

#define STAGE_KV(buf, s0s)                                                    \
    {                                                                         \
        _Pragma("unroll")                                                     \
        for (int i = 0; i < 8; ++i) {                                         \
            int idx = tid + i * 128;                                          \
            int r = idx >> 4, c = idx & 15;                                   \
            int csw = (c & 8) | ((c ^ r) & 7);                                \
            gl_lds16(Kh + (size_t)((s0s) + r) * HEADD + csw * 8,              \
                     &Ks[buf][idx * 8]);                                      \
        }                                                                     \
        _Pragma("unroll")                                                     \
        for (int i = 0; i < 8; ++i) {                                         \
            int idx = tid + i * 128;                                          \
            int r = idx >> 3, c = idx & 7;                                    \
            int csw = (c ^ r) & 7;                                            \
            gl_lds16(Vh + (size_t)r * TT + (s0s) + csw * 8,                   \
                     &Vs[buf][idx * 8]);                                      \
        }                                                                     \
    }

    const int qts[2] = {p, 15 - p};

#pragma unroll
    for (int qi = 0; qi < 2; ++qi) {
        const int qt = qts[qi];
        const int q0 = qt * 64 + rh * 32 + w * 16;
        const int ntiles = qt + 1;

        const unsigned short* Qrow = Qb + ((size_t)h * TT + q0 + l15) * HEADD;
        bf16x8 qf[4];
#pragma unroll
        for (int kk = 0; kk < 4; ++kk)
            qf[kk] = *(const bf16x8*)(Qrow + kk * 32 + g * 8);

        float m_i[4], l_i[4];
#pragma unroll
        for (int r = 0; r < 4; ++r) { m_i[r] = -1e30f; l_i[r] = 0.f; }
        f32x4 of[8] = {};

        STAGE_KV(0, 0);
        __syncthreads();

        for (int st = 0; st < ntiles; ++st) {
            const int cur = st & 1;
            const int s0 = st * 64;
            if (st + 1 < ntiles) STAGE_KV(cur ^ 1, (st + 1) * 64);

            f32x4 sacc[4] = {};
#pragma unroll
            for (int kk = 0; kk < 4; ++kk) {
#pragma unroll
                for (int n = 0; n < 4; ++n) {
                    int R = n * 16 + l15;
                    int cidx = kk * 4 + g;
                    int cs = (cidx & 8) | ((cidx ^ R) & 7);
                    bf16x8 kb = *(const bf16x8*)&Ks[cur][R * 128 + cs * 8];
                    sacc[n] = __builtin_amdgcn_mfma_f32_16x16x32_bf16(
                        qf[kk], kb, sacc[n], 0, 0, 0);
                }
            }

            const bool diag = (st == qt);
            float alpha[4];
#pragma unroll
            for (int r = 0; r < 4; ++r) {
                const int qrow = q0 + g * 4 + r;
                float sv[4] = {sacc[0][r], sacc[1][r], sacc[2][r], sacc[3][r]};
                if (diag) {
#pragma unroll
                    for (int n = 0; n < 4; ++n)
                        if (s0 + n * 16 + l15 > qrow) sv[n] = -1e30f;
                }
                float rm = fmaxf(fmaxf(sv[0], sv[1]), fmaxf(sv[2], sv[3]));
                rm = fmaxf(rm, __shfl_xor(rm, 1));
                rm = fmaxf(rm, __shfl_xor(rm, 2));
                rm = fmaxf(rm, __shfl_xor(rm, 4));
                rm = fmaxf(rm, __shfl_xor(rm, 8));
                float mnew = fmaxf(m_i[r], rm);
                alpha[r] = __expf(m_i[r] - mnew);
                float p0 = __expf(sv[0] - mnew);
                float p1 = __expf(sv[1] - mnew);
                float p2 = __expf(sv[2] - mnew);
                float p3 = __expf(sv[3] - mnew);
                float rs = p0 + p1 + p2 + p3;
                rs += __shfl_xor(rs, 1);
                rs += __shfl_xor(rs, 2);
                rs += __shfl_xor(rs, 4);
                rs += __shfl_xor(rs, 8);
                l_i[r] = l_i[r] * alpha[r] + rs;
                m_i[r] = mnew;
                Pl[w][g * 4 + r][0 * 16 + l15] = f2bf(p0);
                Pl[w][g * 4 + r][1 * 16 + l15] = f2bf(p1);
                Pl[w][g * 4 + r][2 * 16 + l15] = f2bf(p2);
                Pl[w][g * 4 + r][3 * 16 + l15] = f2bf(p3);
            }

#pragma unroll
            for (int nd = 0; nd < 8; ++nd)
#pragma unroll
                for (int r = 0; r < 4; ++r)
                    of[nd][r] *= alpha[r];

#pragma unroll
            for (int kk2 = 0; kk2 < 2; ++kk2) {
                bf16x8 pa = *(const bf16x8*)&Pl[w][l15][kk2 * 32 + g * 8];
#pragma unroll
                for (int nd = 0; nd < 8; ++nd) {
                    int R = nd * 16 + l15;
                    int cidx = kk2 * 4 + g;
                    int cs = (cidx ^ R) & 7;
                    bf16x8 vb = *(const bf16x8*)&Vs[cur][R * 64 + cs * 8];
                    of[nd] = __builtin_amdgcn_mfma_f32_16x16x32_bf16(
                        pa, vb, of[nd], 0, 0, 0);
                }
            }
            __syncthreads();
        }

        float invl[4];
#pragma unroll
        for (int r = 0; r < 4; ++r) invl[r] = 1.f / l_i[r];
#pragma unroll
        for (int nd = 0; nd < 8; ++nd)
#pragma unroll
            for (int r = 0; r < 4; ++r) {
                int trow = q0 + g * 4 + r;
                ctx[(size_t)trow * (NQH * HEADD) + h * HEADD + nd * 16 + l15] =
                    f2bf(of[nd][r] * invl[r]);
            }
    }
}

// ---------------------------------------------------------------------------
// Fused router: rmsnorm(resid2)*w . gate_w, softmax top-4 -> comb (T,16)
// ---------------------------------------------------------------------------
__global__ __launch_bounds__(256) void router_fused(
    const float* __restrict__ resid2, const float* __restrict__ w,
    const float* __restrict__ gate_w, float* __restrict__ comb)
{
    int t = blockIdx.x;
    int tid = threadIdx.x;
    int lane = tid & 63, wv = tid >> 6;

    const float4* r4 = (const float4*)(resid2 + (size_t)t * HD);
    float4 xa = r4[tid * 2], xb = r4[tid * 2 + 1];
    float ss = xa.x * xa.x + xa.y * xa.y + xa.z * xa.z + xa.w * xa.w +
               xb.x * xb.x + xb.y * xb.y + xb.z * xb.z + xb.w * xb.w;
    for (int off = 32; off > 0; off >>= 1) ss += __shfl_down(ss, off);
    __shared__ float red[4];
    if (lane == 0) red[wv] = ss;
    __syncthreads();
    float inv = rsqrtf((red[0] + red[1] + red[2] + red[3]) / (float)HD + 1e-6f);

    const float4* w4 = (const float4*)w;
    float4 wa = w4[tid * 2], wb = w4[tid * 2 + 1];
    float xs[8] = {xa.x * wa.x * inv, xa.y * wa.y * inv, xa.z * wa.z * inv,
                   xa.w * wa.w * inv, xb.x * wb.x * inv, xb.y * wb.y * inv,
                   xb.z * wb.z * inv, xb.w * wb.w * inv};

    float acc[16] = {};
    int kbase = tid * 8;
#pragma unroll
    for (int j = 0; j < 8; ++j) {
        float xv = xs[j];
        const float4* wrow = (const float4*)(gate_w + (size_t)(kbase + j) * NEXP);
        float4 w0 = wrow[0], w1 = wrow[1], w2 = wrow[2], w3 = wrow[3];
        acc[0] += xv * w0.x;  acc[1] += xv * w0.y;  acc[2] += xv * w0.z;  acc[3] += xv * w0.w;
        acc[4] += xv * w1.x;  acc[5] += xv * w1.y;  acc[6] += xv * w1.z;  acc[7] += xv * w1.w;
        acc[8] += xv * w2.x;  acc[9] += xv * w2.y;  acc[10] += xv * w2.z; acc[11] += xv * w2.w;
        acc[12] += xv * w3.x; acc[13] += xv * w3.y; acc[14] += xv * w3.z; acc[15] += xv * w3.w;
    }
    __shared__ float red2[4][16];
#pragma unroll
    for (int e = 0; e < 16; ++e) {
        float v = acc[e];
        v += __shfl_xor(v, 1);
        v += __shfl_xor(v, 2);
        v += __shfl_xor(v, 4);
        v += __shfl_xor(v, 8);
        v += __shfl_xor(v, 16);
        v += __shfl_xor(v, 32);
        if (lane == 0) red2[wv][e] = v;
    }
    __syncthreads();

    if (tid == 0) {
        float l[NEXP];
#pragma unroll
        for (int e = 0; e < NEXP; ++e)
            l[e] = red2[0][e] + red2[1][e] + red2[2][e] + red2[3][e];
        int sel[TOPK];
        float selv[TOPK];
        bool used[NEXP] = {};
#pragma unroll
        for (int r = 0; r < TOPK; ++r) {
            int best = -1;
            float bv = -1e30f;
            for (int e = 0; e < NEXP; ++e)
                if (!used[e] && l[e] > bv) { bv = l[e]; best = e; }
            used[best] = true;
            sel[r] = best;
            selv[r] = bv;
        }
        float mx = selv[0];
        float wsum = 0.f, wvv[TOPK];
#pragma unroll
        for (int r = 0; r < TOPK; ++r) { wvv[r] = __expf(selv[r] - mx); wsum += wvv[r]; }
        float out16[NEXP] = {};
#pragma unroll
        for (int r = 0; r < TOPK; ++r) out16[sel[r]] = wvv[r] / wsum;
#pragma unroll
        for (int e = 0; e < NEXP; ++e) comb[(size_t)t * NEXP + e] = out16[e];
    }
}

// ---------------------------------------------------------------------------
extern "C" void kernel_launch(void* const* d_in, const int* in_sizes, int n_in,
                              void* d_out, int out_size, void* d_ws, size_t ws_size,
                              hipStream_t stream)
{
    const float* hidden   = (const float*)d_in[0];
    const float* residual = (const float*)d_in[1];
    const float* rms1_w   = (const float*)d_in[2];
    const float* rms2_w   = (const float*)d_in[3];
    const float* w_qkv    = (const float*)d_in[4];
    const float* w_dense  = (const float*)d_in[5];
    const float* gate_w   = (const float*)d_in[6];
    const float* w13      = (const float*)d_in[7];
    const float* w2       = (const float*)d_in[8];
    const float* sw13     = (const float*)d_in[9];
    const float* sw2      = (const float*)d_in[10];
    const int*   pos_ids  = (const int*)d_in[11];

    const int T = TT;

    float* out0 = (float*)d_out;
    float* out1 = (float*)d_out + (size_t)T * HD;

    // ---- workspace layout ----
    char* base = (char*)d_ws;
    float*          residF = (float*)(base);                    //  8.39 MB
    unsigned short* xB     = (unsigned short*)(base + 8388608); //  4.19 MB
    unsigned short* ctxB   = (unsigned short*)(base + 12582912);//  4.19 MB
    unsigned short* actC   = (unsigned short*)(base);           //  4.19 MB alias (residF dead by MoE)
    float*          qkvF   = (float*)(base + 16777216);         // 12.58 MB
    unsigned short* x2B    = (unsigned short*)(base + 29360128);//  4.19 MB
    unsigned short* sactB  = (unsigned short*)(base + 33554432);//  2.10 MB
    float*          comb   = (float*)(base + 35651584);         //  0.07 MB
    float*          part   = (float*)(base + 35717120);         // 33.55 MB (split-K / slot partials)
    unsigned short* Wbuf   = (unsigned short*)(base + 69271552);// 67.11 MB (weights, phase-reused)
    int*            lists  = (int*)(base + 139526144);          //  64 KB
    int*            cnts   = (int*)(base + 139591680);          //  256 B
    int*            slots  = (int*)(base + 139591936);          //  64 KB
    int*            bases  = (int*)(base + 139657472);          //  128 B

    // attention bf16 buffers alias the split-K `part` region (dead there)
    unsigned short* Qb = (unsigned short*)(base + 35717120);            // 4 MB
    unsigned short* Kb = Qb + (size_t)NQH * TT * HEADD;                 // 1 MB
    unsigned short* Vb = Kb + (size_t)NKVH * TT * HEADD;                // 1 MB
    unsigned short* Vt = Vb + (size_t)NKVH * TT * HEADD;                // 1 MB

    dim3 blk(256);

    // 1. resid = hidden + residual ; x = rmsnorm -> bf16
    add_rmsnorm_kernel<<<dim3(T), blk, 0, stream>>>(
        hidden, residual, rms1_w, residF, xB);

    // 2. qkv = x @ w_qkv   (split-K x2)
    transpose_convert<<<dim3(QKVN / 32, HD / 32), blk, 0, stream>>>(
        w_qkv, Wbuf, HD, QKVN, 0, 0);
    gemm_splitk<<<dim3(QKVN / 128, T / 128, 2), blk, 0, stream>>>(
        xB, Wbuf, part, T, QKVN, 1024, HD, HD);
    reduce_partials<<<dim3(1024), blk, 0, stream>>>(
        part, 2, T * QKVN / 4, nullptr, qkvF, 0);

    // 3. RoPE + pack head-major bf16 ; V transpose
    rope_pack<<<dim3(T), blk, 0, stream>>>(qkvF, pos_ids, Qb, Kb, Vb);
    transpose_v<<<dim3(T / 32, HEADD / 32, NKVH), blk, 0, stream>>>(Vb, Vt);

    // 4. MFMA flash attention v2 -> ctx (bf16)
    flash_attn_mfma<<<dim3(NQH, 8, 2), dim3(128), 0, stream>>>(Qb, Kb, Vt, ctxB);

    // 5. resid2 = ctx @ w_dense + resid -> out1   (split-K x4)
    transpose_convert<<<dim3(HD / 32, HD / 32), blk, 0, stream>>>(
        w_dense, Wbuf, HD, HD, 0, 0);
    gemm_splitk<<<dim3(HD / 128, T / 128, 4), blk, 0, stream>>>(
        ctxB, Wbuf, part, T, HD, 512, HD, HD);
    reduce_partials<<<dim3(1024), blk, 0, stream>>>(
        part, 4, T * HD / 4, residF, out1, 0);

    // 6. x2 = rmsnorm(resid2) -> bf16
    add_rmsnorm_kernel<<<dim3(T), blk, 0, stream>>>(
        out1, nullptr, rms2_w, nullptr, x2B);

    // 7. fused router -> comb ; 8. expert token lists + slots + bases
    router_fused<<<dim3(T), blk, 0, stream>>>(out1, rms2_w, gate_w, comb);
    build_lists<<<dim3(NEXP), blk, 0, stream>>>(comb, lists, slots, cnts);
    scan_cnts<<<dim3(1), dim3(64), 0, stream>>>(cnts, bases);

    // 9. shared gu = x2 @ sw13  (split-K x4) -> part
    transpose_convert<<<dim3(HD / 32, HD / 32), blk, 0, stream>>>(
        sw13, Wbuf, HD, 2 * SSI, 0, 0);
    gemm_splitk<<<dim3(HD / 128, T / 128, 4), blk, 0, stream>>>(
        x2B, Wbuf, part, T, 2 * SSI, 512, HD, HD);

    // 10. fused reduce + SwiGLU -> sactB (bf16)
    reduce_swiglu<<<dim3(T * SSI / 4 / 256), blk, 0, stream>>>(part, 4, sactB);

    // 11. out0 = shared_act @ sw2  (split-K x4)
    transpose_convert<<<dim3(HD / 32, SSI / 32), blk, 0, stream>>>(
        sw2, Wbuf, SSI, HD, 0, 0);
    gemm_splitk<<<dim3(HD / 128, T / 128, 4), blk, 0, stream>>>(
        sactB, Wbuf, part, T, HD, 256, SSI, SSI);
    reduce_partials<<<dim3(1024), blk, 0, stream>>>(
        part, 4, T * HD / 4, nullptr, out0, 0);

    // 12. sparse expert up + fused SwiGLU*comb -> compact actC
    transpose_convert<<<dim3(1024 / 32, HD / 32, NEXP), blk, 0, stream>>>(
        w13, Wbuf, HD, 1024, (long long)HD * 1024, (long long)1024 * HD);
    moe_up_gather<<<dim3(EI / 64, 16, NEXP), blk, 0, stream>>>(
        x2B, Wbuf, comb, lists, cnts, bases, actC);

    // 13. sparse down: actC @ w2T-slices -> 4 slot partials ; out0 += sum
    transpose_convert<<<dim3(HD / 32, (NEXP * EI) / 32), blk, 0, stream>>>(
        w2, Wbuf, NEXP * EI, HD, 0, 0);
    moe_down_gather<<<dim3(HD / 128, 16, NEXP), blk, 0, stream>>>(
        actC, Wbuf, lists, slots, cnts, bases, part);
    reduce_partials<<<dim3(1024), blk, 0, stream>>>(
        part, 4, T * HD / 4, nullptr, out0, 1);
}

// Round 9
// 360.308 us; speedup vs baseline: 20.9883x; 1.0550x over previous
//
#include <hip/hip_runtime.h>
#include <math.h>

// ---------------------------------------------------------------------------
// Problem constants
// ---------------------------------------------------------------------------
#define HD 2048      // hidden size h
#define NQH 16       // num q heads
#define NKVH 4       // num kv heads
#define HEADD 128    // head dim
#define QKVN 3072    // qkv cols
#define NEXP 16      // experts
#define EI 512       // expert intermediate
#define SSI 1024     // shared intermediate
#define TOPK 4
#define TT 1024      // tokens

typedef __bf16 bf16x8 __attribute__((ext_vector_type(8)));
typedef float f32x4 __attribute__((ext_vector_type(4)));

static __device__ __forceinline__ unsigned short f2bf(float f) {
    union { float f; unsigned int u; } v; v.f = f;
    unsigned int r = v.u + 0x7fff + ((v.u >> 16) & 1);
    return (unsigned short)(r >> 16);
}

static __device__ __forceinline__ void gl_lds16(const unsigned short* g,
                                                unsigned short* l) {
    __builtin_amdgcn_global_load_lds(
        (const __attribute__((address_space(1))) unsigned int*)g,
        (__attribute__((address_space(3))) unsigned int*)l, 16, 0, 0);
}

// ---------------------------------------------------------------------------
// Fused add + RMSNorm. resid_out(f32 opt) ; x_bf (bf16)
// ---------------------------------------------------------------------------
__global__ __launch_bounds__(256) void add_rmsnorm_kernel(
    const float* __restrict__ a, const float* __restrict__ b,
    const float* __restrict__ w, float* __restrict__ resid_out,
    unsigned short* __restrict__ x_bf)
{
    int t = blockIdx.x;
    int tid = threadIdx.x;
    const float4* a4 = (const float4*)(a + (size_t)t * HD);
    const float4* b4 = b ? (const float4*)(b + (size_t)t * HD) : nullptr;
    float4* r4 = resid_out ? (float4*)(resid_out + (size_t)t * HD) : nullptr;
    const float4* w4 = (const float4*)w;

    float4 v[2];
    float ss = 0.f;
#pragma unroll
    for (int l = 0; l < 2; ++l) {
        int idx = tid + l * 256;
        float4 va = a4[idx];
        if (b4) {
            float4 vb = b4[idx];
            va.x += vb.x; va.y += vb.y; va.z += vb.z; va.w += vb.w;
        }
        if (r4) r4[idx] = va;
        v[l] = va;
        ss += va.x * va.x + va.y * va.y + va.z * va.z + va.w * va.w;
    }
    for (int off = 32; off > 0; off >>= 1) ss += __shfl_down(ss, off);
    __shared__ float red[4];
    int lane = tid & 63, wv = tid >> 6;
    if (lane == 0) red[wv] = ss;
    __syncthreads();
    if (tid == 0) {
        float s = red[0] + red[1] + red[2] + red[3];
        red[0] = rsqrtf(s / (float)HD + 1e-6f);
    }
    __syncthreads();
    float inv = red[0];
#pragma unroll
    for (int l = 0; l < 2; ++l) {
        int idx = tid + l * 256;
        float4 va = v[l], vw = w4[idx];
        ushort4 ob;
        ob.x = f2bf(va.x * inv * vw.x);
        ob.y = f2bf(va.y * inv * vw.y);
        ob.z = f2bf(va.z * inv * vw.z);
        ob.w = f2bf(va.w * inv * vw.w);
        ((ushort4*)(x_bf + (size_t)t * HD))[idx] = ob;
    }
}

// ---------------------------------------------------------------------------
// Transpose + convert: f32 in [K][N] -> bf16 out [N][K]   (per-z strides)
// ---------------------------------------------------------------------------
__global__ __launch_bounds__(256) void transpose_convert(
    const float* __restrict__ in, unsigned short* __restrict__ out,
    int K, int N, long long strideIn, long long strideOut)
{
    __shared__ float tile[32][33];
    const int n0 = blockIdx.x * 32;
    const int k0 = blockIdx.y * 32;
    const float* ip = in + (size_t)blockIdx.z * strideIn;
    unsigned short* op = out + (size_t)blockIdx.z * strideOut;
    int tid = threadIdx.x;
    int r = tid >> 3, c = (tid & 7) * 4;
    float4 v = *(const float4*)(ip + (size_t)(k0 + r) * N + n0 + c);
    tile[r][c] = v.x; tile[r][c + 1] = v.y; tile[r][c + 2] = v.z; tile[r][c + 3] = v.w;
    __syncthreads();
    ushort4 o;
    o.x = f2bf(tile[c + 0][r]);
    o.y = f2bf(tile[c + 1][r]);
    o.z = f2bf(tile[c + 2][r]);
    o.w = f2bf(tile[c + 3][r]);
    *(ushort4*)(op + (size_t)(n0 + r) * K + k0 + c) = o;
}

// ---------------------------------------------------------------------------
// Split-K bf16 MFMA GEMM, STAGE-early double-buffered, BK=64,
// T4 counted-vmcnt (8 loads/stage stay in flight across raw barriers).
// ---------------------------------------------------------------------------
#define SBK 64

__global__ __launch_bounds__(256) void gemm_splitk(
    const unsigned short* __restrict__ A, const unsigned short* __restrict__ B,
    float* __restrict__ Cpart, int M, int N, int Kc, int ldA, int ldB)
{
    __shared__ unsigned short As[2][128 * SBK];
    __shared__ unsigned short Bs[2][128 * SBK];

    const int tid = threadIdx.x;
    const int wave = tid >> 6;
    const int lane = tid & 63;
    const int wr = wave >> 1, wc = wave & 1;
    const int l15 = lane & 15;
    const int row0 = blockIdx.y * 128;
    const int col0 = blockIdx.x * 128;
    const int z = blockIdx.z;

    const unsigned short* Ap = A + (size_t)row0 * ldA + (size_t)z * Kc;
    const unsigned short* Bp = B + (size_t)col0 * ldB + (size_t)z * Kc;

    const int r_st = tid >> 3;
    const int q_st = tid & 7;
    const int csrc = (q_st ^ (r_st & 7)) << 3;

    f32x4 acc[4][4] = {};

    const int nsteps = Kc / SBK;

#define STAGE_SK(buf, k0s)                                                    \
    {                                                                         \
        _Pragma("unroll")                                                     \
        for (int i = 0; i < 4; ++i) {                                         \
            int rr = r_st + i * 32;                                           \
            gl_lds16(Ap + (size_t)rr * ldA + (k0s) + csrc,                    \
                     &As[buf][rr * SBK + q_st * 8]);                          \
            gl_lds16(Bp + (size_t)rr * ldB + (k0s) + csrc,                    \
                     &Bs[buf][rr * SBK + q_st * 8]);                          \
        }                                                                     \
    }

    STAGE_SK(0, 0);

    for (int s = 0; s < nsteps; ++s) {
        const int cur = s & 1;
        if (s + 1 < nsteps) {
            STAGE_SK(cur ^ 1, (s + 1) * SBK);
            asm volatile("s_waitcnt vmcnt(8)" ::: "memory");
        } else {
            asm volatile("s_waitcnt vmcnt(0)" ::: "memory");
        }
        __builtin_amdgcn_s_barrier();

#pragma unroll
        for (int half = 0; half < 2; ++half) {
            const int q = half * 4 + (lane >> 4);
            bf16x8 af[4], bfv[4];
#pragma unroll
            for (int i = 0; i < 4; ++i) {
                int R = wr * 64 + i * 16 + l15;
                af[i] = *(const bf16x8*)&As[cur][R * SBK + ((q ^ (R & 7)) << 3)];
            }
#pragma unroll
            for (int j = 0; j < 4; ++j) {
                int R = wc * 64 + j * 16 + l15;
                bfv[j] = *(const bf16x8*)&Bs[cur][R * SBK + ((q ^ (R & 7)) << 3)];
            }
#pragma unroll
            for (int mi = 0; mi < 4; ++mi)
#pragma unroll
                for (int nj = 0; nj < 4; ++nj)
                    acc[mi][nj] = __builtin_amdgcn_mfma_f32_16x16x32_bf16(
                        af[mi], bfv[nj], acc[mi][nj], 0, 0, 0);
        }
        __builtin_amdgcn_s_barrier();
    }

    float* Cp = Cpart + (size_t)z * M * N;
#pragma unroll
    for (int mi = 0; mi < 4; ++mi)
#pragma unroll
        for (int nj = 0; nj < 4; ++nj)
#pragma unroll
            for (int r = 0; r < 4; ++r) {
                int row = row0 + wr * 64 + mi * 16 + (lane >> 4) * 4 + r;
                int col = col0 + wc * 64 + nj * 16 + l15;
                Cp[(size_t)row * N + col] = acc[mi][nj][r];
            }
}

// ---------------------------------------------------------------------------
// Reduce split-K partials: out = sum_z part[z] (+ add) (+= out if acc)
// ---------------------------------------------------------------------------
__global__ __launch_bounds__(256) void reduce_partials(
    const float* __restrict__ part, int ns, int n4,
    const float* __restrict__ add, float* __restrict__ out, int acc)
{
    const float4* p4 = (const float4*)part;
    const float4* a4 = (const float4*)add;
    float4* o4 = (float4*)out;
    for (int idx = blockIdx.x * 256 + threadIdx.x; idx < n4;
         idx += gridDim.x * 256) {
        float4 s = p4[idx];
        for (int z = 1; z < ns; ++z) {
            float4 q = p4[(size_t)z * n4 + idx];
            s.x += q.x; s.y += q.y; s.z += q.z; s.w += q.w;
        }
        if (add) {
            float4 q = a4[idx];
            s.x += q.x; s.y += q.y; s.z += q.z; s.w += q.w;
        }
        if (acc) {
            float4 q = o4[idx];
            s.x += q.x; s.y += q.y; s.z += q.z; s.w += q.w;
        }
        o4[idx] = s;
    }
}

// ---------------------------------------------------------------------------
// Reduce split-K partials of shared-expert gu [T][2048] + SwiGLU -> bf16
// ---------------------------------------------------------------------------
__global__ __launch_bounds__(256) void reduce_swiglu(
    const float* __restrict__ part, int ns, unsigned short* __restrict__ out)
{
    int idx4 = blockIdx.x * 256 + threadIdx.x;
    int t = idx4 >> 8;
    int i4 = (idx4 & 255) * 4;
    const float4* pg = (const float4*)(part + (size_t)t * (2 * SSI) + i4);
    const float4* pu = (const float4*)(part + (size_t)t * (2 * SSI) + SSI + i4);
    float4 g = pg[0], u = pu[0];
    for (int z = 1; z < ns; ++z) {
        float4 g2 = *(const float4*)((const float*)pg + (size_t)z * TT * 2 * SSI);
        float4 u2 = *(const float4*)((const float*)pu + (size_t)z * TT * 2 * SSI);
        g.x += g2.x; g.y += g2.y; g.z += g2.z; g.w += g2.w;
        u.x += u2.x; u.y += u2.y; u.z += u2.z; u.w += u2.w;
    }
    ushort4 o;
    o.x = f2bf((g.x / (1.f + __expf(-g.x))) * u.x);
    o.y = f2bf((g.y / (1.f + __expf(-g.y))) * u.y);
    o.z = f2bf((g.z / (1.f + __expf(-g.z))) * u.z);
    o.w = f2bf((g.w / (1.f + __expf(-g.w))) * u.w);
    *(ushort4*)(out + (size_t)t * SSI + i4) = o;
}

// ---------------------------------------------------------------------------
// Build per-expert token lists + slot ranks (token-ordered, deterministic).
// ---------------------------------------------------------------------------
__global__ __launch_bounds__(256) void build_lists(
    const float* __restrict__ comb, int* __restrict__ lists,
    int* __restrict__ slots, int* __restrict__ cnts)
{
    int e = blockIdx.x;
    int tid = threadIdx.x;
    __shared__ int sc[256];
    int loc[4];
    int c = 0;
#pragma unroll
    for (int j = 0; j < 4; ++j) {
        int t = tid * 4 + j;
        if (comb[(size_t)t * NEXP + e] > 0.f) loc[c++] = t;
    }
    sc[tid] = c;
    __syncthreads();
    for (int off = 1; off < 256; off <<= 1) {
        int v = (tid >= off) ? sc[tid - off] : 0;
        __syncthreads();
        sc[tid] += v;
        __syncthreads();
    }
    int base = sc[tid] - c;
    for (int i = 0; i < c; ++i) {
        int t = loc[i];
        int s = 0;
        for (int e2 = 0; e2 < e; ++e2)
            s += (comb[(size_t)t * NEXP + e2] > 0.f) ? 1 : 0;
        lists[e * TT + base + i] = t;
        slots[e * TT + base + i] = s;
    }
    if (tid == 255) cnts[e] = sc[255];
}

// ---------------------------------------------------------------------------
// Prefix-scan expert counts -> bases[17]
// ---------------------------------------------------------------------------
__global__ void scan_cnts(const int* __restrict__ cnts, int* __restrict__ bases)
{
    if (threadIdx.x == 0 && blockIdx.x == 0) {
        int a = 0;
        for (int e = 0; e < NEXP; ++e) { bases[e] = a; a += cnts[e]; }
        bases[NEXP] = a;
    }
}

// ---------------------------------------------------------------------------
// Sparse MoE expert-up + fused SwiGLU*comb -> compact ragged actC (bf16).
// T4 counted-vmcnt (6 loads/stage in flight across raw barriers).
// ---------------------------------------------------------------------------
__global__ __launch_bounds__(256) void moe_up_gather(
    const unsigned short* __restrict__ x2B,
    const unsigned short* __restrict__ w13T,
    const float* __restrict__ comb,
    const int* __restrict__ lists,
    const int* __restrict__ cnts,
    const int* __restrict__ bases,
    unsigned short* __restrict__ actC)
{
    __shared__ unsigned short As[2][64 * 64];
    __shared__ unsigned short Bgs[2][64 * 64];
    __shared__ unsigned short Bus[2][64 * 64];

    const int e = blockIdx.z;
    const int cnt = cnts[e];
    const int m0 = blockIdx.y * 64;
    if (m0 >= cnt) return;
    const int n0 = blockIdx.x * 64;
    const int base_e = bases[e];

    const int tid = threadIdx.x;
    const int w = tid >> 6;
    const int lane = tid & 63;
    const int l15 = lane & 15;
    const int g = lane >> 4;

    const int r0 = tid >> 3;          // 0..31
    const int q_st = tid & 7;
    const int swz = (q_st ^ (r0 & 7)) << 3;

    int a0 = m0 + r0, a1 = m0 + r0 + 32;
    int tok0 = lists[e * TT + (a0 < cnt ? a0 : cnt - 1)];
    int tok1 = lists[e * TT + (a1 < cnt ? a1 : cnt - 1)];
    const unsigned short* Asrc0 = x2B + (size_t)tok0 * HD;
    const unsigned short* Asrc1 = x2B + (size_t)tok1 * HD;
    const unsigned short* Bbase = w13T + (size_t)e * 1024 * HD;
    const unsigned short* Bg0 = Bbase + (size_t)(n0 + r0) * HD;
    const unsigned short* Bg1 = Bbase + (size_t)(n0 + r0 + 32) * HD;
    const unsigned short* Bu0 = Bg0 + (size_t)512 * HD;
    const unsigned short* Bu1 = Bg1 + (size_t)512 * HD;

    f32x4 ag[4] = {};
    f32x4 au[4] = {};

#define STAGE_UP(buf, k0s)                                                    \
    {                                                                         \
        gl_lds16(Asrc0 + (k0s) + swz, &As[buf][(tid) * 8]);                   \
        gl_lds16(Asrc1 + (k0s) + swz, &As[buf][(tid + 256) * 8]);             \
        gl_lds16(Bg0 + (k0s) + swz, &Bgs[buf][(tid) * 8]);                    \
        gl_lds16(Bg1 + (k0s) + swz, &Bgs[buf][(tid + 256) * 8]);              \
        gl_lds16(Bu0 + (k0s) + swz, &Bus[buf][(tid) * 8]);                    \
        gl_lds16(Bu1 + (k0s) + swz, &Bus[buf][(tid + 256) * 8]);              \
    }

    STAGE_UP(0, 0);

    const int nsteps = HD / 64;   // 32
    for (int s = 0; s < nsteps; ++s) {
        const int cur = s & 1;
        if (s + 1 < nsteps) {
            STAGE_UP(cur ^ 1, (s + 1) * 64);
            asm volatile("s_waitcnt vmcnt(6)" ::: "memory");
        } else {
            asm volatile("s_waitcnt vmcnt(0)" ::: "memory");
        }
        __builtin_amdgcn_s_barrier();

#pragma unroll
        for (int kk2 = 0; kk2 < 2; ++kk2) {
            const int q = kk2 * 4 + g;
            bf16x8 af[4], bg, bu;
#pragma unroll
            for (int i = 0; i < 4; ++i) {
                int R = i * 16 + l15;
                af[i] = *(const bf16x8*)&As[cur][R * 64 + ((q ^ (R & 7)) << 3)];
            }
            {
                int R = w * 16 + l15;
                int off = R * 64 + ((q ^ (R & 7)) << 3);
                bg = *(const bf16x8*)&Bgs[cur][off];
                bu = *(const bf16x8*)&Bus[cur][off];
            }
#pragma unroll
            for (int mi = 0; mi < 4; ++mi) {
                ag[mi] = __builtin_amdgcn_mfma_f32_16x16x32_bf16(
                    af[mi], bg, ag[mi], 0, 0, 0);
                au[mi] = __builtin_amdgcn_mfma_f32_16x16x32_bf16(
                    af[mi], bu, au[mi], 0, 0, 0);
            }
        }
        __builtin_amdgcn_s_barrier();
    }

#pragma unroll
    for (int mi = 0; mi < 4; ++mi) {
#pragma unroll
        for (int r = 0; r < 4; ++r) {
            int grow = m0 + mi * 16 + g * 4 + r;
            if (grow >= cnt) continue;
            int tok = lists[e * TT + grow];
            float cw = comb[(size_t)tok * NEXP + e];
            int col = n0 + w * 16 + l15;
            float gg = ag[mi][r];
            float uu = au[mi][r];
            float v = (gg / (1.f + __expf(-gg))) * uu * cw;
            actC[(size_t)(base_e + grow) * EI + col] = f2bf(v);
        }
    }
}

// ---------------------------------------------------------------------------
// Sparse MoE down: actC @ w2T-slice -> slot partials (f32).
// T4 counted-vmcnt (6 loads/stage in flight).
// ---------------------------------------------------------------------------
__global__ __launch_bounds__(256) void moe_down_gather(
    const unsigned short* __restrict__ actC,
    const unsigned short* __restrict__ w2T,   // [HD][NEXP*EI]
    const int* __restrict__ lists,
    const int* __restrict__ slots,
    const int* __restrict__ cnts,
    const int* __restrict__ bases,
    float* __restrict__ slotpart)
{
    __shared__ unsigned short As[2][64 * 64];
    __shared__ unsigned short Bs[2][128 * 64];

    const int e = blockIdx.z;
    const int cnt = cnts[e];
    const int m0 = blockIdx.y * 64;
    if (m0 >= cnt) return;
    const int n0 = blockIdx.x * 128;
    const int base_e = bases[e];

    const int tid = threadIdx.x;
    const int w = tid >> 6;
    const int lane = tid & 63;
    const int l15 = lane & 15;
    const int g = lane >> 4;

    const int r0 = tid >> 3;          // 0..31
    const int q_st = tid & 7;
    const int swz = (q_st ^ (r0 & 7)) << 3;

    int a0 = m0 + r0, a1 = m0 + r0 + 32;
    const unsigned short* Asrc0 =
        actC + (size_t)(base_e + (a0 < cnt ? a0 : cnt - 1)) * EI;
    const unsigned short* Asrc1 =
        actC + (size_t)(base_e + (a1 < cnt ? a1 : cnt - 1)) * EI;
    const unsigned short* Bbase = w2T + (size_t)e * EI;

#define STAGE_DN(buf, k0s)                                                    \
    {                                                                         \
        gl_lds16(Asrc0 + (k0s) + swz, &As[buf][(tid) * 8]);                   \
        gl_lds16(Asrc1 + (k0s) + swz, &As[buf][(tid + 256) * 8]);             \
        _Pragma("unroll")                                                     \
        for (int i = 0; i < 4; ++i) {                                         \
            int rr = r0 + i * 32;                                             \
            gl_lds16(Bbase + (size_t)(n0 + rr) * (NEXP * EI) + (k0s) + swz,   \
                     &Bs[buf][(tid + i * 256) * 8]);                          \
        }                                                                     \
    }

    f32x4 acc[4][2] = {};

    STAGE_DN(0, 0);

    const int nsteps = EI / 64;   // 8
    for (int s = 0; s < nsteps; ++s) {
        const int cur = s & 1;
        if (s + 1 < nsteps) {
            STAGE_DN(cur ^ 1, (s + 1) * 64);
            asm volatile("s_waitcnt vmcnt(6)" ::: "memory");
        } else {
            asm volatile("s_waitcnt vmcnt(0)" ::: "memory");
        }
        __builtin_amdgcn_s_barrier();

#pragma unroll
        for (int kk2 = 0; kk2 < 2; ++kk2) {
            const int q = kk2 * 4 + g;
            bf16x8 af[4], bf[2];
#pragma unroll
            for (int i = 0; i < 4; ++i) {
                int R = i * 16 + l15;
                af[i] = *(const bf16x8*)&As[cur][R * 64 + ((q ^ (R & 7)) << 3)];
            }
#pragma unroll
            for (int j = 0; j < 2; ++j) {
                int R = w * 32 + j * 16 + l15;
                bf[j] = *(const bf16x8*)&Bs[cur][R * 64 + ((q ^ (R & 7)) << 3)];
            }
#pragma unroll
            for (int mi = 0; mi < 4; ++mi)
#pragma unroll
                for (int nj = 0; nj < 2; ++nj)
                    acc[mi][nj] = __builtin_amdgcn_mfma_f32_16x16x32_bf16(
                        af[mi], bf[nj], acc[mi][nj], 0, 0, 0);
        }
        __builtin_amdgcn_s_barrier();
    }

#pragma unroll
    for (int mi = 0; mi < 4; ++mi) {
#pragma unroll
        for (int r = 0; r < 4; ++r) {
            int grow = m0 + mi * 16 + g * 4 + r;
            if (grow >= cnt) continue;
            int tok = lists[e * TT + grow];
            int sl  = slots[e * TT + grow];
            float* orow = slotpart + (size_t)sl * TT * HD + (size_t)tok * HD;
#pragma unroll
            for (int nj = 0; nj < 2; ++nj) {
                int col = n0 + w * 32 + nj * 16 + l15;
                orow[col] = acc[mi][nj][r];
            }
        }
    }
}

// ---------------------------------------------------------------------------
// RoPE + pack to head-major bf16.  One block per token, 256 threads.
// ---------------------------------------------------------------------------
__global__ __launch_bounds__(256) void rope_pack(
    const float* __restrict__ qkv, const int* __restrict__ pos_ids,
    unsigned short* __restrict__ Qb, unsigned short* __restrict__ Kb,
    unsigned short* __restrict__ Vb)
{
    const float SCALE = 0.08838834764831843f;
    int t = blockIdx.x;
    int tid = threadIdx.x;
    int w = tid >> 6, lane = tid & 63;
    float pos = (float)pos_ids[t];
    float invf = powf(10000.0f, -(float)lane * (1.0f / 64.0f));
    float ang = pos * invf;
    float c = cosf(ang);
    float s = sinf(ang);
    const float* row = qkv + (size_t)t * QKVN;
#pragma unroll
    for (int j = 0; j < 5; ++j) {
        int hh = w * 5 + j;
        const float* hb = row + hh * HEADD;
        float x1 = hb[lane], x2 = hb[lane + 64];
        float o1 = x1 * c - x2 * s;
        float o2 = x2 * c + x1 * s;
        if (hh < NQH) {
            unsigned short* qp = Qb + ((size_t)hh * TT + t) * HEADD;
            qp[lane] = f2bf(o1 * SCALE);
            qp[lane + 64] = f2bf(o2 * SCALE);
        } else {
            unsigned short* kp = Kb + ((size_t)(hh - NQH) * TT + t) * HEADD;
            kp[lane] = f2bf(o1);
            kp[lane + 64] = f2bf(o2);
        }
    }
    float2 v2 = *(const float2*)(row + 2560 + tid * 2);
    int kvh = tid >> 6;
    int d = (tid * 2) & 127;
    unsigned int packed = (unsigned int)f2bf(v2.x) |
                          ((unsigned int)f2bf(v2.y) << 16);
    *(unsigned int*)(Vb + ((size_t)kvh * TT + t) * HEADD + d) = packed;
}

// ---------------------------------------------------------------------------
// V transpose: Vb[kvh][t][128] -> Vt[kvh][128][t]
// ---------------------------------------------------------------------------
__global__ __launch_bounds__(256) void transpose_v(
    const unsigned short* __restrict__ Vb, unsigned short* __restrict__ Vt)
{
    __shared__ unsigned short tile[32][40];
    const int kvh = blockIdx.z;
    const int t0 = blockIdx.x * 32, d0 = blockIdx.y * 32;
    int tid = threadIdx.x;
    int r = tid >> 3, c4 = (tid & 7) * 4;
    ushort4 v = *(const ushort4*)(Vb + ((size_t)kvh * TT + t0 + r) * HEADD + d0 + c4);
    tile[r][c4] = v.x; tile[r][c4 + 1] = v.y;
    tile[r][c4 + 2] = v.z; tile[r][c4 + 3] = v.w;
    __syncthreads();
    ushort4 o;
    o.x = tile[c4 + 0][r];
    o.y = tile[c4 + 1][r];
    o.z = tile[c4 + 2][r];
    o.w = tile[c4 + 3][r];
    *(ushort4*)(Vt + ((size_t)kvh * HEADD + d0 + r) * TT + t0 + c4) = o;
}

// ---------------------------------------------------------------------------
// MFMA flash attention v2 — LDS-staged K/V, double-buffered, triangle-paired,
// T4 counted-vmcnt (16 loads/stage in flight across raw barriers).
// ---------------------------------------------------------------------------
__global__ __launch_bounds__(128) void flash_attn_mfma(
    const unsigned short* __restrict__ Qb,
    const unsigned short* __restrict__ Kb,
    const unsigned short* __restrict__ Vt,
    unsigned short* __restrict__ ctx)
{
    __shared__ __align__(16) unsigned short Ks[2][64 * 128];
    __shared__ __align__(16) unsigned short Vs[2][128 * 64];
    __shared__ __align__(16) unsigned short Pl[2][16][72];

    const int h   = blockIdx.x;
    const int p   = blockIdx.y;
    const int rh  = blockIdx.z;
    const int kvh = h >> 2;
    const int tid = threadIdx.x;
    const int w   = tid >> 6;
    const int lane = tid & 63;
    const int l15 = lane & 15;
    const int g   = lane >> 4;

    const unsigned short* Kh = Kb + (size_t)kvh * TT * HEADD;
    const unsigned short* Vh = Vt + (size_t)kvh * HEADD * TT;

#define STAGE_KV(buf, s0s)                                                    \
    {                                                                         \
        _Pragma("unroll")                                                     \
        for (int i = 0; i < 8; ++i) {                                         \
            int idx = tid + i * 128;                                          \
            int r = idx >> 4, c = idx & 15;                                   \
            int csw = (c & 8) | ((c ^ r) & 7);                                \
            gl_lds16(Kh + (size_t)((s0s) + r) * HEADD + csw * 8,              \
                     &Ks[buf][idx * 8]);                                      \
        }                                                                     \
        _Pragma("unroll")                                                     \
        for (int i = 0; i < 8; ++i) {                                         \
            int idx = tid + i * 128;                                          \
            int r = idx >> 3, c = idx & 7;                                    \
            int csw = (c ^ r) & 7;                                            \
            gl_lds16(Vh + (size_t)r * TT + (s0s) + csw * 8,                   \
                     &Vs[buf][idx * 8]);                                      \
        }                                                                     \
    }

    const int qts[2] = {p, 15 - p};

#pragma unroll
    for (int qi = 0; qi < 2; ++qi) {
        const int qt = qts[qi];
        const int q0 = qt * 64 + rh * 32 + w * 16;
        const int ntiles = qt + 1;

        const unsigned short* Qrow = Qb + ((size_t)h * TT + q0 + l15) * HEADD;
        bf16x8 qf[4];
#pragma unroll
        for (int kk = 0; kk < 4; ++kk)
            qf[kk] = *(const bf16x8*)(Qrow + kk * 32 + g * 8);

        float m_i[4], l_i[4];
#pragma unroll
        for (int r = 0; r < 4; ++r) { m_i[r] = -1e30f; l_i[r] = 0.f; }
        f32x4 of[8] = {};

        STAGE_KV(0, 0);

        for (int st = 0; st < ntiles; ++st) {
            const int cur = st & 1;
            const int s0 = st * 64;
            if (st + 1 < ntiles) {
                STAGE_KV(cur ^ 1, (st + 1) * 64);
                asm volatile("s_waitcnt vmcnt(16)" ::: "memory");
            } else {
                asm volatile("s_waitcnt vmcnt(0)" ::: "memory");
            }
            __builtin_amdgcn_s_barrier();

            f32x4 sacc[4] = {};
#pragma unroll
            for (int kk = 0; kk < 4; ++kk) {
#pragma unroll
                for (int n = 0; n < 4; ++n) {
                    int R = n * 16 + l15;
                    int cidx = kk * 4 + g;
                    int cs = (cidx & 8) | ((cidx ^ R) & 7);
                    bf16x8 kb = *(const bf16x8*)&Ks[cur][R * 128 + cs * 8];
                    sacc[n] = __builtin_amdgcn_mfma_f32_16x16x32_bf16(
                        qf[kk], kb, sacc[n], 0, 0, 0);
                }
            }

            const bool diag = (st == qt);
            float alpha[4];
#pragma unroll
            for (int r = 0; r < 4; ++r) {
                const int qrow = q0 + g * 4 + r;
                float sv[4] = {sacc[0][r], sacc[1][r], sacc[2][r], sacc[3][r]};
                if (diag) {
#pragma unroll
                    for (int n = 0; n < 4; ++n)
                        if (s0 + n * 16 + l15 > qrow) sv[n] = -1e30f;
                }
                float rm = fmaxf(fmaxf(sv[0], sv[1]), fmaxf(sv[2], sv[3]));
                rm = fmaxf(rm, __shfl_xor(rm, 1));
                rm = fmaxf(rm, __shfl_xor(rm, 2));
                rm = fmaxf(rm, __shfl_xor(rm, 4));
                rm = fmaxf(rm, __shfl_xor(rm, 8));
                float mnew = fmaxf(m_i[r], rm);
                alpha[r] = __expf(m_i[r] - mnew);
                float p0 = __expf(sv[0] - mnew);
                float p1 = __expf(sv[1] - mnew);
                float p2 = __expf(sv[2] - mnew);
                float p3 = __expf(sv[3] - mnew);
                float rs = p0 + p1 + p2 + p3;
                rs += __shfl_xor(rs, 1);
                rs += __shfl_xor(rs, 2);
                rs += __shfl_xor(rs, 4);
                rs += __shfl_xor(rs, 8);
                l_i[r] = l_i[r] * alpha[r] + rs;
                m_i[r] = mnew;
                Pl[w][g * 4 + r][0 * 16 + l15] = f2bf(p0);
                Pl[w][g * 4 + r][1 * 16 + l15] = f2bf(p1);
                Pl[w][g * 4 + r][2 * 16 + l15] = f2bf(p2);
                Pl[w][g * 4 + r][3 * 16 + l15] = f2bf(p3);
            }

#pragma unroll
            for (int nd = 0; nd < 8; ++nd)
#pragma unroll
                for (int r = 0; r < 4; ++r)
                    of[nd][r] *= alpha[r];

#pragma unroll
            for (int kk2 = 0; kk2 < 2; ++kk2) {
                bf16x8 pa = *(const bf16x8*)&Pl[w][l15][kk2 * 32 + g * 8];
#pragma unroll
                for (int nd = 0; nd < 8; ++nd) {
                    int R = nd * 16 + l15;
                    int cidx = kk2 * 4 + g;
                    int cs = (cidx ^ R) & 7;
                    bf16x8 vb = *(const bf16x8*)&Vs[cur][R * 64 + cs * 8];
                    of[nd] = __builtin_amdgcn_mfma_f32_16x16x32_bf16(
                        pa, vb, of[nd], 0, 0, 0);
                }
            }
            __builtin_amdgcn_s_barrier();
        }

        float invl[4];
#pragma unroll
        for (int r = 0; r < 4; ++r) invl[r] = 1.f / l_i[r];
#pragma unroll
        for (int nd = 0; nd < 8; ++nd)
#pragma unroll
            for (int r = 0; r < 4; ++r) {
                int trow = q0 + g * 4 + r;
                ctx[(size_t)trow * (NQH * HEADD) + h * HEADD + nd * 16 + l15] =
                    f2bf(of[nd][r] * invl[r]);
            }
    }
}

// ---------------------------------------------------------------------------
// Fused router: rmsnorm(resid2)*w . gate_w, softmax top-4 -> comb (T,16)
// ---------------------------------------------------------------------------
__global__ __launch_bounds__(256) void router_fused(
    const float* __restrict__ resid2, const float* __restrict__ w,
    const float* __restrict__ gate_w, float* __restrict__ comb)
{
    int t = blockIdx.x;
    int tid = threadIdx.x;
    int lane = tid & 63, wv = tid >> 6;

    const float4* r4 = (const float4*)(resid2 + (size_t)t * HD);
    float4 xa = r4[tid * 2], xb = r4[tid * 2 + 1];
    float ss = xa.x * xa.x + xa.y * xa.y + xa.z * xa.z + xa.w * xa.w +
               xb.x * xb.x + xb.y * xb.y + xb.z * xb.z + xb.w * xb.w;
    for (int off = 32; off > 0; off >>= 1) ss += __shfl_down(ss, off);
    __shared__ float red[4];
    if (lane == 0) red[wv] = ss;
    __syncthreads();
    float inv = rsqrtf((red[0] + red[1] + red[2] + red[3]) / (float)HD + 1e-6f);

    const float4* w4 = (const float4*)w;
    float4 wa = w4[tid * 2], wb = w4[tid * 2 + 1];
    float xs[8] = {xa.x * wa.x * inv, xa.y * wa.y * inv, xa.z * wa.z * inv,
                   xa.w * wa.w * inv, xb.x * wb.x * inv, xb.y * wb.y * inv,
                   xb.z * wb.z * inv, xb.w * wb.w * inv};

    float acc[16] = {};
    int kbase = tid * 8;
#pragma unroll
    for (int j = 0; j < 8; ++j) {
        float xv = xs[j];
        const float4* wrow = (const float4*)(gate_w + (size_t)(kbase + j) * NEXP);
        float4 w0 = wrow[0], w1 = wrow[1], w2 = wrow[2], w3 = wrow[3];
        acc[0] += xv * w0.x;  acc[1] += xv * w0.y;  acc[2] += xv * w0.z;  acc[3] += xv * w0.w;
        acc[4] += xv * w1.x;  acc[5] += xv * w1.y;  acc[6] += xv * w1.z;  acc[7] += xv * w1.w;
        acc[8] += xv * w2.x;  acc[9] += xv * w2.y;  acc[10] += xv * w2.z; acc[11] += xv * w2.w;
        acc[12] += xv * w3.x; acc[13] += xv * w3.y; acc[14] += xv * w3.z; acc[15] += xv * w3.w;
    }
    __shared__ float red2[4][16];
#pragma unroll
    for (int e = 0; e < 16; ++e) {
        float v = acc[e];
        v += __shfl_xor(v, 1);
        v += __shfl_xor(v, 2);
        v += __shfl_xor(v, 4);
        v += __shfl_xor(v, 8);
        v += __shfl_xor(v, 16);
        v += __shfl_xor(v, 32);
        if (lane == 0) red2[wv][e] = v;
    }
    __syncthreads();

    if (tid == 0) {
        float l[NEXP];
#pragma unroll
        for (int e = 0; e < NEXP; ++e)
            l[e] = red2[0][e] + red2[1][e] + red2[2][e] + red2[3][e];
        int sel[TOPK];
        float selv[TOPK];
        bool used[NEXP] = {};
#pragma unroll
        for (int r = 0; r < TOPK; ++r) {
            int best = -1;
            float bv = -1e30f;
            for (int e = 0; e < NEXP; ++e)
                if (!used[e] && l[e] > bv) { bv = l[e]; best = e; }
            used[best] = true;
            sel[r] = best;
            selv[r] = bv;
        }
        float mx = selv[0];
        float wsum = 0.f, wvv[TOPK];
#pragma unroll
        for (int r = 0; r < TOPK; ++r) { wvv[r] = __expf(selv[r] - mx); wsum += wvv[r]; }
        float out16[NEXP] = {};
#pragma unroll
        for (int r = 0; r < TOPK; ++r) out16[sel[r]] = wvv[r] / wsum;
#pragma unroll
        for (int e = 0; e < NEXP; ++e) comb[(size_t)t * NEXP + e] = out16[e];
    }
}

// ---------------------------------------------------------------------------
extern "C" void kernel_launch(void* const* d_in, const int* in_sizes, int n_in,
                              void* d_out, int out_size, void* d_ws, size_t ws_size,
                              hipStream_t stream)
{
    const float* hidden   = (const float*)d_in[0];
    const float* residual = (const float*)d_in[1];
    const float* rms1_w   = (const float*)d_in[2];
    const float* rms2_w   = (const float*)d_in[3];
    const float* w_qkv    = (const float*)d_in[4];
    const float* w_dense  = (const float*)d_in[5];
    const float* gate_w   = (const float*)d_in[6];
    const float* w13      = (const float*)d_in[7];
    const float* w2       = (const float*)d_in[8];
    const float* sw13     = (const float*)d_in[9];
    const float* sw2      = (const float*)d_in[10];
    const int*   pos_ids  = (const int*)d_in[11];

    const int T = TT;

    float* out0 = (float*)d_out;
    float* out1 = (float*)d_out + (size_t)T * HD;

    // ---- workspace layout ----
    char* base = (char*)d_ws;
    float*          residF = (float*)(base);                    //  8.39 MB
    unsigned short* xB     = (unsigned short*)(base + 8388608); //  4.19 MB
    unsigned short* ctxB   = (unsigned short*)(base + 12582912);//  4.19 MB
    unsigned short* actC   = (unsigned short*)(base);           //  4.19 MB alias (residF dead by MoE)
    float*          qkvF   = (float*)(base + 16777216);         // 12.58 MB
    unsigned short* x2B    = (unsigned short*)(base + 29360128);//  4.19 MB
    unsigned short* sactB  = (unsigned short*)(base + 33554432);//  2.10 MB
    float*          comb   = (float*)(base + 35651584);         //  0.07 MB
    float*          part   = (float*)(base + 35717120);         // 33.55 MB (split-K / slot partials)
    unsigned short* Wbuf   = (unsigned short*)(base + 69271552);// 67.11 MB (weights, phase-reused)
    int*            lists  = (int*)(base + 139526144);          //  64 KB
    int*            cnts   = (int*)(base + 139591680);          //  256 B
    int*            slots  = (int*)(base + 139591936);          //  64 KB
    int*            bases  = (int*)(base + 139657472);          //  128 B

    // attention bf16 buffers alias the split-K `part` region (dead there)
    unsigned short* Qb = (unsigned short*)(base + 35717120);            // 4 MB
    unsigned short* Kb = Qb + (size_t)NQH * TT * HEADD;                 // 1 MB
    unsigned short* Vb = Kb + (size_t)NKVH * TT * HEADD;                // 1 MB
    unsigned short* Vt = Vb + (size_t)NKVH * TT * HEADD;                // 1 MB

    dim3 blk(256);

    // 1. resid = hidden + residual ; x = rmsnorm -> bf16
    add_rmsnorm_kernel<<<dim3(T), blk, 0, stream>>>(
        hidden, residual, rms1_w, residF, xB);

    // 2. qkv = x @ w_qkv   (split-K x2)
    transpose_convert<<<dim3(QKVN / 32, HD / 32), blk, 0, stream>>>(
        w_qkv, Wbuf, HD, QKVN, 0, 0);
    gemm_splitk<<<dim3(QKVN / 128, T / 128, 2), blk, 0, stream>>>(
        xB, Wbuf, part, T, QKVN, 1024, HD, HD);
    reduce_partials<<<dim3(1024), blk, 0, stream>>>(
        part, 2, T * QKVN / 4, nullptr, qkvF, 0);

    // 3. RoPE + pack head-major bf16 ; V transpose
    rope_pack<<<dim3(T), blk, 0, stream>>>(qkvF, pos_ids, Qb, Kb, Vb);
    transpose_v<<<dim3(T / 32, HEADD / 32, NKVH), blk, 0, stream>>>(Vb, Vt);

    // 4. MFMA flash attention v2 -> ctx (bf16)
    flash_attn_mfma<<<dim3(NQH, 8, 2), dim3(128), 0, stream>>>(Qb, Kb, Vt, ctxB);

    // 5. resid2 = ctx @ w_dense + resid -> out1   (split-K x4)
    transpose_convert<<<dim3(HD / 32, HD / 32), blk, 0, stream>>>(
        w_dense, Wbuf, HD, HD, 0, 0);
    gemm_splitk<<<dim3(HD / 128, T / 128, 4), blk, 0, stream>>>(
        ctxB, Wbuf, part, T, HD, 512, HD, HD);
    reduce_partials<<<dim3(1024), blk, 0, stream>>>(
        part, 4, T * HD / 4, residF, out1, 0);

    // 6. x2 = rmsnorm(resid2) -> bf16
    add_rmsnorm_kernel<<<dim3(T), blk, 0, stream>>>(
        out1, nullptr, rms2_w, nullptr, x2B);

    // 7. fused router -> comb ; 8. expert token lists + slots + bases
    router_fused<<<dim3(T), blk, 0, stream>>>(out1, rms2_w, gate_w, comb);
    build_lists<<<dim3(NEXP), blk, 0, stream>>>(comb, lists, slots, cnts);
    scan_cnts<<<dim3(1), dim3(64), 0, stream>>>(cnts, bases);

    // 9. shared gu = x2 @ sw13  (split-K x4) -> part
    transpose_convert<<<dim3(HD / 32, HD / 32), blk, 0, stream>>>(
        sw13, Wbuf, HD, 2 * SSI, 0, 0);
    gemm_splitk<<<dim3(HD / 128, T / 128, 4), blk, 0, stream>>>(
        x2B, Wbuf, part, T, 2 * SSI, 512, HD, HD);

    // 10. fused reduce + SwiGLU -> sactB (bf16)
    reduce_swiglu<<<dim3(T * SSI / 4 / 256), blk, 0, stream>>>(part, 4, sactB);

    // 11. out0 = shared_act @ sw2  (split-K x4)
    transpose_convert<<<dim3(HD / 32, SSI / 32), blk, 0, stream>>>(
        sw2, Wbuf, SSI, HD, 0, 0);
    gemm_splitk<<<dim3(HD / 128, T / 128, 4), blk, 0, stream>>>(
        sactB, Wbuf, part, T, HD, 256, SSI, SSI);
    reduce_partials<<<dim3(1024), blk, 0, stream>>>(
        part, 4, T * HD / 4, nullptr, out0, 0);

    // 12. sparse expert up + fused SwiGLU*comb -> compact actC
    transpose_convert<<<dim3(1024 / 32, HD / 32, NEXP), blk, 0, stream>>>(
        w13, Wbuf, HD, 1024, (long long)HD * 1024, (long long)1024 * HD);
    moe_up_gather<<<dim3(EI / 64, 16, NEXP), blk, 0, stream>>>(
        x2B, Wbuf, comb, lists, cnts, bases, actC);

    // 13. sparse down: actC @ w2T-slices -> 4 slot partials ; out0 += sum
    transpose_convert<<<dim3(HD / 32, (NEXP * EI) / 32), blk, 0, stream>>>(
        w2, Wbuf, NEXP * EI, HD, 0, 0);
    moe_down_gather<<<dim3(HD / 128, 16, NEXP), blk, 0, stream>>>(
        actC, Wbuf, lists, slots, cnts, bases, part);
    reduce_partials<<<dim3(1024), blk, 0, stream>>>(
        part, 4, T * HD / 4, nullptr, out0, 1);
}